// Round 2
// baseline (9366.975 us; speedup 1.0000x reference)
//
#include <hip/hip_runtime.h>
#include <math.h>

#define BATCH  16384
#define NCATS  16
#define VOCABN 1000
#define DIMD   64
#define NHEAD  4
#define DHEAD  16
#define SHARED_E 10
#define INDIVE 54
#define CONTN  16
#define FLATN  1040   // NCATS*DIMD + CONTN
#define H1N    4160
#define H2N    2080
#define EPSV   1e-5f

__device__ __forceinline__ float gelu_f(float x) {
    return 0.5f * x * (1.0f + erff(x * 0.70710678118654752440f));
}
__device__ __forceinline__ float wsum(float v) {
#pragma unroll
    for (int o = 32; o > 0; o >>= 1) v += __shfl_xor(v, o, 64);
    return v;
}

// ---------------- token build: xflat[:, 0:1024] (chunk-local rows) ----------------
__global__ __launch_bounds__(256) void build_tokens(
    const int* __restrict__ x_cat, const float* __restrict__ shared_emb,
    const float* __restrict__ emb, float* __restrict__ xflat)
{
    int idx = blockIdx.x * 256 + threadIdx.x;      // mc*1024 total
    int b = idx >> 10, r = idx & 1023;
    int c = r >> 6, d = r & 63;
    float v;
    if (d < SHARED_E) v = shared_emb[d];
    else              v = emb[((size_t)c * VOCABN + x_cat[b * NCATS + c]) * INDIVE + (d - SHARED_E)];
    xflat[(size_t)b * FLATN + r] = v;
}

// ---------------- cont projection: xflat[:, 1024:1040] ----------------
__global__ __launch_bounds__(256) void cont_proj(
    const float* __restrict__ x_cont, const float* __restrict__ cw,
    const float* __restrict__ cb, float* __restrict__ xflat)
{
    int idx = blockIdx.x * 256 + threadIdx.x;      // mc*16 total
    int b = idx >> 4, j = idx & 15;
    float acc = cb[j];
#pragma unroll
    for (int k = 0; k < 16; ++k) acc += x_cont[b * 16 + k] * cw[k * 16 + j];
    xflat[(size_t)b * FLATN + 1024 + j] = acc;
}

// ---------------- micro encoder: 2 tokens, 1 wave / sample ----------------
__global__ __launch_bounds__(64) void micro_enc(
    float* __restrict__ xflat,
    const float* __restrict__ qkv_w, const float* __restrict__ out_w,
    const float* __restrict__ ln1w, const float* __restrict__ ln1b,
    const float* __restrict__ ln2w, const float* __restrict__ ln2b,
    const float* __restrict__ w1, const float* __restrict__ b1,
    const float* __restrict__ w2, const float* __restrict__ b2)
{
    int b = blockIdx.x;
    int lane = threadIdx.x;
    __shared__ float X[2][64], XN[2][64], QKV[2][192], OO[2][64], FF[2][256];
    __shared__ float PREV[16], ATTN[16];

    float* xrow = xflat + (size_t)b * FLATN;
    X[0][lane] = xrow[lane];
    X[1][lane] = xrow[64 + lane];
    if (lane < 16) PREV[lane] = 0.f;
    __syncthreads();

    for (int p = 0; p < 2; ++p) {
        const float* qw  = qkv_w + p * 64 * 192;
        const float* ow  = out_w + p * 64 * 64;
        const float* l1w = ln1w + p * 64; const float* l1b = ln1b + p * 64;
        const float* l2w = ln2w + p * 64; const float* l2b = ln2b + p * 64;
        const float* fw1 = w1 + p * 64 * 256; const float* fb1 = b1 + p * 256;
        const float* fw2 = w2 + p * 256 * 64; const float* fb2 = b2 + p * 64;

        // LN1
#pragma unroll
        for (int t = 0; t < 2; ++t) {
            float v = X[t][lane];
            float m = wsum(v) * (1.f / 64.f);
            float d = v - m;
            float var = wsum(d * d) * (1.f / 64.f);
            XN[t][lane] = d * rsqrtf(var + EPSV) * l1w[lane] + l1b[lane];
        }
        __syncthreads();

        // qkv: 2x192 outputs, 3 columns / thread
        for (int cc = 0; cc < 3; ++cc) {
            int c = lane + cc * 64;
            float a0 = 0.f, a1 = 0.f;
            for (int k = 0; k < 64; k += 4) {
                float wv[4];
#pragma unroll
                for (int u = 0; u < 4; ++u) wv[u] = qw[(k + u) * 192 + c];
#pragma unroll
                for (int u = 0; u < 4; ++u) { a0 += XN[0][k + u] * wv[u]; a1 += XN[1][k + u] * wv[u]; }
            }
            QKV[0][c] = a0; QKV[1][c] = a1;
        }
        __syncthreads();

        // scores (4 heads x 2 x 2) + prev carry
        if (lane < 16) {
            int h = lane >> 2, i = (lane >> 1) & 1, j = lane & 1;
            float s = 0.f;
#pragma unroll
            for (int d = 0; d < 16; ++d)
                s += QKV[i][h * 16 + d] * QKV[j][64 + h * 16 + d];
            s = s * 0.25f + PREV[lane];
            PREV[lane] = s;
        }
        __syncthreads();
        // softmax over j (2 elements)
        if (lane < 16) {
            int base = lane & ~1;
            float s0 = PREV[base], s1 = PREV[base + 1];
            float mx = fmaxf(s0, s1);
            float e0 = expf(s0 - mx), e1 = expf(s1 - mx);
            float inv = 1.f / (e0 + e1);
            ATTN[lane] = (lane & 1) ? e1 * inv : e0 * inv;
        }
        __syncthreads();

        // o = attn @ v
        {
            int h = lane >> 4;
#pragma unroll
            for (int t = 0; t < 2; ++t)
                OO[t][lane] = ATTN[h * 4 + t * 2 + 0] * QKV[0][128 + lane]
                            + ATTN[h * 4 + t * 2 + 1] * QKV[1][128 + lane];
        }
        __syncthreads();

        // out proj + residual
        {
            float a0 = 0.f, a1 = 0.f;
            for (int k = 0; k < 64; k += 4) {
                float wv[4];
#pragma unroll
                for (int u = 0; u < 4; ++u) wv[u] = ow[(k + u) * 64 + lane];
#pragma unroll
                for (int u = 0; u < 4; ++u) { a0 += OO[0][k + u] * wv[u]; a1 += OO[1][k + u] * wv[u]; }
            }
            X[0][lane] += a0; X[1][lane] += a1;
        }
        __syncthreads();

        // LN2
#pragma unroll
        for (int t = 0; t < 2; ++t) {
            float v = X[t][lane];
            float m = wsum(v) * (1.f / 64.f);
            float d = v - m;
            float var = wsum(d * d) * (1.f / 64.f);
            XN[t][lane] = d * rsqrtf(var + EPSV) * l2w[lane] + l2b[lane];
        }
        __syncthreads();

        // ff1 + gelu: 2x256, 4 columns / thread
        for (int cc = 0; cc < 4; ++cc) {
            int c = lane + cc * 64;
            float a0 = fb1[c], a1 = fb1[c];
            for (int k = 0; k < 64; k += 4) {
                float wv[4];
#pragma unroll
                for (int u = 0; u < 4; ++u) wv[u] = fw1[(k + u) * 256 + c];
#pragma unroll
                for (int u = 0; u < 4; ++u) { a0 += XN[0][k + u] * wv[u]; a1 += XN[1][k + u] * wv[u]; }
            }
            FF[0][c] = gelu_f(a0); FF[1][c] = gelu_f(a1);
        }
        __syncthreads();

        // ff2 + residual
        {
            float a0 = fb2[lane], a1 = fb2[lane];
            for (int k = 0; k < 256; k += 4) {
                float wv[4];
#pragma unroll
                for (int u = 0; u < 4; ++u) wv[u] = fw2[(k + u) * 64 + lane];
#pragma unroll
                for (int u = 0; u < 4; ++u) { a0 += FF[0][k + u] * wv[u]; a1 += FF[1][k + u] * wv[u]; }
            }
            X[0][lane] += a0; X[1][lane] += a1;
        }
        __syncthreads();
    }

    xrow[lane]      = X[0][lane];
    xrow[64 + lane] = X[1][lane];
}

// ---------------- macro encoder: 16 tokens, 256 threads / sample ----------------
__global__ __launch_bounds__(256) void macro_enc(
    float* __restrict__ xflat,
    const float* __restrict__ qkv_w, const float* __restrict__ out_w,
    const float* __restrict__ ln1w, const float* __restrict__ ln1b,
    const float* __restrict__ ln2w, const float* __restrict__ ln2b,
    const float* __restrict__ w1, const float* __restrict__ b1,
    const float* __restrict__ w2, const float* __restrict__ b2)
{
    int b = blockIdx.x;
    int tid = threadIdx.x;
    int lane = tid & 63, w = tid >> 6;

    __shared__ float X[16][64], XN[16][64], QKV[16][192], OO[16][64], FF[16][256];
    __shared__ float PREV[4][16][16], ATTN[4][16][16];

    float* xrow = xflat + (size_t)b * FLATN;
#pragma unroll
    for (int i = 0; i < 4; ++i) {
        int e = tid + i * 256;
        X[e >> 6][e & 63] = xrow[e];
        ((float*)PREV)[e] = 0.f;
    }
    __syncthreads();

    for (int p = 0; p < 2; ++p) {
        const float* qw  = qkv_w + p * 64 * 192;
        const float* ow  = out_w + p * 64 * 64;
        const float* l1w = ln1w + p * 64; const float* l1b = ln1b + p * 64;
        const float* l2w = ln2w + p * 64; const float* l2b = ln2b + p * 64;
        const float* fw1 = w1 + p * 64 * 256; const float* fb1 = b1 + p * 256;
        const float* fw2 = w2 + p * 256 * 64; const float* fb2 = b2 + p * 64;

        // LN1: thread (w,lane) owns rows w+4i
#pragma unroll
        for (int i = 0; i < 4; ++i) {
            int r = w + 4 * i;
            float v = X[r][lane];
            float m = wsum(v) * (1.f / 64.f);
            float d = v - m;
            float var = wsum(d * d) * (1.f / 64.f);
            XN[r][lane] = d * rsqrtf(var + EPSV) * l1w[lane] + l1b[lane];
        }
        __syncthreads();

        // qkv: 16x192 outputs, one column per thread (tid<192), all 16 rows
        if (tid < 192) {
            int c = tid;
            float acc[16];
#pragma unroll
            for (int t = 0; t < 16; ++t) acc[t] = 0.f;
            for (int k = 0; k < 64; k += 4) {
                float wv[4];
#pragma unroll
                for (int u = 0; u < 4; ++u) wv[u] = qw[(k + u) * 192 + c];
#pragma unroll
                for (int t = 0; t < 16; ++t) {
#pragma unroll
                    for (int u = 0; u < 4; ++u) acc[t] += XN[t][k + u] * wv[u];
                }
            }
#pragma unroll
            for (int t = 0; t < 16; ++t) QKV[t][c] = acc[t];
        }
        __syncthreads();

        // scores + prev carry: 4*16*16 = 1024 entries, 4 per thread
#pragma unroll
        for (int i = 0; i < 4; ++i) {
            int e = tid + i * 256;
            int h = e >> 8, rem = e & 255, qi = rem >> 4, j = rem & 15;
            float s = 0.f;
#pragma unroll
            for (int d = 0; d < 16; ++d)
                s += QKV[qi][h * 16 + d] * QKV[j][64 + h * 16 + d];
            s = s * 0.25f + PREV[h][qi][j];
            PREV[h][qi][j] = s;
        }
        __syncthreads();

        // softmax over j: 64 rows, wave 0
        if (tid < 64) {
            int h = tid >> 4, qi = tid & 15;
            float mx = -1e30f;
#pragma unroll
            for (int j = 0; j < 16; ++j) mx = fmaxf(mx, PREV[h][qi][j]);
            float sum = 0.f;
#pragma unroll
            for (int j = 0; j < 16; ++j) {
                float e = expf(PREV[h][qi][j] - mx);
                ATTN[h][qi][j] = e;
                sum += e;
            }
            float inv = 1.f / sum;
#pragma unroll
            for (int j = 0; j < 16; ++j) ATTN[h][qi][j] *= inv;
        }
        __syncthreads();

        // o = attn @ v : rows w+4i, col lane (head = lane>>4)
        {
            int h = lane >> 4;
#pragma unroll
            for (int i = 0; i < 4; ++i) {
                int r = w + 4 * i;
                float acc = 0.f;
#pragma unroll
                for (int j = 0; j < 16; ++j) acc += ATTN[h][r][j] * QKV[j][128 + lane];
                OO[r][lane] = acc;
            }
        }
        __syncthreads();

        // out proj + residual
        {
            float acc[4] = {0.f, 0.f, 0.f, 0.f};
            for (int k = 0; k < 64; k += 4) {
                float wv[4];
#pragma unroll
                for (int u = 0; u < 4; ++u) wv[u] = ow[(k + u) * 64 + lane];
#pragma unroll
                for (int i = 0; i < 4; ++i) {
                    int r = w + 4 * i;
#pragma unroll
                    for (int u = 0; u < 4; ++u) acc[i] += OO[r][k + u] * wv[u];
                }
            }
#pragma unroll
            for (int i = 0; i < 4; ++i) X[w + 4 * i][lane] += acc[i];
        }
        __syncthreads();

        // LN2
#pragma unroll
        for (int i = 0; i < 4; ++i) {
            int r = w + 4 * i;
            float v = X[r][lane];
            float m = wsum(v) * (1.f / 64.f);
            float d = v - m;
            float var = wsum(d * d) * (1.f / 64.f);
            XN[r][lane] = d * rsqrtf(var + EPSV) * l2w[lane] + l2b[lane];
        }
        __syncthreads();

        // ff1 + gelu: 16x256, one column per thread, all 16 rows
        {
            int c = tid;
            float acc[16];
#pragma unroll
            for (int t = 0; t < 16; ++t) acc[t] = fb1[c];
            for (int k = 0; k < 64; k += 4) {
                float wv[4];
#pragma unroll
                for (int u = 0; u < 4; ++u) wv[u] = fw1[(k + u) * 256 + c];
#pragma unroll
                for (int t = 0; t < 16; ++t) {
#pragma unroll
                    for (int u = 0; u < 4; ++u) acc[t] += XN[t][k + u] * wv[u];
                }
            }
#pragma unroll
            for (int t = 0; t < 16; ++t) FF[t][c] = gelu_f(acc[t]);
        }
        __syncthreads();

        // ff2 + residual: col lane, rows w+4i
        {
            float acc[4];
#pragma unroll
            for (int i = 0; i < 4; ++i) acc[i] = fb2[lane];
            for (int k = 0; k < 256; k += 4) {
                float wv[4];
#pragma unroll
                for (int u = 0; u < 4; ++u) wv[u] = fw2[(k + u) * 64 + lane];
#pragma unroll
                for (int i = 0; i < 4; ++i) {
                    int r = w + 4 * i;
#pragma unroll
                    for (int u = 0; u < 4; ++u) acc[i] += FF[r][k + u] * wv[u];
                }
            }
#pragma unroll
            for (int i = 0; i < 4; ++i) X[w + 4 * i][lane] += acc[i];
        }
        __syncthreads();
    }

#pragma unroll
    for (int i = 0; i < 4; ++i) {
        int e = tid + i * 256;
        xrow[e] = X[e >> 6][e & 63];
    }
}

// ---------------- tiled fp32 GEMM: C = gelu(A @ W + bias) ----------------
__global__ __launch_bounds__(256) void gemm_bias_gelu(
    const float* __restrict__ A, const float* __restrict__ W,
    const float* __restrict__ bias, float* __restrict__ C,
    int M, int N, int K)
{
    __shared__ float As[16][68];
    __shared__ float Bs[16][64];

    int tid = threadIdx.x;
    int bm = blockIdx.y * 64, bn = blockIdx.x * 64;
    int tx = tid & 15, ty = tid >> 4;

    float acc[4][4];
#pragma unroll
    for (int i = 0; i < 4; ++i)
#pragma unroll
        for (int j = 0; j < 4; ++j) acc[i][j] = 0.f;

    for (int k0 = 0; k0 < K; k0 += 16) {
#pragma unroll
        for (int i = 0; i < 4; ++i) {            // A tile 64x16
            int e = tid + i * 256;
            int r = e >> 4, c = e & 15;
            As[c][r] = A[(size_t)(bm + r) * K + k0 + c];
        }
#pragma unroll
        for (int i = 0; i < 4; ++i) {            // B tile 16x64
            int e = tid + i * 256;
            int r = e >> 6, c = e & 63;
            int col = bn + c;
            Bs[r][c] = (col < N) ? W[(size_t)(k0 + r) * N + col] : 0.f;
        }
        __syncthreads();
#pragma unroll
        for (int kk = 0; kk < 16; ++kk) {
            float a[4], bb[4];
#pragma unroll
            for (int i = 0; i < 4; ++i) a[i]  = As[kk][ty * 4 + i];
#pragma unroll
            for (int j = 0; j < 4; ++j) bb[j] = Bs[kk][tx * 4 + j];
#pragma unroll
            for (int i = 0; i < 4; ++i)
#pragma unroll
                for (int j = 0; j < 4; ++j) acc[i][j] += a[i] * bb[j];
        }
        __syncthreads();
    }

#pragma unroll
    for (int i = 0; i < 4; ++i) {
        int row = bm + ty * 4 + i;
#pragma unroll
        for (int j = 0; j < 4; ++j) {
            int col = bn + tx * 4 + j;
            if (col < N) {
                float v = acc[i][j] + bias[col];
                C[(size_t)row * N + col] = gelu_f(v);
            }
        }
    }
}

// ---------------- final dot: logits = h2 @ w3 + b3 ----------------
__global__ __launch_bounds__(256) void final_dot(
    const float* __restrict__ h2, const float* __restrict__ w3,
    const float* __restrict__ b3, float* __restrict__ out)
{
    int b = blockIdx.x;
    int tid = threadIdx.x;
    float acc = 0.f;
    for (int k = tid; k < H2N; k += 256) acc += h2[(size_t)b * H2N + k] * w3[k];
    acc = wsum(acc);
    __shared__ float s[4];
    if ((tid & 63) == 0) s[tid >> 6] = acc;
    __syncthreads();
    if (tid == 0) out[b] = s[0] + s[1] + s[2] + s[3] + b3[0];
}

extern "C" void kernel_launch(void* const* d_in, const int* in_sizes, int n_in,
                              void* d_out, int out_size, void* d_ws, size_t ws_size,
                              hipStream_t stream)
{
    const int*   x_cat      = (const int*)  d_in[0];
    const float* x_cont     = (const float*)d_in[1];
    const float* shared_emb = (const float*)d_in[2];
    const float* emb        = (const float*)d_in[3];
    const float* mi_qkv  = (const float*)d_in[4];
    const float* mi_out  = (const float*)d_in[5];
    const float* mi_ln1w = (const float*)d_in[6];
    const float* mi_ln1b = (const float*)d_in[7];
    const float* mi_ln2w = (const float*)d_in[8];
    const float* mi_ln2b = (const float*)d_in[9];
    const float* mi_w1   = (const float*)d_in[10];
    const float* mi_b1   = (const float*)d_in[11];
    const float* mi_w2   = (const float*)d_in[12];
    const float* mi_b2   = (const float*)d_in[13];
    const float* ma_qkv  = (const float*)d_in[14];
    const float* ma_out  = (const float*)d_in[15];
    const float* ma_ln1w = (const float*)d_in[16];
    const float* ma_ln1b = (const float*)d_in[17];
    const float* ma_ln2w = (const float*)d_in[18];
    const float* ma_ln2b = (const float*)d_in[19];
    const float* ma_w1   = (const float*)d_in[20];
    const float* ma_b1   = (const float*)d_in[21];
    const float* ma_w2   = (const float*)d_in[22];
    const float* ma_b2   = (const float*)d_in[23];
    const float* cont_w  = (const float*)d_in[24];
    const float* cont_b  = (const float*)d_in[25];
    const float* w1      = (const float*)d_in[26];
    const float* b1      = (const float*)d_in[27];
    const float* w2      = (const float*)d_in[28];
    const float* b2      = (const float*)d_in[29];
    const float* w3      = (const float*)d_in[30];
    const float* b3      = (const float*)d_in[31];
    float* out = (float*)d_out;

    // Workspace-adaptive chunking: per-row scratch = (1040+4160+2080)*4 = 29120 B.
    // CH = largest multiple of 64 fitting in ws_size (full batch needs 477 MB).
    const size_t per_row = (size_t)(FLATN + H1N + H2N) * sizeof(float);
    size_t ch = ws_size / per_row;
    int CH = (int)((ch / 64) * 64);
    if (CH > BATCH) CH = BATCH;
    if (CH < 64) CH = 64;   // below this nothing fits; fail loudly via fault rather than silently

    float* xflat = (float*)d_ws;                 // CH * 1040
    float* h1    = xflat + (size_t)CH * FLATN;   // CH * 4160
    float* h2    = h1    + (size_t)CH * H1N;     // CH * 2080

    for (int m0 = 0; m0 < BATCH; m0 += CH) {
        int mc = BATCH - m0 < CH ? BATCH - m0 : CH;   // always a multiple of 64

        build_tokens<<<(mc * 1024) / 256, 256, 0, stream>>>(
            x_cat + (size_t)m0 * NCATS, shared_emb, emb, xflat);
        cont_proj<<<(mc * 16) / 256, 256, 0, stream>>>(
            x_cont + (size_t)m0 * CONTN, cont_w, cont_b, xflat);
        micro_enc<<<mc, 64, 0, stream>>>(xflat, mi_qkv, mi_out, mi_ln1w, mi_ln1b,
                                         mi_ln2w, mi_ln2b, mi_w1, mi_b1, mi_w2, mi_b2);
        macro_enc<<<mc, 256, 0, stream>>>(xflat, ma_qkv, ma_out, ma_ln1w, ma_ln1b,
                                          ma_ln2w, ma_ln2b, ma_w1, ma_b1, ma_w2, ma_b2);
        gemm_bias_gelu<<<dim3(H1N / 64, mc / 64), 256, 0, stream>>>(
            xflat, w1, b1, h1, mc, H1N, FLATN);
        gemm_bias_gelu<<<dim3((H2N + 63) / 64, mc / 64), 256, 0, stream>>>(
            h1, w2, b2, h2, mc, H2N, H1N);
        final_dot<<<mc, 256, 0, stream>>>(h2, w3, b3, out + m0);
    }
}

// Round 4
// 5143.361 us; speedup vs baseline: 1.8212x; 1.8212x over previous
//
#include <hip/hip_runtime.h>
#include <hip/hip_bf16.h>
#include <math.h>

#define BATCH  16384
#define NCATS  16
#define VOCABN 1000
#define DIMD   64
#define SHARED_E 10
#define INDIVE 54
#define CONTN  16
#define FLATN  1040   // NCATS*DIMD + CONTN
#define H1N    4160
#define H2N    2080
#define KP1    1088   // FLATN padded to mult of 64
#define NP1    4224   // H1N padded to mult of 128
#define KP2    4224   // = NP1 (GEMM2 K)
#define NP2    2176   // H2N padded to mult of 128
#define EPSV   1e-5f

typedef __attribute__((ext_vector_type(8))) short bf16x8;
typedef __attribute__((ext_vector_type(4))) float f32x4;

__device__ __forceinline__ float gelu_f(float x) {
    return 0.5f * x * (1.0f + erff(x * 0.70710678118654752440f));
}
__device__ __forceinline__ float wsum(float v) {
#pragma unroll
    for (int o = 32; o > 0; o >>= 1) v += __shfl_xor(v, o, 64);
    return v;
}

// ---------------- token build: xflat[:, 0:1024] (chunk-local rows) ----------------
__global__ __launch_bounds__(256) void build_tokens(
    const int* __restrict__ x_cat, const float* __restrict__ shared_emb,
    const float* __restrict__ emb, float* __restrict__ xflat)
{
    int idx = blockIdx.x * 256 + threadIdx.x;      // mc*1024 total
    int b = idx >> 10, r = idx & 1023;
    int c = r >> 6, d = r & 63;
    float v;
    if (d < SHARED_E) v = shared_emb[d];
    else              v = emb[((size_t)c * VOCABN + x_cat[b * NCATS + c]) * INDIVE + (d - SHARED_E)];
    xflat[(size_t)b * FLATN + r] = v;
}

// ---------------- cont projection: xflat[:, 1024:1040] ----------------
__global__ __launch_bounds__(256) void cont_proj(
    const float* __restrict__ x_cont, const float* __restrict__ cw,
    const float* __restrict__ cb, float* __restrict__ xflat)
{
    int idx = blockIdx.x * 256 + threadIdx.x;      // mc*16 total
    int b = idx >> 4, j = idx & 15;
    float acc = cb[j];
#pragma unroll
    for (int k = 0; k < 16; ++k) acc += x_cont[b * 16 + k] * cw[k * 16 + j];
    xflat[(size_t)b * FLATN + 1024 + j] = acc;
}

// ---------------- micro encoder: 2 tokens, 1 wave / sample ----------------
__global__ __launch_bounds__(64) void micro_enc(
    float* __restrict__ xflat,
    const float* __restrict__ qkv_w, const float* __restrict__ out_w,
    const float* __restrict__ ln1w, const float* __restrict__ ln1b,
    const float* __restrict__ ln2w, const float* __restrict__ ln2b,
    const float* __restrict__ w1, const float* __restrict__ b1,
    const float* __restrict__ w2, const float* __restrict__ b2)
{
    int b = blockIdx.x;
    int lane = threadIdx.x;
    __shared__ float X[2][64], XN[2][64], QKV[2][192], OO[2][64], FF[2][256];
    __shared__ float PREV[16], ATTN[16];

    float* xrow = xflat + (size_t)b * FLATN;
    X[0][lane] = xrow[lane];
    X[1][lane] = xrow[64 + lane];
    if (lane < 16) PREV[lane] = 0.f;
    __syncthreads();

    for (int p = 0; p < 2; ++p) {
        const float* qw  = qkv_w + p * 64 * 192;
        const float* ow  = out_w + p * 64 * 64;
        const float* l1w = ln1w + p * 64; const float* l1b = ln1b + p * 64;
        const float* l2w = ln2w + p * 64; const float* l2b = ln2b + p * 64;
        const float* fw1 = w1 + p * 64 * 256; const float* fb1 = b1 + p * 256;
        const float* fw2 = w2 + p * 256 * 64; const float* fb2 = b2 + p * 64;

#pragma unroll
        for (int t = 0; t < 2; ++t) {
            float v = X[t][lane];
            float m = wsum(v) * (1.f / 64.f);
            float d = v - m;
            float var = wsum(d * d) * (1.f / 64.f);
            XN[t][lane] = d * rsqrtf(var + EPSV) * l1w[lane] + l1b[lane];
        }
        __syncthreads();

        for (int cc = 0; cc < 3; ++cc) {
            int c = lane + cc * 64;
            float a0 = 0.f, a1 = 0.f;
            for (int k = 0; k < 64; k += 4) {
                float wv[4];
#pragma unroll
                for (int u = 0; u < 4; ++u) wv[u] = qw[(k + u) * 192 + c];
#pragma unroll
                for (int u = 0; u < 4; ++u) { a0 += XN[0][k + u] * wv[u]; a1 += XN[1][k + u] * wv[u]; }
            }
            QKV[0][c] = a0; QKV[1][c] = a1;
        }
        __syncthreads();

        if (lane < 16) {
            int h = lane >> 2, i = (lane >> 1) & 1, j = lane & 1;
            float s = 0.f;
#pragma unroll
            for (int d = 0; d < 16; ++d)
                s += QKV[i][h * 16 + d] * QKV[j][64 + h * 16 + d];
            s = s * 0.25f + PREV[lane];
            PREV[lane] = s;
        }
        __syncthreads();
        if (lane < 16) {
            int base = lane & ~1;
            float s0 = PREV[base], s1 = PREV[base + 1];
            float mx = fmaxf(s0, s1);
            float e0 = expf(s0 - mx), e1 = expf(s1 - mx);
            float inv = 1.f / (e0 + e1);
            ATTN[lane] = (lane & 1) ? e1 * inv : e0 * inv;
        }
        __syncthreads();

        {
            int h = lane >> 4;
#pragma unroll
            for (int t = 0; t < 2; ++t)
                OO[t][lane] = ATTN[h * 4 + t * 2 + 0] * QKV[0][128 + lane]
                            + ATTN[h * 4 + t * 2 + 1] * QKV[1][128 + lane];
        }
        __syncthreads();

        {
            float a0 = 0.f, a1 = 0.f;
            for (int k = 0; k < 64; k += 4) {
                float wv[4];
#pragma unroll
                for (int u = 0; u < 4; ++u) wv[u] = ow[(k + u) * 64 + lane];
#pragma unroll
                for (int u = 0; u < 4; ++u) { a0 += OO[0][k + u] * wv[u]; a1 += OO[1][k + u] * wv[u]; }
            }
            X[0][lane] += a0; X[1][lane] += a1;
        }
        __syncthreads();

#pragma unroll
        for (int t = 0; t < 2; ++t) {
            float v = X[t][lane];
            float m = wsum(v) * (1.f / 64.f);
            float d = v - m;
            float var = wsum(d * d) * (1.f / 64.f);
            XN[t][lane] = d * rsqrtf(var + EPSV) * l2w[lane] + l2b[lane];
        }
        __syncthreads();

        for (int cc = 0; cc < 4; ++cc) {
            int c = lane + cc * 64;
            float a0 = fb1[c], a1 = fb1[c];
            for (int k = 0; k < 64; k += 4) {
                float wv[4];
#pragma unroll
                for (int u = 0; u < 4; ++u) wv[u] = fw1[(k + u) * 256 + c];
#pragma unroll
                for (int u = 0; u < 4; ++u) { a0 += XN[0][k + u] * wv[u]; a1 += XN[1][k + u] * wv[u]; }
            }
            FF[0][c] = gelu_f(a0); FF[1][c] = gelu_f(a1);
        }
        __syncthreads();

        {
            float a0 = fb2[lane], a1 = fb2[lane];
            for (int k = 0; k < 256; k += 4) {
                float wv[4];
#pragma unroll
                for (int u = 0; u < 4; ++u) wv[u] = fw2[(k + u) * 64 + lane];
#pragma unroll
                for (int u = 0; u < 4; ++u) { a0 += FF[0][k + u] * wv[u]; a1 += FF[1][k + u] * wv[u]; }
            }
            X[0][lane] += a0; X[1][lane] += a1;
        }
        __syncthreads();
    }

    xrow[lane]      = X[0][lane];
    xrow[64 + lane] = X[1][lane];
}

// ---------------- macro encoder: 16 tokens, 256 threads / sample ----------------
__global__ __launch_bounds__(256) void macro_enc(
    float* __restrict__ xflat,
    const float* __restrict__ qkv_w, const float* __restrict__ out_w,
    const float* __restrict__ ln1w, const float* __restrict__ ln1b,
    const float* __restrict__ ln2w, const float* __restrict__ ln2b,
    const float* __restrict__ w1, const float* __restrict__ b1,
    const float* __restrict__ w2, const float* __restrict__ b2)
{
    int b = blockIdx.x;
    int tid = threadIdx.x;
    int lane = tid & 63, w = tid >> 6;

    __shared__ float X[16][64], XN[16][64], QKV[16][192], OO[16][64], FF[16][256];
    __shared__ float PREV[4][16][16], ATTN[4][16][16];

    float* xrow = xflat + (size_t)b * FLATN;
#pragma unroll
    for (int i = 0; i < 4; ++i) {
        int e = tid + i * 256;
        X[e >> 6][e & 63] = xrow[e];
        ((float*)PREV)[e] = 0.f;
    }
    __syncthreads();

    for (int p = 0; p < 2; ++p) {
        const float* qw  = qkv_w + p * 64 * 192;
        const float* ow  = out_w + p * 64 * 64;
        const float* l1w = ln1w + p * 64; const float* l1b = ln1b + p * 64;
        const float* l2w = ln2w + p * 64; const float* l2b = ln2b + p * 64;
        const float* fw1 = w1 + p * 64 * 256; const float* fb1 = b1 + p * 256;
        const float* fw2 = w2 + p * 256 * 64; const float* fb2 = b2 + p * 64;

#pragma unroll
        for (int i = 0; i < 4; ++i) {
            int r = w + 4 * i;
            float v = X[r][lane];
            float m = wsum(v) * (1.f / 64.f);
            float d = v - m;
            float var = wsum(d * d) * (1.f / 64.f);
            XN[r][lane] = d * rsqrtf(var + EPSV) * l1w[lane] + l1b[lane];
        }
        __syncthreads();

        if (tid < 192) {
            int c = tid;
            float acc[16];
#pragma unroll
            for (int t = 0; t < 16; ++t) acc[t] = 0.f;
            for (int k = 0; k < 64; k += 4) {
                float wv[4];
#pragma unroll
                for (int u = 0; u < 4; ++u) wv[u] = qw[(k + u) * 192 + c];
#pragma unroll
                for (int t = 0; t < 16; ++t) {
#pragma unroll
                    for (int u = 0; u < 4; ++u) acc[t] += XN[t][k + u] * wv[u];
                }
            }
#pragma unroll
            for (int t = 0; t < 16; ++t) QKV[t][c] = acc[t];
        }
        __syncthreads();

#pragma unroll
        for (int i = 0; i < 4; ++i) {
            int e = tid + i * 256;
            int h = e >> 8, rem = e & 255, qi = rem >> 4, j = rem & 15;
            float s = 0.f;
#pragma unroll
            for (int d = 0; d < 16; ++d)
                s += QKV[qi][h * 16 + d] * QKV[j][64 + h * 16 + d];
            s = s * 0.25f + PREV[h][qi][j];
            PREV[h][qi][j] = s;
        }
        __syncthreads();

        if (tid < 64) {
            int h = tid >> 4, qi = tid & 15;
            float mx = -1e30f;
#pragma unroll
            for (int j = 0; j < 16; ++j) mx = fmaxf(mx, PREV[h][qi][j]);
            float sum = 0.f;
#pragma unroll
            for (int j = 0; j < 16; ++j) {
                float e = expf(PREV[h][qi][j] - mx);
                ATTN[h][qi][j] = e;
                sum += e;
            }
            float inv = 1.f / sum;
#pragma unroll
            for (int j = 0; j < 16; ++j) ATTN[h][qi][j] *= inv;
        }
        __syncthreads();

        {
            int h = lane >> 4;
#pragma unroll
            for (int i = 0; i < 4; ++i) {
                int r = w + 4 * i;
                float acc = 0.f;
#pragma unroll
                for (int j = 0; j < 16; ++j) acc += ATTN[h][r][j] * QKV[j][128 + lane];
                OO[r][lane] = acc;
            }
        }
        __syncthreads();

        {
            float acc[4] = {0.f, 0.f, 0.f, 0.f};
            for (int k = 0; k < 64; k += 4) {
                float wv[4];
#pragma unroll
                for (int u = 0; u < 4; ++u) wv[u] = ow[(k + u) * 64 + lane];
#pragma unroll
                for (int i = 0; i < 4; ++i) {
                    int r = w + 4 * i;
#pragma unroll
                    for (int u = 0; u < 4; ++u) acc[i] += OO[r][k + u] * wv[u];
                }
            }
#pragma unroll
            for (int i = 0; i < 4; ++i) X[w + 4 * i][lane] += acc[i];
        }
        __syncthreads();

#pragma unroll
        for (int i = 0; i < 4; ++i) {
            int r = w + 4 * i;
            float v = X[r][lane];
            float m = wsum(v) * (1.f / 64.f);
            float d = v - m;
            float var = wsum(d * d) * (1.f / 64.f);
            XN[r][lane] = d * rsqrtf(var + EPSV) * l2w[lane] + l2b[lane];
        }
        __syncthreads();

        {
            int c = tid;
            float acc[16];
#pragma unroll
            for (int t = 0; t < 16; ++t) acc[t] = fb1[c];
            for (int k = 0; k < 64; k += 4) {
                float wv[4];
#pragma unroll
                for (int u = 0; u < 4; ++u) wv[u] = fw1[(k + u) * 256 + c];
#pragma unroll
                for (int t = 0; t < 16; ++t) {
#pragma unroll
                    for (int u = 0; u < 4; ++u) acc[t] += XN[t][k + u] * wv[u];
                }
            }
#pragma unroll
            for (int t = 0; t < 16; ++t) FF[t][c] = gelu_f(acc[t]);
        }
        __syncthreads();

        {
            float acc[4];
#pragma unroll
            for (int i = 0; i < 4; ++i) acc[i] = fb2[lane];
            for (int k = 0; k < 256; k += 4) {
                float wv[4];
#pragma unroll
                for (int u = 0; u < 4; ++u) wv[u] = fw2[(k + u) * 64 + lane];
#pragma unroll
                for (int i = 0; i < 4; ++i) {
                    int r = w + 4 * i;
#pragma unroll
                    for (int u = 0; u < 4; ++u) acc[i] += FF[r][k + u] * wv[u];
                }
            }
#pragma unroll
            for (int i = 0; i < 4; ++i) X[w + 4 * i][lane] += acc[i];
        }
        __syncthreads();
    }

#pragma unroll
    for (int i = 0; i < 4; ++i) {
        int e = tid + i * 256;
        xrow[e] = X[e >> 6][e & 63];
    }
}

// ---------------- fp32 -> bf16 with K padding: A[M][K] -> Abf[M][Kp] ----------------
__global__ __launch_bounds__(256) void conv_bf16_pad(
    const float* __restrict__ src, __hip_bfloat16* __restrict__ dst, int K, int Kp)
{
    size_t idx = (size_t)blockIdx.x * 256 + threadIdx.x;   // M*Kp total
    int k = (int)(idx % Kp);
    size_t row = idx / Kp;
    float v = (k < K) ? src[row * K + k] : 0.f;
    dst[idx] = __float2bfloat16(v);
}

// ---------------- transpose + convert: W[K][N] fp32 -> Wt[Np][Kp] bf16 (zero-padded) ----
__global__ __launch_bounds__(256) void transpose_conv(
    const float* __restrict__ src, __hip_bfloat16* __restrict__ dst,
    int K, int N, int Kp, int Np)
{
    __shared__ float T[32][33];
    int k0 = blockIdx.y * 32, n0 = blockIdx.x * 32;
    int tn = threadIdx.x & 31, tk = threadIdx.x >> 5;  // tk 0..7
#pragma unroll
    for (int r = 0; r < 4; ++r) {
        int k = k0 + tk + r * 8, n = n0 + tn;
        T[tk + r * 8][tn] = (k < K && n < N) ? src[(size_t)k * N + n] : 0.f;
    }
    __syncthreads();
#pragma unroll
    for (int r = 0; r < 4; ++r) {
        int n = n0 + tk + r * 8, k = k0 + tn;
        dst[(size_t)n * Kp + k] = __float2bfloat16(T[tn][tk + r * 8]);
    }
}

// ---------------- bf16 MFMA GEMM: C = gelu(A @ Bt^T + bias) ----------------
// A: [M][Kp] bf16 row-major; Bt: [Np][Kp] bf16 row-major (= W^T).
// Tile 128x128x64, 4 waves, each wave 64x64 via 4x4 frags of 16x16x32 MFMA.
__global__ __launch_bounds__(256) void gemm_mfma(
    const __hip_bfloat16* __restrict__ A, const __hip_bfloat16* __restrict__ Bt,
    const float* __restrict__ bias, int bias_n,
    void* __restrict__ Cout, int Np, int Kp, int store_n, int store_bf16)
{
    __shared__ short Als[128 * 64];   // [row][k] linear, 16KB
    __shared__ short Bls[128 * 64];

    int tid = threadIdx.x;
    int lane = tid & 63, wave = tid >> 6;

    // bijective XCD swizzle (m204)
    int nbx = gridDim.x;
    int nwg = nbx * gridDim.y;
    int wgid = blockIdx.y * nbx + blockIdx.x;
    int q = nwg >> 3, r = nwg & 7;
    int xcd = wgid & 7, loc = wgid >> 3;
    int sw = (xcd < r ? xcd * (q + 1) : r * (q + 1) + (xcd - r) * q) + loc;
    int bm = (sw / nbx) * 128, bn = (sw % nbx) * 128;

    int rbase = tid >> 3, kp8 = (tid & 7) * 8;
    const __hip_bfloat16* Ab = A  + (size_t)(bm + rbase) * Kp + kp8;
    const __hip_bfloat16* Bb = Bt + (size_t)(bn + rbase) * Kp + kp8;

    f32x4 acc[4][4] = {};

    int4 ar[4], br[4];
#pragma unroll
    for (int it = 0; it < 4; ++it) {
        ar[it] = *(const int4*)(Ab + (size_t)it * 32 * Kp);
        br[it] = *(const int4*)(Bb + (size_t)it * 32 * Kp);
    }

    int wm = (wave >> 1) * 64, wn = (wave & 1) * 64;
    int lrow = lane & 15, lk = lane >> 4;
    const short* Af = Als + (wm + lrow) * 64 + lk * 8;
    const short* Bf = Bls + (wn + lrow) * 64 + lk * 8;

    for (int k0 = 0; k0 < Kp; k0 += 64) {
        __syncthreads();   // prev tile consumed
#pragma unroll
        for (int it = 0; it < 4; ++it) {
            int u = (it * 256 + tid) * 8;
            *(int4*)&Als[u] = ar[it];
            *(int4*)&Bls[u] = br[it];
        }
        __syncthreads();

        if (k0 + 64 < Kp) {
#pragma unroll
            for (int it = 0; it < 4; ++it) {
                ar[it] = *(const int4*)(Ab + (size_t)it * 32 * Kp + k0 + 64);
                br[it] = *(const int4*)(Bb + (size_t)it * 32 * Kp + k0 + 64);
            }
        }

#pragma unroll
        for (int ks = 0; ks < 2; ++ks) {
            bf16x8 af[4], bf[4];
#pragma unroll
            for (int i = 0; i < 4; ++i) af[i] = *(const bf16x8*)(Af + i * 16 * 64 + ks * 32);
#pragma unroll
            for (int j = 0; j < 4; ++j) bf[j] = *(const bf16x8*)(Bf + j * 16 * 64 + ks * 32);
#pragma unroll
            for (int i = 0; i < 4; ++i)
#pragma unroll
                for (int j = 0; j < 4; ++j)
                    acc[i][j] = __builtin_amdgcn_mfma_f32_16x16x32_bf16(af[i], bf[j], acc[i][j], 0, 0, 0);
        }
    }

    // epilogue: row = bm+wm+i*16+4*lk+rr, col = bn+wn+j*16+lrow  (m89/m91 C/D mapping)
    int orow = bm + wm + 4 * lk;
    int ocol = bn + wn + lrow;
    if (store_bf16) {
        __hip_bfloat16* C = (__hip_bfloat16*)Cout;
#pragma unroll
        for (int j = 0; j < 4; ++j) {
            int col = ocol + j * 16;
            float bv = (col < bias_n) ? bias[col] : 0.f;
#pragma unroll
            for (int i = 0; i < 4; ++i) {
                int row = orow + i * 16;
#pragma unroll
                for (int rr = 0; rr < 4; ++rr)
                    C[(size_t)(row + rr) * Np + col] = __float2bfloat16(gelu_f(acc[i][j][rr] + bv));
            }
        }
    } else {
        float* C = (float*)Cout;
#pragma unroll
        for (int j = 0; j < 4; ++j) {
            int col = ocol + j * 16;
            if (col < store_n) {
                float bv = (col < bias_n) ? bias[col] : 0.f;
#pragma unroll
                for (int i = 0; i < 4; ++i) {
                    int row = orow + i * 16;
#pragma unroll
                    for (int rr = 0; rr < 4; ++rr)
                        C[(size_t)(row + rr) * store_n + col] = gelu_f(acc[i][j][rr] + bv);
                }
            }
        }
    }
}

// ---------------- final dot: logits = h2 @ w3 + b3 ----------------
__global__ __launch_bounds__(256) void final_dot(
    const float* __restrict__ h2, const float* __restrict__ w3,
    const float* __restrict__ b3, float* __restrict__ out)
{
    int b = blockIdx.x;
    int tid = threadIdx.x;
    float acc = 0.f;
    for (int k = tid; k < H2N; k += 256) acc += h2[(size_t)b * H2N + k] * w3[k];
    acc = wsum(acc);
    __shared__ float s[4];
    if ((tid & 63) == 0) s[tid >> 6] = acc;
    __syncthreads();
    if (tid == 0) out[b] = s[0] + s[1] + s[2] + s[3] + b3[0];
}

extern "C" void kernel_launch(void* const* d_in, const int* in_sizes, int n_in,
                              void* d_out, int out_size, void* d_ws, size_t ws_size,
                              hipStream_t stream)
{
    const int*   x_cat      = (const int*)  d_in[0];
    const float* x_cont     = (const float*)d_in[1];
    const float* shared_emb = (const float*)d_in[2];
    const float* emb        = (const float*)d_in[3];
    const float* mi_qkv  = (const float*)d_in[4];
    const float* mi_out  = (const float*)d_in[5];
    const float* mi_ln1w = (const float*)d_in[6];
    const float* mi_ln1b = (const float*)d_in[7];
    const float* mi_ln2w = (const float*)d_in[8];
    const float* mi_ln2b = (const float*)d_in[9];
    const float* mi_w1   = (const float*)d_in[10];
    const float* mi_b1   = (const float*)d_in[11];
    const float* mi_w2   = (const float*)d_in[12];
    const float* mi_b2   = (const float*)d_in[13];
    const float* ma_qkv  = (const float*)d_in[14];
    const float* ma_out  = (const float*)d_in[15];
    const float* ma_ln1w = (const float*)d_in[16];
    const float* ma_ln1b = (const float*)d_in[17];
    const float* ma_ln2w = (const float*)d_in[18];
    const float* ma_ln2b = (const float*)d_in[19];
    const float* ma_w1   = (const float*)d_in[20];
    const float* ma_b1   = (const float*)d_in[21];
    const float* ma_w2   = (const float*)d_in[22];
    const float* ma_b2   = (const float*)d_in[23];
    const float* cont_w  = (const float*)d_in[24];
    const float* cont_b  = (const float*)d_in[25];
    const float* w1      = (const float*)d_in[26];
    const float* b1      = (const float*)d_in[27];
    const float* w2      = (const float*)d_in[28];
    const float* b2      = (const float*)d_in[29];
    const float* w3      = (const float*)d_in[30];
    const float* b3      = (const float*)d_in[31];
    float* out = (float*)d_out;

    // ---- workspace budget (evidence: round-1 477MB crash, round-2 chunked pass,
    // round-3 406MB crash => ws_size ~ 384MB). Be chunk-adaptive; alias phases:
    //   buf1 (per-chunk): h1   [CH][NP1] bf16          = CH*8448 B
    //   buf2 (per-chunk): xflat[CH][FLATN] f32 + Abf[CH][KP1] bf16   (phase A/B)
    //                     h2   [CH][H2N] f32           (phase C/D, overwrites)
    //                     per-row = max(4160+2176, 8320) = 8320 B
    // fixed: w1T (9.2MB) + w2T (18.4MB). per-row total = 16768 B.
    const size_t FIXED = ((size_t)NP1 * KP1 + (size_t)NP2 * KP2) * sizeof(__hip_bfloat16);
    const size_t PER_ROW = (size_t)NP1 * 2 + (size_t)H2N * 4;   // 8448 + 8320
    size_t avail = (ws_size > FIXED) ? ws_size - FIXED : 0;
    long long chl = (long long)(avail / PER_ROW);
    int CH = (int)((chl / 128) * 128);
    if (CH > BATCH) CH = BATCH;
    if (CH < 128) CH = 128;   // nothing sane fits below this; fault loudly

    char* p = (char*)d_ws;
    __hip_bfloat16* w1T = (__hip_bfloat16*)p; p += (size_t)NP1 * KP1 * 2;
    __hip_bfloat16* w2T = (__hip_bfloat16*)p; p += (size_t)NP2 * KP2 * 2;
    __hip_bfloat16* h1  = (__hip_bfloat16*)p; p += (size_t)CH * NP1 * 2;
    char* buf2 = p;
    float* xflat = (float*)buf2;                                     // CH*1040 f32
    __hip_bfloat16* Abf = (__hip_bfloat16*)(buf2 + (size_t)CH * FLATN * 4); // CH*1088 bf16
    float* h2 = (float*)buf2;                                        // CH*2080 f32 (aliases)

    transpose_conv<<<dim3(NP1 / 32, KP1 / 32), 256, 0, stream>>>(w1, w1T, FLATN, H1N, KP1, NP1);
    transpose_conv<<<dim3(NP2 / 32, KP2 / 32), 256, 0, stream>>>(w2, w2T, H1N, H2N, KP2, NP2);

    for (int m0 = 0; m0 < BATCH; m0 += CH) {
        int mc = BATCH - m0 < CH ? BATCH - m0 : CH;   // multiple of 128

        build_tokens<<<(mc * 1024) / 256, 256, 0, stream>>>(
            x_cat + (size_t)m0 * NCATS, shared_emb, emb, xflat);
        cont_proj<<<(mc * 16) / 256, 256, 0, stream>>>(
            x_cont + (size_t)m0 * CONTN, cont_w, cont_b, xflat);
        micro_enc<<<mc, 64, 0, stream>>>(xflat, mi_qkv, mi_out, mi_ln1w, mi_ln1b,
                                         mi_ln2w, mi_ln2b, mi_w1, mi_b1, mi_w2, mi_b2);
        macro_enc<<<mc, 256, 0, stream>>>(xflat, ma_qkv, ma_out, ma_ln1w, ma_ln1b,
                                          ma_ln2w, ma_ln2b, ma_w1, ma_b1, ma_w2, ma_b2);

        conv_bf16_pad<<<(int)(((size_t)mc * KP1) / 256), 256, 0, stream>>>(
            xflat, Abf, FLATN, KP1);

        gemm_mfma<<<dim3(NP1 / 128, mc / 128), 256, 0, stream>>>(
            Abf, w1T, b1, H1N, h1, NP1, KP1, 0, 1);
        gemm_mfma<<<dim3(NP2 / 128, mc / 128), 256, 0, stream>>>(
            h1, w2T, b2, H2N, h2, NP2, KP2, H2N, 0);

        final_dot<<<mc, 256, 0, stream>>>(h2, w3, b3, out + m0);
    }
}

// Round 5
// 4135.860 us; speedup vs baseline: 2.2648x; 1.2436x over previous
//
#include <hip/hip_runtime.h>
#include <hip/hip_bf16.h>
#include <math.h>

#define BATCH  16384
#define NCATS  16
#define VOCABN 1000
#define DIMD   64
#define SHARED_E 10
#define INDIVE 54
#define CONTN  16
#define FLATN  1040   // NCATS*DIMD + CONTN
#define H1N    4160
#define H2N    2080
#define KP1    1088   // FLATN padded to mult of 64
#define NP1    4224   // H1N padded to mult of 128
#define KP2    4224   // = NP1 (GEMM2 K)
#define NP2    2176   // H2N padded to mult of 128
#define EPSV   1e-5f

typedef __attribute__((ext_vector_type(8))) short bf16x8;
typedef __attribute__((ext_vector_type(4))) float f32x4;

__device__ __forceinline__ float gelu_f(float x) {
    return 0.5f * x * (1.0f + erff(x * 0.70710678118654752440f));
}
__device__ __forceinline__ float wsum(float v) {
#pragma unroll
    for (int o = 32; o > 0; o >>= 1) v += __shfl_xor(v, o, 64);
    return v;
}
__device__ __forceinline__ short f2bf_s(float a) {
    __hip_bfloat16 x = __float2bfloat16(a);
    return *reinterpret_cast<short*>(&x);
}
__device__ __forceinline__ unsigned int packbf(float a, float b) {
    __hip_bfloat16 x = __float2bfloat16(a), y = __float2bfloat16(b);
    unsigned short ux = *reinterpret_cast<unsigned short*>(&x);
    unsigned short uy = *reinterpret_cast<unsigned short*>(&y);
    return (unsigned)ux | ((unsigned)uy << 16);
}

// ---------------- token build: xflat[:, 0:1024] (chunk-local rows) ----------------
__global__ __launch_bounds__(256) void build_tokens(
    const int* __restrict__ x_cat, const float* __restrict__ shared_emb,
    const float* __restrict__ emb, float* __restrict__ xflat)
{
    int idx = blockIdx.x * 256 + threadIdx.x;      // mc*1024 total
    int b = idx >> 10, r = idx & 1023;
    int c = r >> 6, d = r & 63;
    float v;
    if (d < SHARED_E) v = shared_emb[d];
    else              v = emb[((size_t)c * VOCABN + x_cat[b * NCATS + c]) * INDIVE + (d - SHARED_E)];
    xflat[(size_t)b * FLATN + r] = v;
}

// ---------------- cont projection: xflat[:, 1024:1040] ----------------
__global__ __launch_bounds__(256) void cont_proj(
    const float* __restrict__ x_cont, const float* __restrict__ cw,
    const float* __restrict__ cb, float* __restrict__ xflat)
{
    int idx = blockIdx.x * 256 + threadIdx.x;      // mc*16 total
    int b = idx >> 4, j = idx & 15;
    float acc = cb[j];
#pragma unroll
    for (int k = 0; k < 16; ++k) acc += x_cont[b * 16 + k] * cw[k * 16 + j];
    xflat[(size_t)b * FLATN + 1024 + j] = acc;
}

// ---------------- micro encoder: 2 tokens, 1 wave / sample ----------------
__global__ __launch_bounds__(64) void micro_enc(
    float* __restrict__ xflat,
    const float* __restrict__ qkv_w, const float* __restrict__ out_w,
    const float* __restrict__ ln1w, const float* __restrict__ ln1b,
    const float* __restrict__ ln2w, const float* __restrict__ ln2b,
    const float* __restrict__ w1, const float* __restrict__ b1,
    const float* __restrict__ w2, const float* __restrict__ b2)
{
    int b = blockIdx.x;
    int lane = threadIdx.x;
    __shared__ float X[2][64], XN[2][64], QKV[2][192], OO[2][64], FF[2][256];
    __shared__ float PREV[16], ATTN[16];

    float* xrow = xflat + (size_t)b * FLATN;
    X[0][lane] = xrow[lane];
    X[1][lane] = xrow[64 + lane];
    if (lane < 16) PREV[lane] = 0.f;
    __syncthreads();

    for (int p = 0; p < 2; ++p) {
        const float* qw  = qkv_w + p * 64 * 192;
        const float* ow  = out_w + p * 64 * 64;
        const float* l1w = ln1w + p * 64; const float* l1b = ln1b + p * 64;
        const float* l2w = ln2w + p * 64; const float* l2b = ln2b + p * 64;
        const float* fw1 = w1 + p * 64 * 256; const float* fb1 = b1 + p * 256;
        const float* fw2 = w2 + p * 256 * 64; const float* fb2 = b2 + p * 64;

#pragma unroll
        for (int t = 0; t < 2; ++t) {
            float v = X[t][lane];
            float m = wsum(v) * (1.f / 64.f);
            float d = v - m;
            float var = wsum(d * d) * (1.f / 64.f);
            XN[t][lane] = d * rsqrtf(var + EPSV) * l1w[lane] + l1b[lane];
        }
        __syncthreads();

        for (int cc = 0; cc < 3; ++cc) {
            int c = lane + cc * 64;
            float a0 = 0.f, a1 = 0.f;
            for (int k = 0; k < 64; k += 4) {
                float wv[4];
#pragma unroll
                for (int u = 0; u < 4; ++u) wv[u] = qw[(k + u) * 192 + c];
#pragma unroll
                for (int u = 0; u < 4; ++u) { a0 += XN[0][k + u] * wv[u]; a1 += XN[1][k + u] * wv[u]; }
            }
            QKV[0][c] = a0; QKV[1][c] = a1;
        }
        __syncthreads();

        if (lane < 16) {
            int h = lane >> 2, i = (lane >> 1) & 1, j = lane & 1;
            float s = 0.f;
#pragma unroll
            for (int d = 0; d < 16; ++d)
                s += QKV[i][h * 16 + d] * QKV[j][64 + h * 16 + d];
            s = s * 0.25f + PREV[lane];
            PREV[lane] = s;
        }
        __syncthreads();
        if (lane < 16) {
            int base = lane & ~1;
            float s0 = PREV[base], s1 = PREV[base + 1];
            float mx = fmaxf(s0, s1);
            float e0 = expf(s0 - mx), e1 = expf(s1 - mx);
            float inv = 1.f / (e0 + e1);
            ATTN[lane] = (lane & 1) ? e1 * inv : e0 * inv;
        }
        __syncthreads();

        {
            int h = lane >> 4;
#pragma unroll
            for (int t = 0; t < 2; ++t)
                OO[t][lane] = ATTN[h * 4 + t * 2 + 0] * QKV[0][128 + lane]
                            + ATTN[h * 4 + t * 2 + 1] * QKV[1][128 + lane];
        }
        __syncthreads();

        {
            float a0 = 0.f, a1 = 0.f;
            for (int k = 0; k < 64; k += 4) {
                float wv[4];
#pragma unroll
                for (int u = 0; u < 4; ++u) wv[u] = ow[(k + u) * 64 + lane];
#pragma unroll
                for (int u = 0; u < 4; ++u) { a0 += OO[0][k + u] * wv[u]; a1 += OO[1][k + u] * wv[u]; }
            }
            X[0][lane] += a0; X[1][lane] += a1;
        }
        __syncthreads();

#pragma unroll
        for (int t = 0; t < 2; ++t) {
            float v = X[t][lane];
            float m = wsum(v) * (1.f / 64.f);
            float d = v - m;
            float var = wsum(d * d) * (1.f / 64.f);
            XN[t][lane] = d * rsqrtf(var + EPSV) * l2w[lane] + l2b[lane];
        }
        __syncthreads();

        for (int cc = 0; cc < 4; ++cc) {
            int c = lane + cc * 64;
            float a0 = fb1[c], a1 = fb1[c];
            for (int k = 0; k < 64; k += 4) {
                float wv[4];
#pragma unroll
                for (int u = 0; u < 4; ++u) wv[u] = fw1[(k + u) * 256 + c];
#pragma unroll
                for (int u = 0; u < 4; ++u) { a0 += XN[0][k + u] * wv[u]; a1 += XN[1][k + u] * wv[u]; }
            }
            FF[0][c] = gelu_f(a0); FF[1][c] = gelu_f(a1);
        }
        __syncthreads();

        {
            float a0 = fb2[lane], a1 = fb2[lane];
            for (int k = 0; k < 256; k += 4) {
                float wv[4];
#pragma unroll
                for (int u = 0; u < 4; ++u) wv[u] = fw2[(k + u) * 64 + lane];
#pragma unroll
                for (int u = 0; u < 4; ++u) { a0 += FF[0][k + u] * wv[u]; a1 += FF[1][k + u] * wv[u]; }
            }
            X[0][lane] += a0; X[1][lane] += a1;
        }
        __syncthreads();
    }

    xrow[lane]      = X[0][lane];
    xrow[64 + lane] = X[1][lane];
}

// ---------------- macro encoder (MFMA): 4 samples / block, wave = sample ----------------
// wT per layer: [qkvT 192x64 | outT 64x64 | ff1T 256x64 | ff2T 64x256] bf16, 49152 shorts.
__global__ __launch_bounds__(256) void macro_enc_mfma(
    float* __restrict__ xflat, const short* __restrict__ wT,
    const float* __restrict__ ln1w, const float* __restrict__ ln1b,
    const float* __restrict__ ln2w, const float* __restrict__ ln2b,
    const float* __restrict__ b1, const float* __restrict__ b2)
{
    __shared__ float Xr[64][64];                 // residual, fp32
    __shared__ __align__(16) short XN[64][72];   // LN out / attn O (bf16, A-operand)
    __shared__ __align__(16) short KV[64][136];  // K (cols 0-63), V (cols 64-127)
    __shared__ __align__(16) short FFb[64][136]; // Q during attn; ff1-half output

    int tid = threadIdx.x;
    int lane = tid & 63, w = tid >> 6;
    int b0 = blockIdx.x * 4;

    // load residual (coalesced float4)
    {
        int r = tid >> 2, c0 = (tid & 3) * 16;
        const float* gx = xflat + (size_t)(b0 + (r >> 4)) * FLATN + (r & 15) * 64 + c0;
#pragma unroll
        for (int u = 0; u < 4; ++u) *(float4*)&Xr[r][c0 + u * 4] = *(const float4*)(gx + u * 4);
    }
    __syncthreads();

    int fr = lane & 15, fk = lane >> 4;          // MFMA fragment coords (verified mapping)
    int rb = w * 16 + 4 * fk;                    // C-frag row base within block
    float prev[16];
#pragma unroll
    for (int j = 0; j < 16; ++j) prev[j] = 0.f;

    for (int p = 0; p < 2; ++p) {
        const short* lq  = wT + p * 49152;
        const short* lo  = lq + 12288;
        const short* lf1 = lo + 4096;
        const short* lf2 = lf1 + 16384;
        const float* l1w = ln1w + p * 64; const float* l1b = ln1b + p * 64;
        const float* l2w = ln2w + p * 64; const float* l2b = ln2b + p * 64;
        const float* fb1 = b1 + p * 256;  const float* fb2 = b2 + p * 64;

        // ---- LN1 -> XN (bf16) ----
        {
            float wv = l1w[lane], bv = l1b[lane];
#pragma unroll
            for (int i = 0; i < 16; ++i) {
                int r = w * 16 + i;
                float v = Xr[r][lane];
                float m = wsum(v) * (1.f / 64.f);
                float d = v - m;
                float var = wsum(d * d) * (1.f / 64.f);
                XN[r][lane] = f2bf_s(d * rsqrtf(var + EPSV) * wv + bv);
            }
        }
        __syncthreads();

        // ---- qkv MFMA: N=192. nf 0-3 -> Q (FFb), nf 4-11 -> K,V (KV) ----
        {
            bf16x8 a0 = *(const bf16x8*)&XN[w * 16 + fr][fk * 8];
            bf16x8 a1 = *(const bf16x8*)&XN[w * 16 + fr][fk * 8 + 32];
#pragma unroll
            for (int nf = 0; nf < 12; ++nf) {
                const short* bp = lq + (nf * 16 + fr) * 64 + fk * 8;
                bf16x8 bv0 = *(const bf16x8*)bp;
                bf16x8 bv1 = *(const bf16x8*)(bp + 32);
                f32x4 acc = {};
                acc = __builtin_amdgcn_mfma_f32_16x16x32_bf16(a0, bv0, acc, 0, 0, 0);
                acc = __builtin_amdgcn_mfma_f32_16x16x32_bf16(a1, bv1, acc, 0, 0, 0);
                int cc = nf * 16 + fr;
#pragma unroll
                for (int rr = 0; rr < 4; ++rr) {
                    if (nf < 4) FFb[rb + rr][cc] = f2bf_s(acc[rr]);
                    else        KV[rb + rr][cc - 64] = f2bf_s(acc[rr]);
                }
            }
        }
        __syncthreads();

        // ---- attention: thread = (sample=w, head, qi); scores/softmax/PV in registers ----
        {
            int h = fk & 3;      // lane = h*16 + qi
            int qi = fr;
            int qrow = w * 16 + qi;
            float q[16];
            const unsigned int* qp = (const unsigned int*)&FFb[qrow][h * 16];
#pragma unroll
            for (int e = 0; e < 8; ++e) {
                unsigned int u = qp[e];
                q[2 * e]     = __uint_as_float(u << 16);
                q[2 * e + 1] = __uint_as_float(u & 0xffff0000u);
            }
            float sc[16];
#pragma unroll
            for (int j = 0; j < 16; ++j) {
                const unsigned int* kp = (const unsigned int*)&KV[w * 16 + j][h * 16];
                float a = 0.f;
#pragma unroll
                for (int e = 0; e < 8; ++e) {
                    unsigned int u = kp[e];
                    a += q[2 * e] * __uint_as_float(u << 16)
                       + q[2 * e + 1] * __uint_as_float(u & 0xffff0000u);
                }
                a = a * 0.25f + prev[j];
                prev[j] = a;
                sc[j] = a;
            }
            float mx = sc[0];
#pragma unroll
            for (int j = 1; j < 16; ++j) mx = fmaxf(mx, sc[j]);
            float sum = 0.f;
#pragma unroll
            for (int j = 0; j < 16; ++j) { sc[j] = expf(sc[j] - mx); sum += sc[j]; }
            float inv = 1.f / sum;
            float o[16];
#pragma unroll
            for (int d = 0; d < 16; ++d) o[d] = 0.f;
#pragma unroll
            for (int j = 0; j < 16; ++j) {
                float a = sc[j] * inv;
                const unsigned int* vp = (const unsigned int*)&KV[w * 16 + j][64 + h * 16];
#pragma unroll
                for (int e = 0; e < 8; ++e) {
                    unsigned int u = vp[e];
                    o[2 * e]     += a * __uint_as_float(u << 16);
                    o[2 * e + 1] += a * __uint_as_float(u & 0xffff0000u);
                }
            }
            unsigned int* op = (unsigned int*)&XN[qrow][h * 16];
#pragma unroll
            for (int e = 0; e < 8; ++e) op[e] = packbf(o[2 * e], o[2 * e + 1]);
        }
        __syncthreads();

        // ---- out proj MFMA (N=64) + residual into Xr ----
        {
            bf16x8 a0 = *(const bf16x8*)&XN[w * 16 + fr][fk * 8];
            bf16x8 a1 = *(const bf16x8*)&XN[w * 16 + fr][fk * 8 + 32];
#pragma unroll
            for (int nf = 0; nf < 4; ++nf) {
                const short* bp = lo + (nf * 16 + fr) * 64 + fk * 8;
                bf16x8 bv0 = *(const bf16x8*)bp;
                bf16x8 bv1 = *(const bf16x8*)(bp + 32);
                f32x4 acc = {};
                acc = __builtin_amdgcn_mfma_f32_16x16x32_bf16(a0, bv0, acc, 0, 0, 0);
                acc = __builtin_amdgcn_mfma_f32_16x16x32_bf16(a1, bv1, acc, 0, 0, 0);
                int cc = nf * 16 + fr;
#pragma unroll
                for (int rr = 0; rr < 4; ++rr) Xr[rb + rr][cc] += acc[rr];
            }
        }
        __syncthreads();

        // ---- LN2 -> XN ----
        {
            float wv = l2w[lane], bv = l2b[lane];
#pragma unroll
            for (int i = 0; i < 16; ++i) {
                int r = w * 16 + i;
                float v = Xr[r][lane];
                float m = wsum(v) * (1.f / 64.f);
                float d = v - m;
                float var = wsum(d * d) * (1.f / 64.f);
                XN[r][lane] = f2bf_s(d * rsqrtf(var + EPSV) * wv + bv);
            }
        }
        __syncthreads();

        // ---- FFN in two K-halves; ff2 acc held in registers ----
        {
            bf16x8 a0 = *(const bf16x8*)&XN[w * 16 + fr][fk * 8];
            bf16x8 a1 = *(const bf16x8*)&XN[w * 16 + fr][fk * 8 + 32];
            f32x4 facc[4] = {};
#pragma unroll
            for (int half = 0; half < 2; ++half) {
                // ff1: cols half*128 .. +127 -> gelu -> FFb (local cols 0-127)
#pragma unroll
                for (int nf = 0; nf < 8; ++nf) {
                    int ng = half * 128 + nf * 16;
                    const short* bp = lf1 + (ng + fr) * 64 + fk * 8;
                    bf16x8 bv0 = *(const bf16x8*)bp;
                    bf16x8 bv1 = *(const bf16x8*)(bp + 32);
                    f32x4 acc = {};
                    acc = __builtin_amdgcn_mfma_f32_16x16x32_bf16(a0, bv0, acc, 0, 0, 0);
                    acc = __builtin_amdgcn_mfma_f32_16x16x32_bf16(a1, bv1, acc, 0, 0, 0);
                    int cc = nf * 16 + fr;
                    float bias1 = fb1[ng + fr];
#pragma unroll
                    for (int rr = 0; rr < 4; ++rr)
                        FFb[rb + rr][cc] = f2bf_s(gelu_f(acc[rr] + bias1));
                }
                __syncthreads();
                // ff2 partial: K-slice half*128..+127
                bf16x8 fa[4];
#pragma unroll
                for (int kf = 0; kf < 4; ++kf)
                    fa[kf] = *(const bf16x8*)&FFb[w * 16 + fr][kf * 32 + fk * 8];
#pragma unroll
                for (int nf = 0; nf < 4; ++nf) {
                    const short* bp = lf2 + (nf * 16 + fr) * 256 + half * 128 + fk * 8;
#pragma unroll
                    for (int kf = 0; kf < 4; ++kf)
                        facc[nf] = __builtin_amdgcn_mfma_f32_16x16x32_bf16(
                            fa[kf], *(const bf16x8*)(bp + kf * 32), facc[nf], 0, 0, 0);
                }
                __syncthreads();
            }
            // residual + bias
#pragma unroll
            for (int nf = 0; nf < 4; ++nf) {
                int cc = nf * 16 + fr;
                float bias2 = fb2[cc];
#pragma unroll
                for (int rr = 0; rr < 4; ++rr) Xr[rb + rr][cc] += facc[nf][rr] + bias2;
            }
        }
        __syncthreads();
    }

    // store residual back
    {
        int r = tid >> 2, c0 = (tid & 3) * 16;
        float* gx = xflat + (size_t)(b0 + (r >> 4)) * FLATN + (r & 15) * 64 + c0;
#pragma unroll
        for (int u = 0; u < 4; ++u) *(float4*)(gx + u * 4) = *(const float4*)&Xr[r][c0 + u * 4];
    }
}

// ---------------- fp32 -> bf16 with K padding: A[M][K] -> Abf[M][Kp] ----------------
__global__ __launch_bounds__(256) void conv_bf16_pad(
    const float* __restrict__ src, __hip_bfloat16* __restrict__ dst, int K, int Kp)
{
    size_t idx = (size_t)blockIdx.x * 256 + threadIdx.x;   // M*Kp total
    int k = (int)(idx % Kp);
    size_t row = idx / Kp;
    float v = (k < K) ? src[row * K + k] : 0.f;
    dst[idx] = __float2bfloat16(v);
}

// ---------------- transpose + convert: W[K][N] fp32 -> Wt[Np][Kp] bf16 (zero-padded) ----
__global__ __launch_bounds__(256) void transpose_conv(
    const float* __restrict__ src, __hip_bfloat16* __restrict__ dst,
    int K, int N, int Kp, int Np)
{
    __shared__ float T[32][33];
    int k0 = blockIdx.y * 32, n0 = blockIdx.x * 32;
    int tn = threadIdx.x & 31, tk = threadIdx.x >> 5;  // tk 0..7
#pragma unroll
    for (int r = 0; r < 4; ++r) {
        int k = k0 + tk + r * 8, n = n0 + tn;
        T[tk + r * 8][tn] = (k < K && n < N) ? src[(size_t)k * N + n] : 0.f;
    }
    __syncthreads();
#pragma unroll
    for (int r = 0; r < 4; ++r) {
        int n = n0 + tk + r * 8, k = k0 + tn;
        dst[(size_t)n * Kp + k] = __float2bfloat16(T[tn][tk + r * 8]);
    }
}

// ---------------- bf16 MFMA GEMM: C = gelu(A @ Bt^T + bias) ----------------
__global__ __launch_bounds__(256) void gemm_mfma(
    const __hip_bfloat16* __restrict__ A, const __hip_bfloat16* __restrict__ Bt,
    const float* __restrict__ bias, int bias_n,
    void* __restrict__ Cout, int Np, int Kp, int store_n, int store_bf16)
{
    __shared__ short Als[128 * 64];
    __shared__ short Bls[128 * 64];

    int tid = threadIdx.x;
    int lane = tid & 63, wave = tid >> 6;

    int nbx = gridDim.x;
    int nwg = nbx * gridDim.y;
    int wgid = blockIdx.y * nbx + blockIdx.x;
    int q = nwg >> 3, r = nwg & 7;
    int xcd = wgid & 7, loc = wgid >> 3;
    int sw = (xcd < r ? xcd * (q + 1) : r * (q + 1) + (xcd - r) * q) + loc;
    int bm = (sw / nbx) * 128, bn = (sw % nbx) * 128;

    int rbase = tid >> 3, kp8 = (tid & 7) * 8;
    const __hip_bfloat16* Ab = A  + (size_t)(bm + rbase) * Kp + kp8;
    const __hip_bfloat16* Bb = Bt + (size_t)(bn + rbase) * Kp + kp8;

    f32x4 acc[4][4] = {};

    int4 ar[4], br[4];
#pragma unroll
    for (int it = 0; it < 4; ++it) {
        ar[it] = *(const int4*)(Ab + (size_t)it * 32 * Kp);
        br[it] = *(const int4*)(Bb + (size_t)it * 32 * Kp);
    }

    int wm = (wave >> 1) * 64, wn = (wave & 1) * 64;
    int lrow = lane & 15, lk = lane >> 4;
    const short* Af = Als + (wm + lrow) * 64 + lk * 8;
    const short* Bf = Bls + (wn + lrow) * 64 + lk * 8;

    for (int k0 = 0; k0 < Kp; k0 += 64) {
        __syncthreads();
#pragma unroll
        for (int it = 0; it < 4; ++it) {
            int u = (it * 256 + tid) * 8;
            *(int4*)&Als[u] = ar[it];
            *(int4*)&Bls[u] = br[it];
        }
        __syncthreads();

        if (k0 + 64 < Kp) {
#pragma unroll
            for (int it = 0; it < 4; ++it) {
                ar[it] = *(const int4*)(Ab + (size_t)it * 32 * Kp + k0 + 64);
                br[it] = *(const int4*)(Bb + (size_t)it * 32 * Kp + k0 + 64);
            }
        }

#pragma unroll
        for (int ks = 0; ks < 2; ++ks) {
            bf16x8 af[4], bf[4];
#pragma unroll
            for (int i = 0; i < 4; ++i) af[i] = *(const bf16x8*)(Af + i * 16 * 64 + ks * 32);
#pragma unroll
            for (int j = 0; j < 4; ++j) bf[j] = *(const bf16x8*)(Bf + j * 16 * 64 + ks * 32);
#pragma unroll
            for (int i = 0; i < 4; ++i)
#pragma unroll
                for (int j = 0; j < 4; ++j)
                    acc[i][j] = __builtin_amdgcn_mfma_f32_16x16x32_bf16(af[i], bf[j], acc[i][j], 0, 0, 0);
        }
    }

    int orow = bm + wm + 4 * lk;
    int ocol = bn + wn + lrow;
    if (store_bf16) {
        __hip_bfloat16* C = (__hip_bfloat16*)Cout;
#pragma unroll
        for (int j = 0; j < 4; ++j) {
            int col = ocol + j * 16;
            float bv = (col < bias_n) ? bias[col] : 0.f;
#pragma unroll
            for (int i = 0; i < 4; ++i) {
                int row = orow + i * 16;
#pragma unroll
                for (int rr = 0; rr < 4; ++rr)
                    C[(size_t)(row + rr) * Np + col] = __float2bfloat16(gelu_f(acc[i][j][rr] + bv));
            }
        }
    } else {
        float* C = (float*)Cout;
#pragma unroll
        for (int j = 0; j < 4; ++j) {
            int col = ocol + j * 16;
            if (col < store_n) {
                float bv = (col < bias_n) ? bias[col] : 0.f;
#pragma unroll
                for (int i = 0; i < 4; ++i) {
                    int row = orow + i * 16;
#pragma unroll
                    for (int rr = 0; rr < 4; ++rr)
                        C[(size_t)(row + rr) * store_n + col] = gelu_f(acc[i][j][rr] + bv);
                }
            }
        }
    }
}

// ---------------- final dot: logits = h2 @ w3 + b3 ----------------
__global__ __launch_bounds__(256) void final_dot(
    const float* __restrict__ h2, const float* __restrict__ w3,
    const float* __restrict__ b3, float* __restrict__ out)
{
    int b = blockIdx.x;
    int tid = threadIdx.x;
    float acc = 0.f;
    for (int k = tid; k < H2N; k += 256) acc += h2[(size_t)b * H2N + k] * w3[k];
    acc = wsum(acc);
    __shared__ float s[4];
    if ((tid & 63) == 0) s[tid >> 6] = acc;
    __syncthreads();
    if (tid == 0) out[b] = s[0] + s[1] + s[2] + s[3] + b3[0];
}

extern "C" void kernel_launch(void* const* d_in, const int* in_sizes, int n_in,
                              void* d_out, int out_size, void* d_ws, size_t ws_size,
                              hipStream_t stream)
{
    const int*   x_cat      = (const int*)  d_in[0];
    const float* x_cont     = (const float*)d_in[1];
    const float* shared_emb = (const float*)d_in[2];
    const float* emb        = (const float*)d_in[3];
    const float* mi_qkv  = (const float*)d_in[4];
    const float* mi_out  = (const float*)d_in[5];
    const float* mi_ln1w = (const float*)d_in[6];
    const float* mi_ln1b = (const float*)d_in[7];
    const float* mi_ln2w = (const float*)d_in[8];
    const float* mi_ln2b = (const float*)d_in[9];
    const float* mi_w1   = (const float*)d_in[10];
    const float* mi_b1   = (const float*)d_in[11];
    const float* mi_w2   = (const float*)d_in[12];
    const float* mi_b2   = (const float*)d_in[13];
    const float* ma_qkv  = (const float*)d_in[14];
    const float* ma_out  = (const float*)d_in[15];
    const float* ma_ln1w = (const float*)d_in[16];
    const float* ma_ln1b = (const float*)d_in[17];
    const float* ma_ln2w = (const float*)d_in[18];
    const float* ma_ln2b = (const float*)d_in[19];
    const float* ma_w1   = (const float*)d_in[20];
    const float* ma_b1   = (const float*)d_in[21];
    const float* ma_w2   = (const float*)d_in[22];
    const float* ma_b2   = (const float*)d_in[23];
    const float* cont_w  = (const float*)d_in[24];
    const float* cont_b  = (const float*)d_in[25];
    const float* w1      = (const float*)d_in[26];
    const float* b1      = (const float*)d_in[27];
    const float* w2      = (const float*)d_in[28];
    const float* b2      = (const float*)d_in[29];
    const float* w3      = (const float*)d_in[30];
    const float* b3      = (const float*)d_in[31];
    float* out = (float*)d_out;

    // fixed ws: w1T + w2T + macro encoder transposed weights (2 layers x 49152 shorts)
    const size_t ENC_SH = 2 * 49152;     // shorts
    const size_t FIXED = ((size_t)NP1 * KP1 + (size_t)NP2 * KP2 + ENC_SH) * sizeof(__hip_bfloat16);
    const size_t PER_ROW = (size_t)NP1 * 2 + (size_t)H2N * 4;   // 8448 + 8320
    size_t avail = (ws_size > FIXED) ? ws_size - FIXED : 0;
    long long chl = (long long)(avail / PER_ROW);
    int CH = (int)((chl / 128) * 128);
    if (CH > BATCH) CH = BATCH;
    if (CH < 128) CH = 128;

    char* p = (char*)d_ws;
    __hip_bfloat16* w1T = (__hip_bfloat16*)p; p += (size_t)NP1 * KP1 * 2;
    __hip_bfloat16* w2T = (__hip_bfloat16*)p; p += (size_t)NP2 * KP2 * 2;
    __hip_bfloat16* encT = (__hip_bfloat16*)p; p += ENC_SH * 2;
    __hip_bfloat16* h1  = (__hip_bfloat16*)p; p += (size_t)CH * NP1 * 2;
    char* buf2 = p;
    float* xflat = (float*)buf2;
    __hip_bfloat16* Abf = (__hip_bfloat16*)(buf2 + (size_t)CH * FLATN * 4);
    float* h2 = (float*)buf2;   // aliases xflat/Abf after GEMM1

    transpose_conv<<<dim3(NP1 / 32, KP1 / 32), 256, 0, stream>>>(w1, w1T, FLATN, H1N, KP1, NP1);
    transpose_conv<<<dim3(NP2 / 32, KP2 / 32), 256, 0, stream>>>(w2, w2T, H1N, H2N, KP2, NP2);

    // macro encoder weights -> bf16 [N][K] per layer: qkvT | outT | ff1T | ff2T
    for (int pl = 0; pl < 2; ++pl) {
        __hip_bfloat16* base = encT + (size_t)pl * 49152;
        transpose_conv<<<dim3(192 / 32, 64 / 32), 256, 0, stream>>>(
            ma_qkv + pl * 64 * 192, base, 64, 192, 64, 192);
        transpose_conv<<<dim3(64 / 32, 64 / 32), 256, 0, stream>>>(
            ma_out + pl * 64 * 64, base + 12288, 64, 64, 64, 64);
        transpose_conv<<<dim3(256 / 32, 64 / 32), 256, 0, stream>>>(
            ma_w1 + pl * 64 * 256, base + 16384, 64, 256, 64, 256);
        transpose_conv<<<dim3(64 / 32, 256 / 32), 256, 0, stream>>>(
            ma_w2 + pl * 256 * 64, base + 32768, 256, 64, 256, 64);
    }

    for (int m0 = 0; m0 < BATCH; m0 += CH) {
        int mc = BATCH - m0 < CH ? BATCH - m0 : CH;   // multiple of 128

        build_tokens<<<(mc * 1024) / 256, 256, 0, stream>>>(
            x_cat + (size_t)m0 * NCATS, shared_emb, emb, xflat);
        cont_proj<<<(mc * 16) / 256, 256, 0, stream>>>(
            x_cont + (size_t)m0 * CONTN, cont_w, cont_b, xflat);
        micro_enc<<<mc, 64, 0, stream>>>(xflat, mi_qkv, mi_out, mi_ln1w, mi_ln1b,
                                         mi_ln2w, mi_ln2b, mi_w1, mi_b1, mi_w2, mi_b2);
        macro_enc_mfma<<<mc / 4, 256, 0, stream>>>(
            xflat, (const short*)encT, ma_ln1w, ma_ln1b, ma_ln2w, ma_ln2b, ma_b1, ma_b2);

        conv_bf16_pad<<<(int)(((size_t)mc * KP1) / 256), 256, 0, stream>>>(
            xflat, Abf, FLATN, KP1);

        gemm_mfma<<<dim3(NP1 / 128, mc / 128), 256, 0, stream>>>(
            Abf, w1T, b1, H1N, h1, NP1, KP1, 0, 1);
        gemm_mfma<<<dim3(NP2 / 128, mc / 128), 256, 0, stream>>>(
            h1, w2T, b2, H2N, h2, NP2, KP2, H2N, 0);

        final_dot<<<mc, 256, 0, stream>>>(h2, w3, b3, out + m0);
    }
}

// Round 6
// 2891.548 us; speedup vs baseline: 3.2394x; 1.4303x over previous
//
#include <hip/hip_runtime.h>
#include <hip/hip_bf16.h>
#include <math.h>

#define BATCH  16384
#define NCATS  16
#define VOCABN 1000
#define DIMD   64
#define SHARED_E 10
#define INDIVE 54
#define CONTN  16
#define FLATN  1040   // NCATS*DIMD + CONTN
#define H1N    4160
#define H2N    2080
#define KP1    1088   // FLATN padded to mult of 64
#define NP1    4224   // H1N padded to mult of 128
#define KP2    4224   // = NP1 (GEMM2 K)
#define NP2    2176   // H2N padded to mult of 128
#define EPSV   1e-5f

typedef __attribute__((ext_vector_type(8))) short bf16x8;
typedef __attribute__((ext_vector_type(4))) float f32x4;

__device__ __forceinline__ float gelu_f(float x) {
    return 0.5f * x * (1.0f + erff(x * 0.70710678118654752440f));
}
__device__ __forceinline__ float wsum(float v) {
#pragma unroll
    for (int o = 32; o > 0; o >>= 1) v += __shfl_xor(v, o, 64);
    return v;
}
__device__ __forceinline__ short f2bf_s(float a) {
    __hip_bfloat16 x = __float2bfloat16(a);
    return *reinterpret_cast<short*>(&x);
}
__device__ __forceinline__ unsigned int packbf(float a, float b) {
    __hip_bfloat16 x = __float2bfloat16(a), y = __float2bfloat16(b);
    unsigned short ux = *reinterpret_cast<unsigned short*>(&x);
    unsigned short uy = *reinterpret_cast<unsigned short*>(&y);
    return (unsigned)ux | ((unsigned)uy << 16);
}
// async global->LDS, 16B per lane; LDS dest is wave-uniform base + lane*16 (m97)
__device__ __forceinline__ void gload16(const void* g, void* l) {
    __builtin_amdgcn_global_load_lds(
        (const __attribute__((address_space(1))) void*)g,
        (__attribute__((address_space(3))) void*)l, 16, 0, 0);
}

// ---------------- token build: xflat[:, 0:1024] (chunk-local rows) ----------------
__global__ __launch_bounds__(256) void build_tokens(
    const int* __restrict__ x_cat, const float* __restrict__ shared_emb,
    const float* __restrict__ emb, float* __restrict__ xflat)
{
    int idx = blockIdx.x * 256 + threadIdx.x;      // mc*1024 total
    int b = idx >> 10, r = idx & 1023;
    int c = r >> 6, d = r & 63;
    float v;
    if (d < SHARED_E) v = shared_emb[d];
    else              v = emb[((size_t)c * VOCABN + x_cat[b * NCATS + c]) * INDIVE + (d - SHARED_E)];
    xflat[(size_t)b * FLATN + r] = v;
}

// ---------------- cont projection: xflat[:, 1024:1040] ----------------
__global__ __launch_bounds__(256) void cont_proj(
    const float* __restrict__ x_cont, const float* __restrict__ cw,
    const float* __restrict__ cb, float* __restrict__ xflat)
{
    int idx = blockIdx.x * 256 + threadIdx.x;      // mc*16 total
    int b = idx >> 4, j = idx & 15;
    float acc = cb[j];
#pragma unroll
    for (int k = 0; k < 16; ++k) acc += x_cont[b * 16 + k] * cw[k * 16 + j];
    xflat[(size_t)b * FLATN + 1024 + j] = acc;
}

// ---------------- micro encoder: 2 tokens, 1 wave / sample ----------------
__global__ __launch_bounds__(64) void micro_enc(
    float* __restrict__ xflat,
    const float* __restrict__ qkv_w, const float* __restrict__ out_w,
    const float* __restrict__ ln1w, const float* __restrict__ ln1b,
    const float* __restrict__ ln2w, const float* __restrict__ ln2b,
    const float* __restrict__ w1, const float* __restrict__ b1,
    const float* __restrict__ w2, const float* __restrict__ b2)
{
    int b = blockIdx.x;
    int lane = threadIdx.x;
    __shared__ float X[2][64], XN[2][64], QKV[2][192], OO[2][64], FF[2][256];
    __shared__ float PREV[16], ATTN[16];

    float* xrow = xflat + (size_t)b * FLATN;
    X[0][lane] = xrow[lane];
    X[1][lane] = xrow[64 + lane];
    if (lane < 16) PREV[lane] = 0.f;
    __syncthreads();

    for (int p = 0; p < 2; ++p) {
        const float* qw  = qkv_w + p * 64 * 192;
        const float* ow  = out_w + p * 64 * 64;
        const float* l1w = ln1w + p * 64; const float* l1b = ln1b + p * 64;
        const float* l2w = ln2w + p * 64; const float* l2b = ln2b + p * 64;
        const float* fw1 = w1 + p * 64 * 256; const float* fb1 = b1 + p * 256;
        const float* fw2 = w2 + p * 256 * 64; const float* fb2 = b2 + p * 64;

#pragma unroll
        for (int t = 0; t < 2; ++t) {
            float v = X[t][lane];
            float m = wsum(v) * (1.f / 64.f);
            float d = v - m;
            float var = wsum(d * d) * (1.f / 64.f);
            XN[t][lane] = d * rsqrtf(var + EPSV) * l1w[lane] + l1b[lane];
        }
        __syncthreads();

        for (int cc = 0; cc < 3; ++cc) {
            int c = lane + cc * 64;
            float a0 = 0.f, a1 = 0.f;
            for (int k = 0; k < 64; k += 4) {
                float wv[4];
#pragma unroll
                for (int u = 0; u < 4; ++u) wv[u] = qw[(k + u) * 192 + c];
#pragma unroll
                for (int u = 0; u < 4; ++u) { a0 += XN[0][k + u] * wv[u]; a1 += XN[1][k + u] * wv[u]; }
            }
            QKV[0][c] = a0; QKV[1][c] = a1;
        }
        __syncthreads();

        if (lane < 16) {
            int h = lane >> 2, i = (lane >> 1) & 1, j = lane & 1;
            float s = 0.f;
#pragma unroll
            for (int d = 0; d < 16; ++d)
                s += QKV[i][h * 16 + d] * QKV[j][64 + h * 16 + d];
            s = s * 0.25f + PREV[lane];
            PREV[lane] = s;
        }
        __syncthreads();
        if (lane < 16) {
            int base = lane & ~1;
            float s0 = PREV[base], s1 = PREV[base + 1];
            float mx = fmaxf(s0, s1);
            float e0 = expf(s0 - mx), e1 = expf(s1 - mx);
            float inv = 1.f / (e0 + e1);
            ATTN[lane] = (lane & 1) ? e1 * inv : e0 * inv;
        }
        __syncthreads();

        {
            int h = lane >> 4;
#pragma unroll
            for (int t = 0; t < 2; ++t)
                OO[t][lane] = ATTN[h * 4 + t * 2 + 0] * QKV[0][128 + lane]
                            + ATTN[h * 4 + t * 2 + 1] * QKV[1][128 + lane];
        }
        __syncthreads();

        {
            float a0 = 0.f, a1 = 0.f;
            for (int k = 0; k < 64; k += 4) {
                float wv[4];
#pragma unroll
                for (int u = 0; u < 4; ++u) wv[u] = ow[(k + u) * 64 + lane];
#pragma unroll
                for (int u = 0; u < 4; ++u) { a0 += OO[0][k + u] * wv[u]; a1 += OO[1][k + u] * wv[u]; }
            }
            X[0][lane] += a0; X[1][lane] += a1;
        }
        __syncthreads();

#pragma unroll
        for (int t = 0; t < 2; ++t) {
            float v = X[t][lane];
            float m = wsum(v) * (1.f / 64.f);
            float d = v - m;
            float var = wsum(d * d) * (1.f / 64.f);
            XN[t][lane] = d * rsqrtf(var + EPSV) * l2w[lane] + l2b[lane];
        }
        __syncthreads();

        for (int cc = 0; cc < 4; ++cc) {
            int c = lane + cc * 64;
            float a0 = fb1[c], a1 = fb1[c];
            for (int k = 0; k < 64; k += 4) {
                float wv[4];
#pragma unroll
                for (int u = 0; u < 4; ++u) wv[u] = fw1[(k + u) * 256 + c];
#pragma unroll
                for (int u = 0; u < 4; ++u) { a0 += XN[0][k + u] * wv[u]; a1 += XN[1][k + u] * wv[u]; }
            }
            FF[0][c] = gelu_f(a0); FF[1][c] = gelu_f(a1);
        }
        __syncthreads();

        {
            float a0 = fb2[lane], a1 = fb2[lane];
            for (int k = 0; k < 256; k += 4) {
                float wv[4];
#pragma unroll
                for (int u = 0; u < 4; ++u) wv[u] = fw2[(k + u) * 64 + lane];
#pragma unroll
                for (int u = 0; u < 4; ++u) { a0 += FF[0][k + u] * wv[u]; a1 += FF[1][k + u] * wv[u]; }
            }
            X[0][lane] += a0; X[1][lane] += a1;
        }
        __syncthreads();
    }

    xrow[lane]      = X[0][lane];
    xrow[64 + lane] = X[1][lane];
}

// ---------------- macro encoder (MFMA): 4 samples / block, wave = sample ----------------
// also emits Abf = bf16([xflat row | zero-pad to KP1])
__global__ __launch_bounds__(256) void macro_enc_mfma(
    float* __restrict__ xflat, __hip_bfloat16* __restrict__ Abf,
    const short* __restrict__ wT,
    const float* __restrict__ ln1w, const float* __restrict__ ln1b,
    const float* __restrict__ ln2w, const float* __restrict__ ln2b,
    const float* __restrict__ b1, const float* __restrict__ b2)
{
    __shared__ float Xr[64][64];
    __shared__ __align__(16) short XN[64][72];
    __shared__ __align__(16) short KV[64][136];
    __shared__ __align__(16) short FFb[64][136];

    int tid = threadIdx.x;
    int lane = tid & 63, w = tid >> 6;
    int b0 = blockIdx.x * 4;

    {
        int r = tid >> 2, c0 = (tid & 3) * 16;
        const float* gx = xflat + (size_t)(b0 + (r >> 4)) * FLATN + (r & 15) * 64 + c0;
#pragma unroll
        for (int u = 0; u < 4; ++u) *(float4*)&Xr[r][c0 + u * 4] = *(const float4*)(gx + u * 4);
    }
    __syncthreads();

    int fr = lane & 15, fk = lane >> 4;
    int rb = w * 16 + 4 * fk;
    float prev[16];
#pragma unroll
    for (int j = 0; j < 16; ++j) prev[j] = 0.f;

    for (int p = 0; p < 2; ++p) {
        const short* lq  = wT + p * 49152;
        const short* lo  = lq + 12288;
        const short* lf1 = lo + 4096;
        const short* lf2 = lf1 + 16384;
        const float* l1w = ln1w + p * 64; const float* l1b = ln1b + p * 64;
        const float* l2w = ln2w + p * 64; const float* l2b = ln2b + p * 64;
        const float* fb1 = b1 + p * 256;  const float* fb2 = b2 + p * 64;

        {
            float wv = l1w[lane], bv = l1b[lane];
#pragma unroll
            for (int i = 0; i < 16; ++i) {
                int r = w * 16 + i;
                float v = Xr[r][lane];
                float m = wsum(v) * (1.f / 64.f);
                float d = v - m;
                float var = wsum(d * d) * (1.f / 64.f);
                XN[r][lane] = f2bf_s(d * rsqrtf(var + EPSV) * wv + bv);
            }
        }
        __syncthreads();

        {
            bf16x8 a0 = *(const bf16x8*)&XN[w * 16 + fr][fk * 8];
            bf16x8 a1 = *(const bf16x8*)&XN[w * 16 + fr][fk * 8 + 32];
#pragma unroll
            for (int nf = 0; nf < 12; ++nf) {
                const short* bp = lq + (nf * 16 + fr) * 64 + fk * 8;
                bf16x8 bv0 = *(const bf16x8*)bp;
                bf16x8 bv1 = *(const bf16x8*)(bp + 32);
                f32x4 acc = {};
                acc = __builtin_amdgcn_mfma_f32_16x16x32_bf16(a0, bv0, acc, 0, 0, 0);
                acc = __builtin_amdgcn_mfma_f32_16x16x32_bf16(a1, bv1, acc, 0, 0, 0);
                int cc = nf * 16 + fr;
#pragma unroll
                for (int rr = 0; rr < 4; ++rr) {
                    if (nf < 4) FFb[rb + rr][cc] = f2bf_s(acc[rr]);
                    else        KV[rb + rr][cc - 64] = f2bf_s(acc[rr]);
                }
            }
        }
        __syncthreads();

        {
            int h = fk & 3;
            int qi = fr;
            int qrow = w * 16 + qi;
            float q[16];
            const unsigned int* qp = (const unsigned int*)&FFb[qrow][h * 16];
#pragma unroll
            for (int e = 0; e < 8; ++e) {
                unsigned int u = qp[e];
                q[2 * e]     = __uint_as_float(u << 16);
                q[2 * e + 1] = __uint_as_float(u & 0xffff0000u);
            }
            float sc[16];
#pragma unroll
            for (int j = 0; j < 16; ++j) {
                const unsigned int* kp = (const unsigned int*)&KV[w * 16 + j][h * 16];
                float a = 0.f;
#pragma unroll
                for (int e = 0; e < 8; ++e) {
                    unsigned int u = kp[e];
                    a += q[2 * e] * __uint_as_float(u << 16)
                       + q[2 * e + 1] * __uint_as_float(u & 0xffff0000u);
                }
                a = a * 0.25f + prev[j];
                prev[j] = a;
                sc[j] = a;
            }
            float mx = sc[0];
#pragma unroll
            for (int j = 1; j < 16; ++j) mx = fmaxf(mx, sc[j]);
            float sum = 0.f;
#pragma unroll
            for (int j = 0; j < 16; ++j) { sc[j] = expf(sc[j] - mx); sum += sc[j]; }
            float inv = 1.f / sum;
            float o[16];
#pragma unroll
            for (int d = 0; d < 16; ++d) o[d] = 0.f;
#pragma unroll
            for (int j = 0; j < 16; ++j) {
                float a = sc[j] * inv;
                const unsigned int* vp = (const unsigned int*)&KV[w * 16 + j][64 + h * 16];
#pragma unroll
                for (int e = 0; e < 8; ++e) {
                    unsigned int u = vp[e];
                    o[2 * e]     += a * __uint_as_float(u << 16);
                    o[2 * e + 1] += a * __uint_as_float(u & 0xffff0000u);
                }
            }
            unsigned int* op = (unsigned int*)&XN[qrow][h * 16];
#pragma unroll
            for (int e = 0; e < 8; ++e) op[e] = packbf(o[2 * e], o[2 * e + 1]);
        }
        __syncthreads();

        {
            bf16x8 a0 = *(const bf16x8*)&XN[w * 16 + fr][fk * 8];
            bf16x8 a1 = *(const bf16x8*)&XN[w * 16 + fr][fk * 8 + 32];
#pragma unroll
            for (int nf = 0; nf < 4; ++nf) {
                const short* bp = lo + (nf * 16 + fr) * 64 + fk * 8;
                bf16x8 bv0 = *(const bf16x8*)bp;
                bf16x8 bv1 = *(const bf16x8*)(bp + 32);
                f32x4 acc = {};
                acc = __builtin_amdgcn_mfma_f32_16x16x32_bf16(a0, bv0, acc, 0, 0, 0);
                acc = __builtin_amdgcn_mfma_f32_16x16x32_bf16(a1, bv1, acc, 0, 0, 0);
                int cc = nf * 16 + fr;
#pragma unroll
                for (int rr = 0; rr < 4; ++rr) Xr[rb + rr][cc] += acc[rr];
            }
        }
        __syncthreads();

        {
            float wv = l2w[lane], bv = l2b[lane];
#pragma unroll
            for (int i = 0; i < 16; ++i) {
                int r = w * 16 + i;
                float v = Xr[r][lane];
                float m = wsum(v) * (1.f / 64.f);
                float d = v - m;
                float var = wsum(d * d) * (1.f / 64.f);
                XN[r][lane] = f2bf_s(d * rsqrtf(var + EPSV) * wv + bv);
            }
        }
        __syncthreads();

        {
            bf16x8 a0 = *(const bf16x8*)&XN[w * 16 + fr][fk * 8];
            bf16x8 a1 = *(const bf16x8*)&XN[w * 16 + fr][fk * 8 + 32];
            f32x4 facc[4] = {};
#pragma unroll
            for (int half = 0; half < 2; ++half) {
#pragma unroll
                for (int nf = 0; nf < 8; ++nf) {
                    int ng = half * 128 + nf * 16;
                    const short* bp = lf1 + (ng + fr) * 64 + fk * 8;
                    bf16x8 bv0 = *(const bf16x8*)bp;
                    bf16x8 bv1 = *(const bf16x8*)(bp + 32);
                    f32x4 acc = {};
                    acc = __builtin_amdgcn_mfma_f32_16x16x32_bf16(a0, bv0, acc, 0, 0, 0);
                    acc = __builtin_amdgcn_mfma_f32_16x16x32_bf16(a1, bv1, acc, 0, 0, 0);
                    int cc = nf * 16 + fr;
                    float bias1 = fb1[ng + fr];
#pragma unroll
                    for (int rr = 0; rr < 4; ++rr)
                        FFb[rb + rr][cc] = f2bf_s(gelu_f(acc[rr] + bias1));
                }
                __syncthreads();
                bf16x8 fa[4];
#pragma unroll
                for (int kf = 0; kf < 4; ++kf)
                    fa[kf] = *(const bf16x8*)&FFb[w * 16 + fr][kf * 32 + fk * 8];
#pragma unroll
                for (int nf = 0; nf < 4; ++nf) {
                    const short* bp = lf2 + (nf * 16 + fr) * 256 + half * 128 + fk * 8;
#pragma unroll
                    for (int kf = 0; kf < 4; ++kf)
                        facc[nf] = __builtin_amdgcn_mfma_f32_16x16x32_bf16(
                            fa[kf], *(const bf16x8*)(bp + kf * 32), facc[nf], 0, 0, 0);
                }
                __syncthreads();
            }
#pragma unroll
            for (int nf = 0; nf < 4; ++nf) {
                int cc = nf * 16 + fr;
                float bias2 = fb2[cc];
#pragma unroll
                for (int rr = 0; rr < 4; ++rr) Xr[rb + rr][cc] += facc[nf][rr] + bias2;
            }
        }
        __syncthreads();
    }

    // store residual back (fp32) + bf16 token part of Abf
    {
        int r = tid >> 2, c0 = (tid & 3) * 16;
        int b = b0 + (r >> 4);
        float* gx = xflat + (size_t)b * FLATN + (r & 15) * 64 + c0;
#pragma unroll
        for (int u = 0; u < 4; ++u) *(float4*)(gx + u * 4) = *(const float4*)&Xr[r][c0 + u * 4];
        unsigned int pk[8];
#pragma unroll
        for (int e = 0; e < 8; ++e) pk[e] = packbf(Xr[r][c0 + 2 * e], Xr[r][c0 + 2 * e + 1]);
        unsigned int* ga = (unsigned int*)(Abf + (size_t)b * KP1 + (r & 15) * 64 + c0);
#pragma unroll
        for (int e = 0; e < 8; ++e) ga[e] = pk[e];
    }
    // cont + zero-pad cols (1024..1087) of Abf
    {
        int s = tid >> 6, c = tid & 63;
        int b = b0 + s;
        float v = (c < CONTN) ? xflat[(size_t)b * FLATN + 1024 + c] : 0.f;
        Abf[(size_t)b * KP1 + 1024 + c] = __float2bfloat16(v);
    }
}

// ---------------- transpose + convert: W[K][N] fp32 -> Wt[Np][Kp] bf16 (zero-padded) ----
__global__ __launch_bounds__(256) void transpose_conv(
    const float* __restrict__ src, __hip_bfloat16* __restrict__ dst,
    int K, int N, int Kp, int Np)
{
    __shared__ float T[32][33];
    int k0 = blockIdx.y * 32, n0 = blockIdx.x * 32;
    int tn = threadIdx.x & 31, tk = threadIdx.x >> 5;
#pragma unroll
    for (int r = 0; r < 4; ++r) {
        int k = k0 + tk + r * 8, n = n0 + tn;
        T[tk + r * 8][tn] = (k < K && n < N) ? src[(size_t)k * N + n] : 0.f;
    }
    __syncthreads();
#pragma unroll
    for (int r = 0; r < 4; ++r) {
        int n = n0 + tk + r * 8, k = k0 + tn;
        dst[(size_t)n * Kp + k] = __float2bfloat16(T[tn][tk + r * 8]);
    }
}

// ---------------- m97-structure bf16 MFMA GEMM ----------------
// A: [M][Kp] bf16 row-major; Bt: [Np][Kp] bf16 (= W^T).
// 128x128x64 tile, 4 waves, global_load_lds staging, 2 barriers/K-step.
// MODE 1: C[M][Np] = bf16(gelu(A@Bt^T + bias)), coalesced via LDS restage.
// MODE 2: partials[row][bx] = sum_cols gelu(A@Bt^T + bias) * w3[col]  (fused final dot)
template <int MODE>
__global__ __launch_bounds__(256) void gemm_mfma(
    const __hip_bfloat16* __restrict__ A, const __hip_bfloat16* __restrict__ Bt,
    const float* __restrict__ bias, int bias_n,
    __hip_bfloat16* __restrict__ Cbf, const float* __restrict__ w3,
    float* __restrict__ partials, int Np, int Kp)
{
    __shared__ __align__(16) short LDSbuf[2 * 128 * 64];   // 32 KB: A tile | B tile
    short* Als = LDSbuf;
    short* Bls = LDSbuf + 128 * 64;

    int tid = threadIdx.x;
    int lane = tid & 63, wave = tid >> 6;

    // bijective XCD swizzle (m204)
    int nbx = gridDim.x;
    int nwg = nbx * gridDim.y;
    int wgid = blockIdx.y * nbx + blockIdx.x;
    int q = nwg >> 3, r = nwg & 7;
    int xcd = wgid & 7, loc = wgid >> 3;
    int sw = (xcd < r ? xcd * (q + 1) : r * (q + 1) + (xcd - r) * q) + loc;
    int bm = (sw / nbx) * 128, bx = sw % nbx, bn = bx * 128;

    // staging: wave w stages rows w*32..w*32+31; per issue 8 rows, lane l -> row +l/8, k-slice (l%8)*8
    int lrow8 = lane >> 3, lk8 = (lane & 7) * 8;
    const __hip_bfloat16* Ag = A  + (size_t)(bm + wave * 32 + lrow8) * Kp + lk8;
    const __hip_bfloat16* Bg = Bt + (size_t)(bn + wave * 32 + lrow8) * Kp + lk8;
    short* Al = Als + (wave * 32) * 64;
    short* Bl = Bls + (wave * 32) * 64;

    int wm = (wave >> 1) * 64, wn = (wave & 1) * 64;
    int lrow = lane & 15, lk = lane >> 4;
    const short* Af = Als + (wm + lrow) * 64 + lk * 8;
    const short* Bf = Bls + (wn + lrow) * 64 + lk * 8;

    f32x4 acc[4][4] = {};

    for (int k0 = 0; k0 < Kp; k0 += 64) {
        __syncthreads();                       // prev tile fully consumed
#pragma unroll
        for (int it = 0; it < 4; ++it) {
            gload16(Ag + (size_t)(it * 8) * Kp + k0, Al + (it * 8) * 64);
            gload16(Bg + (size_t)(it * 8) * Kp + k0, Bl + (it * 8) * 64);
        }
        __syncthreads();                       // vmcnt(0) drain -> tile ready
#pragma unroll
        for (int ks = 0; ks < 2; ++ks) {
            bf16x8 af[4], bf[4];
#pragma unroll
            for (int i = 0; i < 4; ++i) af[i] = *(const bf16x8*)(Af + i * 16 * 64 + ks * 32);
#pragma unroll
            for (int j = 0; j < 4; ++j) bf[j] = *(const bf16x8*)(Bf + j * 16 * 64 + ks * 32);
#pragma unroll
            for (int i = 0; i < 4; ++i)
#pragma unroll
                for (int j = 0; j < 4; ++j)
                    acc[i][j] = __builtin_amdgcn_mfma_f32_16x16x32_bf16(af[i], bf[j], acc[i][j], 0, 0, 0);
        }
    }
    __syncthreads();   // all LDS reads done; buffer reusable for epilogue

    if (MODE == 1) {
        // stage bf16 outputs into LDS [128][128], then full-line coalesced stores
        short* Cs = LDSbuf;
#pragma unroll
        for (int j = 0; j < 4; ++j) {
            int cl = wn + j * 16 + lrow;
            float bv = (bn + cl < bias_n) ? bias[bn + cl] : 0.f;
#pragma unroll
            for (int i = 0; i < 4; ++i) {
                int rl = wm + i * 16 + 4 * lk;
#pragma unroll
                for (int rr = 0; rr < 4; ++rr)
                    Cs[(rl + rr) * 128 + cl] = f2bf_s(gelu_f(acc[i][j][rr] + bv));
            }
        }
        __syncthreads();
        int rloc = tid >> 1, cb = (tid & 1) * 64;      // 2 threads/row, 128B each
        const int4* src = (const int4*)&Cs[rloc * 128 + cb];
        int4* dst = (int4*)(Cbf + (size_t)(bm + rloc) * Np + bn + cb);
#pragma unroll
        for (int u = 0; u < 8; ++u) dst[u] = src[u];
    } else {
        // fused w3 reduction: per-thread sums over its 4 cols, shfl-reduce over the 16 col-lanes
        float rs[16];
#pragma unroll
        for (int t = 0; t < 16; ++t) rs[t] = 0.f;
#pragma unroll
        for (int j = 0; j < 4; ++j) {
            int gcol = bn + wn + j * 16 + lrow;
            float bv  = (gcol < bias_n) ? bias[gcol] : 0.f;
            float w3v = (gcol < H2N) ? w3[gcol] : 0.f;
#pragma unroll
            for (int i = 0; i < 4; ++i)
#pragma unroll
                for (int rr = 0; rr < 4; ++rr)
                    rs[i * 4 + rr] += gelu_f(acc[i][j][rr] + bv) * w3v;
        }
#pragma unroll
        for (int o = 1; o < 16; o <<= 1)
#pragma unroll
            for (int t = 0; t < 16; ++t) rs[t] += __shfl_xor(rs[t], o, 64);
        float* pr = (float*)LDSbuf;                    // [128][2]
        if (lrow == 0) {
#pragma unroll
            for (int i = 0; i < 4; ++i)
#pragma unroll
                for (int rr = 0; rr < 4; ++rr)
                    pr[(wm + i * 16 + 4 * lk + rr) * 2 + (wave & 1)] = rs[i * 4 + rr];
        }
        __syncthreads();
        if (tid < 128)
            partials[(size_t)(bm + tid) * nbx + bx] = pr[tid * 2] + pr[tid * 2 + 1];
    }
}

// ---------------- logits = b3 + sum over N-tiles of partials ----------------
__global__ __launch_bounds__(256) void reduce_partials(
    const float* __restrict__ partials, const float* __restrict__ b3,
    float* __restrict__ out, int n, int nbx)
{
    int b = blockIdx.x * 256 + threadIdx.x;
    if (b >= n) return;
    float s = b3[0];
    for (int x = 0; x < nbx; ++x) s += partials[(size_t)b * nbx + x];
    out[b] = s;
}

extern "C" void kernel_launch(void* const* d_in, const int* in_sizes, int n_in,
                              void* d_out, int out_size, void* d_ws, size_t ws_size,
                              hipStream_t stream)
{
    const int*   x_cat      = (const int*)  d_in[0];
    const float* x_cont     = (const float*)d_in[1];
    const float* shared_emb = (const float*)d_in[2];
    const float* emb        = (const float*)d_in[3];
    const float* mi_qkv  = (const float*)d_in[4];
    const float* mi_out  = (const float*)d_in[5];
    const float* mi_ln1w = (const float*)d_in[6];
    const float* mi_ln1b = (const float*)d_in[7];
    const float* mi_ln2w = (const float*)d_in[8];
    const float* mi_ln2b = (const float*)d_in[9];
    const float* mi_w1   = (const float*)d_in[10];
    const float* mi_b1   = (const float*)d_in[11];
    const float* mi_w2   = (const float*)d_in[12];
    const float* mi_b2   = (const float*)d_in[13];
    const float* ma_qkv  = (const float*)d_in[14];
    const float* ma_out  = (const float*)d_in[15];
    const float* ma_ln1w = (const float*)d_in[16];
    const float* ma_ln1b = (const float*)d_in[17];
    const float* ma_ln2w = (const float*)d_in[18];
    const float* ma_ln2b = (const float*)d_in[19];
    const float* ma_w1   = (const float*)d_in[20];
    const float* ma_b1   = (const float*)d_in[21];
    const float* ma_w2   = (const float*)d_in[22];
    const float* ma_b2   = (const float*)d_in[23];
    const float* cont_w  = (const float*)d_in[24];
    const float* cont_b  = (const float*)d_in[25];
    const float* w1      = (const float*)d_in[26];
    const float* b1      = (const float*)d_in[27];
    const float* w2      = (const float*)d_in[28];
    const float* b2      = (const float*)d_in[29];
    const float* w3      = (const float*)d_in[30];
    const float* b3      = (const float*)d_in[31];
    float* out = (float*)d_out;

    const int NBX2 = NP2 / 128;          // 17 N-tiles in GEMM2
    const size_t ENC_SH = 2 * 49152;
    const size_t FIXED = ((size_t)NP1 * KP1 + (size_t)NP2 * KP2 + ENC_SH) * 2;
    // per-row: h1 (NP1 bf16) + xflat (FLATN f32) + Abf (KP1 bf16) + partials (NBX2 f32)
    const size_t PER_ROW = (size_t)NP1 * 2 + (size_t)FLATN * 4 + (size_t)KP1 * 2 + (size_t)NBX2 * 4;
    size_t avail = (ws_size > FIXED) ? ws_size - FIXED : 0;
    long long chl = (long long)(avail / PER_ROW);
    int CH = (int)((chl / 128) * 128);
    if (CH > BATCH) CH = BATCH;
    if (CH < 128) CH = 128;

    char* p = (char*)d_ws;
    __hip_bfloat16* w1T = (__hip_bfloat16*)p; p += (size_t)NP1 * KP1 * 2;
    __hip_bfloat16* w2T = (__hip_bfloat16*)p; p += (size_t)NP2 * KP2 * 2;
    __hip_bfloat16* encT = (__hip_bfloat16*)p; p += ENC_SH * 2;
    __hip_bfloat16* h1  = (__hip_bfloat16*)p; p += (size_t)CH * NP1 * 2;
    float* xflat = (float*)p;                 p += (size_t)CH * FLATN * 4;
    __hip_bfloat16* Abf = (__hip_bfloat16*)p; p += (size_t)CH * KP1 * 2;
    float* partials = (float*)p;

    transpose_conv<<<dim3(NP1 / 32, KP1 / 32), 256, 0, stream>>>(w1, w1T, FLATN, H1N, KP1, NP1);
    transpose_conv<<<dim3(NP2 / 32, KP2 / 32), 256, 0, stream>>>(w2, w2T, H1N, H2N, KP2, NP2);

    for (int pl = 0; pl < 2; ++pl) {
        __hip_bfloat16* base = encT + (size_t)pl * 49152;
        transpose_conv<<<dim3(192 / 32, 64 / 32), 256, 0, stream>>>(
            ma_qkv + pl * 64 * 192, base, 64, 192, 64, 192);
        transpose_conv<<<dim3(64 / 32, 64 / 32), 256, 0, stream>>>(
            ma_out + pl * 64 * 64, base + 12288, 64, 64, 64, 64);
        transpose_conv<<<dim3(256 / 32, 64 / 32), 256, 0, stream>>>(
            ma_w1 + pl * 64 * 256, base + 16384, 64, 256, 64, 256);
        transpose_conv<<<dim3(64 / 32, 256 / 32), 256, 0, stream>>>(
            ma_w2 + pl * 256 * 64, base + 32768, 256, 64, 256, 64);
    }

    for (int m0 = 0; m0 < BATCH; m0 += CH) {
        int mc = BATCH - m0 < CH ? BATCH - m0 : CH;   // multiple of 128

        build_tokens<<<(mc * 1024) / 256, 256, 0, stream>>>(
            x_cat + (size_t)m0 * NCATS, shared_emb, emb, xflat);
        cont_proj<<<(mc * 16) / 256, 256, 0, stream>>>(
            x_cont + (size_t)m0 * CONTN, cont_w, cont_b, xflat);
        micro_enc<<<mc, 64, 0, stream>>>(xflat, mi_qkv, mi_out, mi_ln1w, mi_ln1b,
                                         mi_ln2w, mi_ln2b, mi_w1, mi_b1, mi_w2, mi_b2);
        macro_enc_mfma<<<mc / 4, 256, 0, stream>>>(
            xflat, Abf, (const short*)encT, ma_ln1w, ma_ln1b, ma_ln2w, ma_ln2b, ma_b1, ma_b2);

        gemm_mfma<1><<<dim3(NP1 / 128, mc / 128), 256, 0, stream>>>(
            Abf, w1T, b1, H1N, h1, nullptr, nullptr, NP1, KP1);
        gemm_mfma<2><<<dim3(NBX2, mc / 128), 256, 0, stream>>>(
            h1, w2T, b2, H2N, nullptr, w3, partials, NP2, KP2);

        reduce_partials<<<(mc + 255) / 256, 256, 0, stream>>>(partials, b3, out + m0, mc, NBX2);
    }
}

// Round 7
// 2455.262 us; speedup vs baseline: 3.8151x; 1.1777x over previous
//
#include <hip/hip_runtime.h>
#include <hip/hip_bf16.h>
#include <math.h>

#define BATCH  16384
#define NCATS  16
#define VOCABN 1000
#define DIMD   64
#define SHARED_E 10
#define INDIVE 54
#define CONTN  16
#define FLATN  1040   // NCATS*DIMD + CONTN
#define H1N    4160
#define H2N    2080
#define KP1    1088   // FLATN padded to mult of 64
#define NP1    4224   // H1N padded to mult of 128
#define KP2    4224   // = NP1 (GEMM2 K)
#define NP2    2176   // H2N padded to mult of 128
#define EPSV   1e-5f

typedef __attribute__((ext_vector_type(8))) short bf16x8;
typedef __attribute__((ext_vector_type(4))) float f32x4;

__device__ __forceinline__ float gelu_f(float x) {
    return 0.5f * x * (1.0f + erff(x * 0.70710678118654752440f));
}
__device__ __forceinline__ float wsum(float v) {
#pragma unroll
    for (int o = 32; o > 0; o >>= 1) v += __shfl_xor(v, o, 64);
    return v;
}
__device__ __forceinline__ short f2bf_s(float a) {
    __hip_bfloat16 x = __float2bfloat16(a);
    return *reinterpret_cast<short*>(&x);
}
__device__ __forceinline__ unsigned int packbf(float a, float b) {
    __hip_bfloat16 x = __float2bfloat16(a), y = __float2bfloat16(b);
    unsigned short ux = *reinterpret_cast<unsigned short*>(&x);
    unsigned short uy = *reinterpret_cast<unsigned short*>(&y);
    return (unsigned)ux | ((unsigned)uy << 16);
}
// async global->LDS, 16B per lane; LDS dest is wave-uniform base + lane*16 (m97)
__device__ __forceinline__ void gload16(const void* g, void* l) {
    __builtin_amdgcn_global_load_lds(
        (const __attribute__((address_space(1))) void*)g,
        (__attribute__((address_space(3))) void*)l, 16, 0, 0);
}

// ---------------- token build: xflat[:, 0:1024] (chunk-local rows) ----------------
__global__ __launch_bounds__(256) void build_tokens(
    const int* __restrict__ x_cat, const float* __restrict__ shared_emb,
    const float* __restrict__ emb, float* __restrict__ xflat)
{
    int idx = blockIdx.x * 256 + threadIdx.x;      // mc*1024 total
    int b = idx >> 10, r = idx & 1023;
    int c = r >> 6, d = r & 63;
    float v;
    if (d < SHARED_E) v = shared_emb[d];
    else              v = emb[((size_t)c * VOCABN + x_cat[b * NCATS + c]) * INDIVE + (d - SHARED_E)];
    xflat[(size_t)b * FLATN + r] = v;
}

// ---------------- cont projection: xflat[:, 1024:1040] ----------------
__global__ __launch_bounds__(256) void cont_proj(
    const float* __restrict__ x_cont, const float* __restrict__ cw,
    const float* __restrict__ cb, float* __restrict__ xflat)
{
    int idx = blockIdx.x * 256 + threadIdx.x;      // mc*16 total
    int b = idx >> 4, j = idx & 15;
    float acc = cb[j];
#pragma unroll
    for (int k = 0; k < 16; ++k) acc += x_cont[b * 16 + k] * cw[k * 16 + j];
    xflat[(size_t)b * FLATN + 1024 + j] = acc;
}

// ---------------- micro encoder: 2 tokens, 1 wave / sample ----------------
__global__ __launch_bounds__(64) void micro_enc(
    float* __restrict__ xflat,
    const float* __restrict__ qkv_w, const float* __restrict__ out_w,
    const float* __restrict__ ln1w, const float* __restrict__ ln1b,
    const float* __restrict__ ln2w, const float* __restrict__ ln2b,
    const float* __restrict__ w1, const float* __restrict__ b1,
    const float* __restrict__ w2, const float* __restrict__ b2)
{
    int b = blockIdx.x;
    int lane = threadIdx.x;
    __shared__ float X[2][64], XN[2][64], QKV[2][192], OO[2][64], FF[2][256];
    __shared__ float PREV[16], ATTN[16];

    float* xrow = xflat + (size_t)b * FLATN;
    X[0][lane] = xrow[lane];
    X[1][lane] = xrow[64 + lane];
    if (lane < 16) PREV[lane] = 0.f;
    __syncthreads();

    for (int p = 0; p < 2; ++p) {
        const float* qw  = qkv_w + p * 64 * 192;
        const float* ow  = out_w + p * 64 * 64;
        const float* l1w = ln1w + p * 64; const float* l1b = ln1b + p * 64;
        const float* l2w = ln2w + p * 64; const float* l2b = ln2b + p * 64;
        const float* fw1 = w1 + p * 64 * 256; const float* fb1 = b1 + p * 256;
        const float* fw2 = w2 + p * 256 * 64; const float* fb2 = b2 + p * 64;

#pragma unroll
        for (int t = 0; t < 2; ++t) {
            float v = X[t][lane];
            float m = wsum(v) * (1.f / 64.f);
            float d = v - m;
            float var = wsum(d * d) * (1.f / 64.f);
            XN[t][lane] = d * rsqrtf(var + EPSV) * l1w[lane] + l1b[lane];
        }
        __syncthreads();

        for (int cc = 0; cc < 3; ++cc) {
            int c = lane + cc * 64;
            float a0 = 0.f, a1 = 0.f;
            for (int k = 0; k < 64; k += 4) {
                float wv[4];
#pragma unroll
                for (int u = 0; u < 4; ++u) wv[u] = qw[(k + u) * 192 + c];
#pragma unroll
                for (int u = 0; u < 4; ++u) { a0 += XN[0][k + u] * wv[u]; a1 += XN[1][k + u] * wv[u]; }
            }
            QKV[0][c] = a0; QKV[1][c] = a1;
        }
        __syncthreads();

        if (lane < 16) {
            int h = lane >> 2, i = (lane >> 1) & 1, j = lane & 1;
            float s = 0.f;
#pragma unroll
            for (int d = 0; d < 16; ++d)
                s += QKV[i][h * 16 + d] * QKV[j][64 + h * 16 + d];
            s = s * 0.25f + PREV[lane];
            PREV[lane] = s;
        }
        __syncthreads();
        if (lane < 16) {
            int base = lane & ~1;
            float s0 = PREV[base], s1 = PREV[base + 1];
            float mx = fmaxf(s0, s1);
            float e0 = expf(s0 - mx), e1 = expf(s1 - mx);
            float inv = 1.f / (e0 + e1);
            ATTN[lane] = (lane & 1) ? e1 * inv : e0 * inv;
        }
        __syncthreads();

        {
            int h = lane >> 4;
#pragma unroll
            for (int t = 0; t < 2; ++t)
                OO[t][lane] = ATTN[h * 4 + t * 2 + 0] * QKV[0][128 + lane]
                            + ATTN[h * 4 + t * 2 + 1] * QKV[1][128 + lane];
        }
        __syncthreads();

        {
            float a0 = 0.f, a1 = 0.f;
            for (int k = 0; k < 64; k += 4) {
                float wv[4];
#pragma unroll
                for (int u = 0; u < 4; ++u) wv[u] = ow[(k + u) * 64 + lane];
#pragma unroll
                for (int u = 0; u < 4; ++u) { a0 += OO[0][k + u] * wv[u]; a1 += OO[1][k + u] * wv[u]; }
            }
            X[0][lane] += a0; X[1][lane] += a1;
        }
        __syncthreads();

#pragma unroll
        for (int t = 0; t < 2; ++t) {
            float v = X[t][lane];
            float m = wsum(v) * (1.f / 64.f);
            float d = v - m;
            float var = wsum(d * d) * (1.f / 64.f);
            XN[t][lane] = d * rsqrtf(var + EPSV) * l2w[lane] + l2b[lane];
        }
        __syncthreads();

        for (int cc = 0; cc < 4; ++cc) {
            int c = lane + cc * 64;
            float a0 = fb1[c], a1 = fb1[c];
            for (int k = 0; k < 64; k += 4) {
                float wv[4];
#pragma unroll
                for (int u = 0; u < 4; ++u) wv[u] = fw1[(k + u) * 256 + c];
#pragma unroll
                for (int u = 0; u < 4; ++u) { a0 += XN[0][k + u] * wv[u]; a1 += XN[1][k + u] * wv[u]; }
            }
            FF[0][c] = gelu_f(a0); FF[1][c] = gelu_f(a1);
        }
        __syncthreads();

        {
            float a0 = fb2[lane], a1 = fb2[lane];
            for (int k = 0; k < 256; k += 4) {
                float wv[4];
#pragma unroll
                for (int u = 0; u < 4; ++u) wv[u] = fw2[(k + u) * 64 + lane];
#pragma unroll
                for (int u = 0; u < 4; ++u) { a0 += FF[0][k + u] * wv[u]; a1 += FF[1][k + u] * wv[u]; }
            }
            X[0][lane] += a0; X[1][lane] += a1;
        }
        __syncthreads();
    }

    xrow[lane]      = X[0][lane];
    xrow[64 + lane] = X[1][lane];
}

// ---------------- macro encoder (MFMA): 4 samples / block, wave = sample ----------------
// LDS 53.2KB -> 3 blocks/CU. Buffers: Xr (residual, padded), XN (LN out / attn O),
// KVb (K|V, later ff1 output), Qb (Q only). Also emits Abf.
__global__ __launch_bounds__(256) void macro_enc_mfma(
    float* __restrict__ xflat, __hip_bfloat16* __restrict__ Abf,
    const short* __restrict__ wT,
    const float* __restrict__ ln1w, const float* __restrict__ ln1b,
    const float* __restrict__ ln2w, const float* __restrict__ ln2b,
    const float* __restrict__ b1, const float* __restrict__ b2)
{
    __shared__ __align__(16) float Xr[64][68];    // 17408 B (pad 68: 2-way banks)
    __shared__ __align__(16) short XN[64][72];    //  9216 B
    __shared__ __align__(16) short KVb[64][136];  // 17408 B: K cols 0-63, V 64-127; later ff1
    __shared__ __align__(16) short Qb[64][72];    //  9216 B

    int tid = threadIdx.x;
    int lane = tid & 63, w = tid >> 6;
    int b0 = blockIdx.x * 4;

    {
        int r = tid >> 2, c0 = (tid & 3) * 16;
        const float* gx = xflat + (size_t)(b0 + (r >> 4)) * FLATN + (r & 15) * 64 + c0;
#pragma unroll
        for (int u = 0; u < 4; ++u) *(float4*)&Xr[r][c0 + u * 4] = *(const float4*)(gx + u * 4);
    }
    __syncthreads();

    int fr = lane & 15, fk = lane >> 4;
    int rb = w * 16 + 4 * fk;
    float prev[16];
#pragma unroll
    for (int j = 0; j < 16; ++j) prev[j] = 0.f;

    for (int p = 0; p < 2; ++p) {
        const short* lq  = wT + p * 49152;
        const short* lo  = lq + 12288;
        const short* lf1 = lo + 4096;
        const short* lf2 = lf1 + 16384;
        const float* l1w = ln1w + p * 64; const float* l1b = ln1b + p * 64;
        const float* l2w = ln2w + p * 64; const float* l2b = ln2b + p * 64;
        const float* fb1 = b1 + p * 256;  const float* fb2 = b2 + p * 64;

        {   // LN1 -> XN
            float wv = l1w[lane], bv = l1b[lane];
#pragma unroll
            for (int i = 0; i < 16; ++i) {
                int r = w * 16 + i;
                float v = Xr[r][lane];
                float m = wsum(v) * (1.f / 64.f);
                float d = v - m;
                float var = wsum(d * d) * (1.f / 64.f);
                XN[r][lane] = f2bf_s(d * rsqrtf(var + EPSV) * wv + bv);
            }
        }
        __syncthreads();

        {   // qkv MFMA: nf 0-3 -> Qb, nf 4-11 -> KVb
            bf16x8 a0 = *(const bf16x8*)&XN[w * 16 + fr][fk * 8];
            bf16x8 a1 = *(const bf16x8*)&XN[w * 16 + fr][fk * 8 + 32];
#pragma unroll
            for (int nf = 0; nf < 12; ++nf) {
                const short* bp = lq + (nf * 16 + fr) * 64 + fk * 8;
                bf16x8 bv0 = *(const bf16x8*)bp;
                bf16x8 bv1 = *(const bf16x8*)(bp + 32);
                f32x4 acc = {};
                acc = __builtin_amdgcn_mfma_f32_16x16x32_bf16(a0, bv0, acc, 0, 0, 0);
                acc = __builtin_amdgcn_mfma_f32_16x16x32_bf16(a1, bv1, acc, 0, 0, 0);
                int cc = nf * 16 + fr;
#pragma unroll
                for (int rr = 0; rr < 4; ++rr) {
                    if (nf < 4) Qb[rb + rr][cc] = f2bf_s(acc[rr]);
                    else        KVb[rb + rr][cc - 64] = f2bf_s(acc[rr]);
                }
            }
        }
        __syncthreads();

        {   // attention in registers: thread = (sample=w, head=fk&3, qi=fr)
            int h = fk & 3;
            int qi = fr;
            int qrow = w * 16 + qi;
            float q[16];
            const unsigned int* qp = (const unsigned int*)&Qb[qrow][h * 16];
#pragma unroll
            for (int e = 0; e < 8; ++e) {
                unsigned int u = qp[e];
                q[2 * e]     = __uint_as_float(u << 16);
                q[2 * e + 1] = __uint_as_float(u & 0xffff0000u);
            }
            float sc[16];
#pragma unroll
            for (int j = 0; j < 16; ++j) {
                const unsigned int* kp = (const unsigned int*)&KVb[w * 16 + j][h * 16];
                float a = 0.f;
#pragma unroll
                for (int e = 0; e < 8; ++e) {
                    unsigned int u = kp[e];
                    a += q[2 * e] * __uint_as_float(u << 16)
                       + q[2 * e + 1] * __uint_as_float(u & 0xffff0000u);
                }
                a = a * 0.25f + prev[j];
                prev[j] = a;
                sc[j] = a;
            }
            float mx = sc[0];
#pragma unroll
            for (int j = 1; j < 16; ++j) mx = fmaxf(mx, sc[j]);
            float sum = 0.f;
#pragma unroll
            for (int j = 0; j < 16; ++j) { sc[j] = expf(sc[j] - mx); sum += sc[j]; }
            float inv = 1.f / sum;
            float o[16];
#pragma unroll
            for (int d = 0; d < 16; ++d) o[d] = 0.f;
#pragma unroll
            for (int j = 0; j < 16; ++j) {
                float a = sc[j] * inv;
                const unsigned int* vp = (const unsigned int*)&KVb[w * 16 + j][64 + h * 16];
#pragma unroll
                for (int e = 0; e < 8; ++e) {
                    unsigned int u = vp[e];
                    o[2 * e]     += a * __uint_as_float(u << 16);
                    o[2 * e + 1] += a * __uint_as_float(u & 0xffff0000u);
                }
            }
            unsigned int* op = (unsigned int*)&XN[qrow][h * 16];
#pragma unroll
            for (int e = 0; e < 8; ++e) op[e] = packbf(o[2 * e], o[2 * e + 1]);
        }
        __syncthreads();

        {   // out proj + residual
            bf16x8 a0 = *(const bf16x8*)&XN[w * 16 + fr][fk * 8];
            bf16x8 a1 = *(const bf16x8*)&XN[w * 16 + fr][fk * 8 + 32];
#pragma unroll
            for (int nf = 0; nf < 4; ++nf) {
                const short* bp = lo + (nf * 16 + fr) * 64 + fk * 8;
                bf16x8 bv0 = *(const bf16x8*)bp;
                bf16x8 bv1 = *(const bf16x8*)(bp + 32);
                f32x4 acc = {};
                acc = __builtin_amdgcn_mfma_f32_16x16x32_bf16(a0, bv0, acc, 0, 0, 0);
                acc = __builtin_amdgcn_mfma_f32_16x16x32_bf16(a1, bv1, acc, 0, 0, 0);
                int cc = nf * 16 + fr;
#pragma unroll
                for (int rr = 0; rr < 4; ++rr) Xr[rb + rr][cc] += acc[rr];
            }
        }
        __syncthreads();

        {   // LN2 -> XN
            float wv = l2w[lane], bv = l2b[lane];
#pragma unroll
            for (int i = 0; i < 16; ++i) {
                int r = w * 16 + i;
                float v = Xr[r][lane];
                float m = wsum(v) * (1.f / 64.f);
                float d = v - m;
                float var = wsum(d * d) * (1.f / 64.f);
                XN[r][lane] = f2bf_s(d * rsqrtf(var + EPSV) * wv + bv);
            }
        }
        __syncthreads();

        {   // FFN: ff1 halves -> KVb (K/V dead), ff2 acc in regs
            bf16x8 a0 = *(const bf16x8*)&XN[w * 16 + fr][fk * 8];
            bf16x8 a1 = *(const bf16x8*)&XN[w * 16 + fr][fk * 8 + 32];
            f32x4 facc[4] = {};
#pragma unroll
            for (int half = 0; half < 2; ++half) {
#pragma unroll
                for (int nf = 0; nf < 8; ++nf) {
                    int ng = half * 128 + nf * 16;
                    const short* bp = lf1 + (ng + fr) * 64 + fk * 8;
                    bf16x8 bv0 = *(const bf16x8*)bp;
                    bf16x8 bv1 = *(const bf16x8*)(bp + 32);
                    f32x4 acc = {};
                    acc = __builtin_amdgcn_mfma_f32_16x16x32_bf16(a0, bv0, acc, 0, 0, 0);
                    acc = __builtin_amdgcn_mfma_f32_16x16x32_bf16(a1, bv1, acc, 0, 0, 0);
                    int cc = nf * 16 + fr;
                    float bias1 = fb1[ng + fr];
#pragma unroll
                    for (int rr = 0; rr < 4; ++rr)
                        KVb[rb + rr][cc] = f2bf_s(gelu_f(acc[rr] + bias1));
                }
                __syncthreads();
                bf16x8 fa[4];
#pragma unroll
                for (int kf = 0; kf < 4; ++kf)
                    fa[kf] = *(const bf16x8*)&KVb[w * 16 + fr][kf * 32 + fk * 8];
#pragma unroll
                for (int nf = 0; nf < 4; ++nf) {
                    const short* bp = lf2 + (nf * 16 + fr) * 256 + half * 128 + fk * 8;
#pragma unroll
                    for (int kf = 0; kf < 4; ++kf)
                        facc[nf] = __builtin_amdgcn_mfma_f32_16x16x32_bf16(
                            fa[kf], *(const bf16x8*)(bp + kf * 32), facc[nf], 0, 0, 0);
                }
                __syncthreads();
            }
#pragma unroll
            for (int nf = 0; nf < 4; ++nf) {
                int cc = nf * 16 + fr;
                float bias2 = fb2[cc];
#pragma unroll
                for (int rr = 0; rr < 4; ++rr) Xr[rb + rr][cc] += facc[nf][rr] + bias2;
            }
        }
        __syncthreads();
    }

    // store residual (fp32) + bf16 token part of Abf
    {
        int r = tid >> 2, c0 = (tid & 3) * 16;
        int b = b0 + (r >> 4);
        float* gx = xflat + (size_t)b * FLATN + (r & 15) * 64 + c0;
#pragma unroll
        for (int u = 0; u < 4; ++u) *(float4*)(gx + u * 4) = *(const float4*)&Xr[r][c0 + u * 4];
        unsigned int pk[8];
#pragma unroll
        for (int e = 0; e < 8; ++e) pk[e] = packbf(Xr[r][c0 + 2 * e], Xr[r][c0 + 2 * e + 1]);
        unsigned int* ga = (unsigned int*)(Abf + (size_t)b * KP1 + (r & 15) * 64 + c0);
#pragma unroll
        for (int e = 0; e < 8; ++e) ga[e] = pk[e];
    }
    {
        int s = tid >> 6, c = tid & 63;
        int b = b0 + s;
        float v = (c < CONTN) ? xflat[(size_t)b * FLATN + 1024 + c] : 0.f;
        Abf[(size_t)b * KP1 + 1024 + c] = __float2bfloat16(v);
    }
}

// ---------------- transpose + convert: W[K][N] fp32 -> Wt[Np][Kp] bf16 (zero-padded) ----
__global__ __launch_bounds__(256) void transpose_conv(
    const float* __restrict__ src, __hip_bfloat16* __restrict__ dst,
    int K, int N, int Kp, int Np)
{
    __shared__ float T[32][33];
    int k0 = blockIdx.y * 32, n0 = blockIdx.x * 32;
    int tn = threadIdx.x & 31, tk = threadIdx.x >> 5;
#pragma unroll
    for (int r = 0; r < 4; ++r) {
        int k = k0 + tk + r * 8, n = n0 + tn;
        T[tk + r * 8][tn] = (k < K && n < N) ? src[(size_t)k * N + n] : 0.f;
    }
    __syncthreads();
#pragma unroll
    for (int r = 0; r < 4; ++r) {
        int n = n0 + tk + r * 8, k = k0 + tn;
        dst[(size_t)n * Kp + k] = __float2bfloat16(T[tn][tk + r * 8]);
    }
}

// ---------------- bf16 MFMA GEMM: 128x128x64, dbuf prefetch + T2 swizzle ----------------
// A: [M][Kp] bf16; Bt: [Np][Kp] bf16 (= W^T).
// T2 (rule #21): linear LDS dest (gload_lds) + pre-swizzled GLOBAL k-slot
// (lane&7)^(lane>>3) + same XOR on the fragment-read slot -> 2-way banks (free).
// T3-min: stage next tile BEFORE compute, one __syncthreads per K-step.
// MODE 1: C[M][Np] bf16 gelu, coalesced via slot-swizzled LDS restage.
// MODE 2: partials[row][bx] = sum_cols gelu(.)*w3[col] (fused final dot).
template <int MODE>
__global__ __launch_bounds__(256) void gemm_mfma(
    const __hip_bfloat16* __restrict__ A, const __hip_bfloat16* __restrict__ Bt,
    const float* __restrict__ bias, int bias_n,
    __hip_bfloat16* __restrict__ Cbf, const float* __restrict__ w3,
    float* __restrict__ partials, int Np, int Kp)
{
    __shared__ __align__(16) short LDSbuf[32768];   // 64KB: buf{0,1} x (A 8192 | B 8192 shorts)

    int tid = threadIdx.x;
    int lane = tid & 63, wave = tid >> 6;

    // bijective XCD swizzle (m204)
    int nbx = gridDim.x;
    int nwg = nbx * gridDim.y;
    int wgid = blockIdx.y * nbx + blockIdx.x;
    int q = nwg >> 3, r = nwg & 7;
    int xcd = wgid & 7, loc = wgid >> 3;
    int sw = (xcd < r ? xcd * (q + 1) : r * (q + 1) + (xcd - r) * q) + loc;
    int bm = (sw / nbx) * 128, bx = sw % nbx, bn = bx * 128;

    // staging addresses: lane l -> row (l>>3), k-slot (l&7)^(l>>3)  [T2 pre-swizzle]
    int lrow8 = lane >> 3;
    int lk8sw = ((lane & 7) ^ lrow8) * 8;
    const __hip_bfloat16* Ag = A  + (size_t)(bm + wave * 32 + lrow8) * Kp + lk8sw;
    const __hip_bfloat16* Bg = Bt + (size_t)(bn + wave * 32 + lrow8) * Kp + lk8sw;

    int wm = (wave >> 1) * 64, wn = (wave & 1) * 64;
    int lrow = lane & 15, lk = lane >> 4;
    int key = lane & 7;                     // = (row&7) for this lane's fragment rows

    f32x4 acc[4][4] = {};
    int nt = Kp >> 6;

    // prologue: stage tile 0 into buf 0
    {
        short* Al = LDSbuf + wave * 32 * 64;
        short* Bl = Al + 8192;
#pragma unroll
        for (int it = 0; it < 4; ++it) {
            gload16(Ag + (size_t)(it * 8) * Kp, Al + it * 8 * 64);
            gload16(Bg + (size_t)(it * 8) * Kp, Bl + it * 8 * 64);
        }
    }
    __syncthreads();

    for (int t = 0; t < nt; ++t) {
        int cur = (t & 1) << 14;            // *16384 shorts
        if (t + 1 < nt) {
            int k0 = (t + 1) << 6;
            short* Al = LDSbuf + (((t + 1) & 1) << 14) + wave * 32 * 64;
            short* Bl = Al + 8192;
#pragma unroll
            for (int it = 0; it < 4; ++it) {
                gload16(Ag + (size_t)(it * 8) * Kp + k0, Al + it * 8 * 64);
                gload16(Bg + (size_t)(it * 8) * Kp + k0, Bl + it * 8 * 64);
            }
        }
        const short* Ab = LDSbuf + cur;
        const short* Bb = Ab + 8192;
#pragma unroll
        for (int ks = 0; ks < 2; ++ks) {
            int so = ((ks * 4 + lk) ^ key) * 8;     // swizzled slot offset (shorts)
            bf16x8 af[4], bf[4];
#pragma unroll
            for (int i = 0; i < 4; ++i) af[i] = *(const bf16x8*)(Ab + (wm + i * 16 + lrow) * 64 + so);
#pragma unroll
            for (int j = 0; j < 4; ++j) bf[j] = *(const bf16x8*)(Bb + (wn + j * 16 + lrow) * 64 + so);
#pragma unroll
            for (int i = 0; i < 4; ++i)
#pragma unroll
                for (int j = 0; j < 4; ++j)
                    acc[i][j] = __builtin_amdgcn_mfma_f32_16x16x32_bf16(af[i], bf[j], acc[i][j], 0, 0, 0);
        }
        __syncthreads();   // drains prefetch (issued before compute -> latency hidden)
    }

    if (MODE == 1) {
        // slot-swizzled LDS restage -> full-line coalesced bf16 stores
        short* Cs = LDSbuf;                 // [128][128] shorts, slot = 8 shorts
#pragma unroll
        for (int j = 0; j < 4; ++j) {
            int cl = wn + j * 16 + lrow;
            float bv = (bn + cl < bias_n) ? bias[bn + cl] : 0.f;
#pragma unroll
            for (int i = 0; i < 4; ++i) {
#pragma unroll
                for (int rr = 0; rr < 4; ++rr) {
                    int rl = wm + i * 16 + 4 * lk + rr;
                    int pos = ((((cl >> 3) ^ (rl & 7)) << 3) | (cl & 7));
                    Cs[rl * 128 + pos] = f2bf_s(gelu_f(acc[i][j][rr] + bv));
                }
            }
        }
        __syncthreads();
        int rloc = tid >> 1, half = tid & 1;
        int4* dst = (int4*)(Cbf + (size_t)(bm + rloc) * Np + bn + half * 64);
#pragma unroll
        for (int u = 0; u < 8; ++u) {
            int slot = half * 8 + (u ^ (rloc & 7));
            dst[u] = *(const int4*)&Cs[rloc * 128 + slot * 8];
        }
    } else {
        // fused w3 reduction
        float rs[16];
#pragma unroll
        for (int t = 0; t < 16; ++t) rs[t] = 0.f;
#pragma unroll
        for (int j = 0; j < 4; ++j) {
            int gcol = bn + wn + j * 16 + lrow;
            float bv  = (gcol < bias_n) ? bias[gcol] : 0.f;
            float w3v = (gcol < H2N) ? w3[gcol] : 0.f;
#pragma unroll
            for (int i = 0; i < 4; ++i)
#pragma unroll
                for (int rr = 0; rr < 4; ++rr)
                    rs[i * 4 + rr] += gelu_f(acc[i][j][rr] + bv) * w3v;
        }
#pragma unroll
        for (int o = 1; o < 16; o <<= 1)
#pragma unroll
            for (int t = 0; t < 16; ++t) rs[t] += __shfl_xor(rs[t], o, 64);
        float* pr = (float*)LDSbuf;         // [128][2]
        if (lrow == 0) {
#pragma unroll
            for (int i = 0; i < 4; ++i)
#pragma unroll
                for (int rr = 0; rr < 4; ++rr)
                    pr[(wm + i * 16 + 4 * lk + rr) * 2 + (wave & 1)] = rs[i * 4 + rr];
        }
        __syncthreads();
        if (tid < 128)
            partials[(size_t)(bm + tid) * nbx + bx] = pr[tid * 2] + pr[tid * 2 + 1];
    }
}

// ---------------- logits = b3 + sum over N-tiles of partials ----------------
__global__ __launch_bounds__(256) void reduce_partials(
    const float* __restrict__ partials, const float* __restrict__ b3,
    float* __restrict__ out, int n, int nbx)
{
    int b = blockIdx.x * 256 + threadIdx.x;
    if (b >= n) return;
    float s = b3[0];
    for (int x = 0; x < nbx; ++x) s += partials[(size_t)b * nbx + x];
    out[b] = s;
}

extern "C" void kernel_launch(void* const* d_in, const int* in_sizes, int n_in,
                              void* d_out, int out_size, void* d_ws, size_t ws_size,
                              hipStream_t stream)
{
    const int*   x_cat      = (const int*)  d_in[0];
    const float* x_cont     = (const float*)d_in[1];
    const float* shared_emb = (const float*)d_in[2];
    const float* emb        = (const float*)d_in[3];
    const float* mi_qkv  = (const float*)d_in[4];
    const float* mi_out  = (const float*)d_in[5];
    const float* mi_ln1w = (const float*)d_in[6];
    const float* mi_ln1b = (const float*)d_in[7];
    const float* mi_ln2w = (const float*)d_in[8];
    const float* mi_ln2b = (const float*)d_in[9];
    const float* mi_w1   = (const float*)d_in[10];
    const float* mi_b1   = (const float*)d_in[11];
    const float* mi_w2   = (const float*)d_in[12];
    const float* mi_b2   = (const float*)d_in[13];
    const float* ma_qkv  = (const float*)d_in[14];
    const float* ma_out  = (const float*)d_in[15];
    const float* ma_ln1w = (const float*)d_in[16];
    const float* ma_ln1b = (const float*)d_in[17];
    const float* ma_ln2w = (const float*)d_in[18];
    const float* ma_ln2b = (const float*)d_in[19];
    const float* ma_w1   = (const float*)d_in[20];
    const float* ma_b1   = (const float*)d_in[21];
    const float* ma_w2   = (const float*)d_in[22];
    const float* ma_b2   = (const float*)d_in[23];
    const float* cont_w  = (const float*)d_in[24];
    const float* cont_b  = (const float*)d_in[25];
    const float* w1      = (const float*)d_in[26];
    const float* b1      = (const float*)d_in[27];
    const float* w2      = (const float*)d_in[28];
    const float* b2      = (const float*)d_in[29];
    const float* w3      = (const float*)d_in[30];
    const float* b3      = (const float*)d_in[31];
    float* out = (float*)d_out;

    const int NBX2 = NP2 / 128;          // 17 N-tiles in GEMM2
    const size_t ENC_SH = 2 * 49152;
    const size_t FIXED = ((size_t)NP1 * KP1 + (size_t)NP2 * KP2 + ENC_SH) * 2;
    const size_t PER_ROW = (size_t)NP1 * 2 + (size_t)FLATN * 4 + (size_t)KP1 * 2 + (size_t)NBX2 * 4;
    size_t avail = (ws_size > FIXED) ? ws_size - FIXED : 0;
    long long chl = (long long)(avail / PER_ROW);
    int CH = (int)((chl / 128) * 128);
    if (CH > BATCH) CH = BATCH;
    if (CH < 128) CH = 128;

    char* p = (char*)d_ws;
    __hip_bfloat16* w1T = (__hip_bfloat16*)p; p += (size_t)NP1 * KP1 * 2;
    __hip_bfloat16* w2T = (__hip_bfloat16*)p; p += (size_t)NP2 * KP2 * 2;
    __hip_bfloat16* encT = (__hip_bfloat16*)p; p += ENC_SH * 2;
    __hip_bfloat16* h1  = (__hip_bfloat16*)p; p += (size_t)CH * NP1 * 2;
    float* xflat = (float*)p;                 p += (size_t)CH * FLATN * 4;
    __hip_bfloat16* Abf = (__hip_bfloat16*)p; p += (size_t)CH * KP1 * 2;
    float* partials = (float*)p;

    transpose_conv<<<dim3(NP1 / 32, KP1 / 32), 256, 0, stream>>>(w1, w1T, FLATN, H1N, KP1, NP1);
    transpose_conv<<<dim3(NP2 / 32, KP2 / 32), 256, 0, stream>>>(w2, w2T, H1N, H2N, KP2, NP2);

    for (int pl = 0; pl < 2; ++pl) {
        __hip_bfloat16* base = encT + (size_t)pl * 49152;
        transpose_conv<<<dim3(192 / 32, 64 / 32), 256, 0, stream>>>(
            ma_qkv + pl * 64 * 192, base, 64, 192, 64, 192);
        transpose_conv<<<dim3(64 / 32, 64 / 32), 256, 0, stream>>>(
            ma_out + pl * 64 * 64, base + 12288, 64, 64, 64, 64);
        transpose_conv<<<dim3(256 / 32, 64 / 32), 256, 0, stream>>>(
            ma_w1 + pl * 64 * 256, base + 16384, 64, 256, 64, 256);
        transpose_conv<<<dim3(64 / 32, 256 / 32), 256, 0, stream>>>(
            ma_w2 + pl * 256 * 64, base + 32768, 256, 64, 256, 64);
    }

    for (int m0 = 0; m0 < BATCH; m0 += CH) {
        int mc = BATCH - m0 < CH ? BATCH - m0 : CH;   // multiple of 128

        build_tokens<<<(mc * 1024) / 256, 256, 0, stream>>>(
            x_cat + (size_t)m0 * NCATS, shared_emb, emb, xflat);
        cont_proj<<<(mc * 16) / 256, 256, 0, stream>>>(
            x_cont + (size_t)m0 * CONTN, cont_w, cont_b, xflat);
        micro_enc<<<mc, 64, 0, stream>>>(xflat, mi_qkv, mi_out, mi_ln1w, mi_ln1b,
                                         mi_ln2w, mi_ln2b, mi_w1, mi_b1, mi_w2, mi_b2);
        macro_enc_mfma<<<mc / 4, 256, 0, stream>>>(
            xflat, Abf, (const short*)encT, ma_ln1w, ma_ln1b, ma_ln2w, ma_ln2b, ma_b1, ma_b2);

        gemm_mfma<1><<<dim3(NP1 / 128, mc / 128), 256, 0, stream>>>(
            Abf, w1T, b1, H1N, h1, nullptr, nullptr, NP1, KP1);
        gemm_mfma<2><<<dim3(NBX2, mc / 128), 256, 0, stream>>>(
            h1, w2T, b2, H2N, nullptr, w3, partials, NP2, KP2);

        reduce_partials<<<(mc + 255) / 256, 256, 0, stream>>>(partials, b3, out + m0, mc, NBX2);
    }
}

// Round 8
// 2303.987 us; speedup vs baseline: 4.0656x; 1.0657x over previous
//
#include <hip/hip_runtime.h>
#include <hip/hip_bf16.h>
#include <math.h>

#define BATCH  16384
#define NCATS  16
#define VOCABN 1000
#define DIMD   64
#define SHARED_E 10
#define INDIVE 54
#define CONTN  16
#define FLATN  1040   // NCATS*DIMD + CONTN
#define H1N    4160
#define H2N    2080
#define KP1    1088   // FLATN padded to mult of 64
#define NP1    4224   // H1N padded to mult of 128
#define KP2    4224   // = NP1 (GEMM2 K)
#define NP2    2176   // H2N padded to mult of 128
#define EPSV   1e-5f

typedef __attribute__((ext_vector_type(8))) short bf16x8;
typedef __attribute__((ext_vector_type(4))) float f32x4;

__device__ __forceinline__ float gelu_f(float x) {
    return 0.5f * x * (1.0f + erff(x * 0.70710678118654752440f));
}
__device__ __forceinline__ float wsum(float v) {
#pragma unroll
    for (int o = 32; o > 0; o >>= 1) v += __shfl_xor(v, o, 64);
    return v;
}
__device__ __forceinline__ short f2bf_s(float a) {
    __hip_bfloat16 x = __float2bfloat16(a);
    return *reinterpret_cast<short*>(&x);
}
__device__ __forceinline__ unsigned int packbf(float a, float b) {
    __hip_bfloat16 x = __float2bfloat16(a), y = __float2bfloat16(b);
    unsigned short ux = *reinterpret_cast<unsigned short*>(&x);
    unsigned short uy = *reinterpret_cast<unsigned short*>(&y);
    return (unsigned)ux | ((unsigned)uy << 16);
}
__device__ __forceinline__ float bf_lo(unsigned int u) { return __uint_as_float(u << 16); }
__device__ __forceinline__ float bf_hi(unsigned int u) { return __uint_as_float(u & 0xffff0000u); }
// async global->LDS, 16B per lane; LDS dest is wave-uniform base + lane*16 (m97)
__device__ __forceinline__ void gload16(const void* g, void* l) {
    __builtin_amdgcn_global_load_lds(
        (const __attribute__((address_space(1))) void*)g,
        (__attribute__((address_space(3))) void*)l, 16, 0, 0);
}

// ---------------- token build: xflat[:, 0:1024] (chunk-local rows) ----------------
__global__ __launch_bounds__(256) void build_tokens(
    const int* __restrict__ x_cat, const float* __restrict__ shared_emb,
    const float* __restrict__ emb, float* __restrict__ xflat)
{
    int idx = blockIdx.x * 256 + threadIdx.x;      // mc*1024 total
    int b = idx >> 10, r = idx & 1023;
    int c = r >> 6, d = r & 63;
    float v;
    if (d < SHARED_E) v = shared_emb[d];
    else              v = emb[((size_t)c * VOCABN + x_cat[b * NCATS + c]) * INDIVE + (d - SHARED_E)];
    xflat[(size_t)b * FLATN + r] = v;
}

// ---------------- cont projection: xflat[:, 1024:1040] ----------------
__global__ __launch_bounds__(256) void cont_proj(
    const float* __restrict__ x_cont, const float* __restrict__ cw,
    const float* __restrict__ cb, float* __restrict__ xflat)
{
    int idx = blockIdx.x * 256 + threadIdx.x;      // mc*16 total
    int b = idx >> 4, j = idx & 15;
    float acc = cb[j];
#pragma unroll
    for (int k = 0; k < 16; ++k) acc += x_cont[b * 16 + k] * cw[k * 16 + j];
    xflat[(size_t)b * FLATN + 1024 + j] = acc;
}

// ---------------- micro encoder: 2 tokens, 1 wave / sample ----------------
__global__ __launch_bounds__(64) void micro_enc(
    float* __restrict__ xflat,
    const float* __restrict__ qkv_w, const float* __restrict__ out_w,
    const float* __restrict__ ln1w, const float* __restrict__ ln1b,
    const float* __restrict__ ln2w, const float* __restrict__ ln2b,
    const float* __restrict__ w1, const float* __restrict__ b1,
    const float* __restrict__ w2, const float* __restrict__ b2)
{
    int b = blockIdx.x;
    int lane = threadIdx.x;
    __shared__ float X[2][64], XN[2][64], QKV[2][192], OO[2][64], FF[2][256];
    __shared__ float PREV[16], ATTN[16];

    float* xrow = xflat + (size_t)b * FLATN;
    X[0][lane] = xrow[lane];
    X[1][lane] = xrow[64 + lane];
    if (lane < 16) PREV[lane] = 0.f;
    __syncthreads();

    for (int p = 0; p < 2; ++p) {
        const float* qw  = qkv_w + p * 64 * 192;
        const float* ow  = out_w + p * 64 * 64;
        const float* l1w = ln1w + p * 64; const float* l1b = ln1b + p * 64;
        const float* l2w = ln2w + p * 64; const float* l2b = ln2b + p * 64;
        const float* fw1 = w1 + p * 64 * 256; const float* fb1 = b1 + p * 256;
        const float* fw2 = w2 + p * 256 * 64; const float* fb2 = b2 + p * 64;

#pragma unroll
        for (int t = 0; t < 2; ++t) {
            float v = X[t][lane];
            float m = wsum(v) * (1.f / 64.f);
            float d = v - m;
            float var = wsum(d * d) * (1.f / 64.f);
            XN[t][lane] = d * rsqrtf(var + EPSV) * l1w[lane] + l1b[lane];
        }
        __syncthreads();

        for (int cc = 0; cc < 3; ++cc) {
            int c = lane + cc * 64;
            float a0 = 0.f, a1 = 0.f;
            for (int k = 0; k < 64; k += 4) {
                float wv[4];
#pragma unroll
                for (int u = 0; u < 4; ++u) wv[u] = qw[(k + u) * 192 + c];
#pragma unroll
                for (int u = 0; u < 4; ++u) { a0 += XN[0][k + u] * wv[u]; a1 += XN[1][k + u] * wv[u]; }
            }
            QKV[0][c] = a0; QKV[1][c] = a1;
        }
        __syncthreads();

        if (lane < 16) {
            int h = lane >> 2, i = (lane >> 1) & 1, j = lane & 1;
            float s = 0.f;
#pragma unroll
            for (int d = 0; d < 16; ++d)
                s += QKV[i][h * 16 + d] * QKV[j][64 + h * 16 + d];
            s = s * 0.25f + PREV[lane];
            PREV[lane] = s;
        }
        __syncthreads();
        if (lane < 16) {
            int base = lane & ~1;
            float s0 = PREV[base], s1 = PREV[base + 1];
            float mx = fmaxf(s0, s1);
            float e0 = expf(s0 - mx), e1 = expf(s1 - mx);
            float inv = 1.f / (e0 + e1);
            ATTN[lane] = (lane & 1) ? e1 * inv : e0 * inv;
        }
        __syncthreads();

        {
            int h = lane >> 4;
#pragma unroll
            for (int t = 0; t < 2; ++t)
                OO[t][lane] = ATTN[h * 4 + t * 2 + 0] * QKV[0][128 + lane]
                            + ATTN[h * 4 + t * 2 + 1] * QKV[1][128 + lane];
        }
        __syncthreads();

        {
            float a0 = 0.f, a1 = 0.f;
            for (int k = 0; k < 64; k += 4) {
                float wv[4];
#pragma unroll
                for (int u = 0; u < 4; ++u) wv[u] = ow[(k + u) * 64 + lane];
#pragma unroll
                for (int u = 0; u < 4; ++u) { a0 += OO[0][k + u] * wv[u]; a1 += OO[1][k + u] * wv[u]; }
            }
            X[0][lane] += a0; X[1][lane] += a1;
        }
        __syncthreads();

#pragma unroll
        for (int t = 0; t < 2; ++t) {
            float v = X[t][lane];
            float m = wsum(v) * (1.f / 64.f);
            float d = v - m;
            float var = wsum(d * d) * (1.f / 64.f);
            XN[t][lane] = d * rsqrtf(var + EPSV) * l2w[lane] + l2b[lane];
        }
        __syncthreads();

        for (int cc = 0; cc < 4; ++cc) {
            int c = lane + cc * 64;
            float a0 = fb1[c], a1 = fb1[c];
            for (int k = 0; k < 64; k += 4) {
                float wv[4];
#pragma unroll
                for (int u = 0; u < 4; ++u) wv[u] = fw1[(k + u) * 256 + c];
#pragma unroll
                for (int u = 0; u < 4; ++u) { a0 += XN[0][k + u] * wv[u]; a1 += XN[1][k + u] * wv[u]; }
            }
            FF[0][c] = gelu_f(a0); FF[1][c] = gelu_f(a1);
        }
        __syncthreads();

        {
            float a0 = fb2[lane], a1 = fb2[lane];
            for (int k = 0; k < 256; k += 4) {
                float wv[4];
#pragma unroll
                for (int u = 0; u < 4; ++u) wv[u] = fw2[(k + u) * 64 + lane];
#pragma unroll
                for (int u = 0; u < 4; ++u) { a0 += FF[0][k + u] * wv[u]; a1 += FF[1][k + u] * wv[u]; }
            }
            X[0][lane] += a0; X[1][lane] += a1;
        }
        __syncthreads();
    }

    xrow[lane]      = X[0][lane];
    xrow[64 + lane] = X[1][lane];
}

// ---------------- macro encoder (MFMA): 1 sample / block, single wave ----------------
// LDS 13.3KB -> ~12 blocks/CU, barriers intra-wave (TLP fix for latency stalls).
// wT per layer: [qkvT 192x64 | outT 64x64 | ff1T 256x64 | ff2T 64x256] bf16.
__global__ __launch_bounds__(64) void macro_enc_mfma(
    float* __restrict__ xflat, __hip_bfloat16* __restrict__ Abf,
    const short* __restrict__ wT,
    const float* __restrict__ ln1w, const float* __restrict__ ln1b,
    const float* __restrict__ ln2w, const float* __restrict__ ln2b,
    const float* __restrict__ b1, const float* __restrict__ b2)
{
    __shared__ __align__(16) float Xr[16][68];    // 4352 B (pad: 2-way banks)
    __shared__ __align__(16) short XN[16][72];    // 2304 B
    __shared__ __align__(16) short KVb[16][136];  // 4352 B: K cols 0-63, V 64-127; later ff1
    __shared__ __align__(16) short Qb[16][72];    // 2304 B

    int lane = threadIdx.x;
    int b = blockIdx.x;

    {   // load residual: 16 rows x 64 cols, 16 floats / lane
        int r = lane >> 2, c0 = (lane & 3) * 16;
        const float* gx = xflat + (size_t)b * FLATN + r * 64 + c0;
#pragma unroll
        for (int u = 0; u < 4; ++u) *(float4*)&Xr[r][c0 + u * 4] = *(const float4*)(gx + u * 4);
    }
    __syncthreads();

    int fr = lane & 15, fk = lane >> 4;
    int rb = 4 * fk;
    float prev[16];
#pragma unroll
    for (int j = 0; j < 16; ++j) prev[j] = 0.f;

    for (int p = 0; p < 2; ++p) {
        const short* lq  = wT + p * 49152;
        const short* lo  = lq + 12288;
        const short* lf1 = lo + 4096;
        const short* lf2 = lf1 + 16384;
        const float* l1w = ln1w + p * 64; const float* l1b = ln1b + p * 64;
        const float* l2w = ln2w + p * 64; const float* l2b = ln2b + p * 64;
        const float* fb1 = b1 + p * 256;  const float* fb2 = b2 + p * 64;

        {   // LN1 -> XN
            float wv = l1w[lane], bv = l1b[lane];
#pragma unroll
            for (int i = 0; i < 16; ++i) {
                float v = Xr[i][lane];
                float m = wsum(v) * (1.f / 64.f);
                float d = v - m;
                float var = wsum(d * d) * (1.f / 64.f);
                XN[i][lane] = f2bf_s(d * rsqrtf(var + EPSV) * wv + bv);
            }
        }
        __syncthreads();

        {   // qkv MFMA: nf 0-3 -> Qb, nf 4-11 -> KVb
            bf16x8 a0 = *(const bf16x8*)&XN[fr][fk * 8];
            bf16x8 a1 = *(const bf16x8*)&XN[fr][fk * 8 + 32];
#pragma unroll
            for (int nf = 0; nf < 12; ++nf) {
                const short* bp = lq + (nf * 16 + fr) * 64 + fk * 8;
                bf16x8 bv0 = *(const bf16x8*)bp;
                bf16x8 bv1 = *(const bf16x8*)(bp + 32);
                f32x4 acc = {};
                acc = __builtin_amdgcn_mfma_f32_16x16x32_bf16(a0, bv0, acc, 0, 0, 0);
                acc = __builtin_amdgcn_mfma_f32_16x16x32_bf16(a1, bv1, acc, 0, 0, 0);
                int cc = nf * 16 + fr;
#pragma unroll
                for (int rr = 0; rr < 4; ++rr) {
                    if (nf < 4) Qb[rb + rr][cc] = f2bf_s(acc[rr]);
                    else        KVb[rb + rr][cc - 64] = f2bf_s(acc[rr]);
                }
            }
        }
        __syncthreads();

        {   // attention in registers: lane = (head=fk, qi=fr); b128 K/V reads (broadcast)
            int h = fk, qi = fr;
            uint4 qv0 = ((const uint4*)&Qb[qi][h * 16])[0];
            uint4 qv1 = ((const uint4*)&Qb[qi][h * 16])[1];
            float q[16];
            {
                unsigned int uu[8] = {qv0.x, qv0.y, qv0.z, qv0.w, qv1.x, qv1.y, qv1.z, qv1.w};
#pragma unroll
                for (int e = 0; e < 8; ++e) { q[2 * e] = bf_lo(uu[e]); q[2 * e + 1] = bf_hi(uu[e]); }
            }
            float sc[16];
#pragma unroll
            for (int j = 0; j < 16; ++j) {
                uint4 k0 = ((const uint4*)&KVb[j][h * 16])[0];
                uint4 k1 = ((const uint4*)&KVb[j][h * 16])[1];
                unsigned int uu[8] = {k0.x, k0.y, k0.z, k0.w, k1.x, k1.y, k1.z, k1.w};
                float a = 0.f;
#pragma unroll
                for (int e = 0; e < 8; ++e)
                    a += q[2 * e] * bf_lo(uu[e]) + q[2 * e + 1] * bf_hi(uu[e]);
                a = a * 0.25f + prev[j];
                prev[j] = a;
                sc[j] = a;
            }
            float mx = sc[0];
#pragma unroll
            for (int j = 1; j < 16; ++j) mx = fmaxf(mx, sc[j]);
            float sum = 0.f;
#pragma unroll
            for (int j = 0; j < 16; ++j) { sc[j] = expf(sc[j] - mx); sum += sc[j]; }
            float inv = 1.f / sum;
            float o[16];
#pragma unroll
            for (int d = 0; d < 16; ++d) o[d] = 0.f;
#pragma unroll
            for (int j = 0; j < 16; ++j) {
                float a = sc[j] * inv;
                uint4 v0 = ((const uint4*)&KVb[j][64 + h * 16])[0];
                uint4 v1 = ((const uint4*)&KVb[j][64 + h * 16])[1];
                unsigned int uu[8] = {v0.x, v0.y, v0.z, v0.w, v1.x, v1.y, v1.z, v1.w};
#pragma unroll
                for (int e = 0; e < 8; ++e) {
                    o[2 * e]     += a * bf_lo(uu[e]);
                    o[2 * e + 1] += a * bf_hi(uu[e]);
                }
            }
            unsigned int* op = (unsigned int*)&XN[qi][h * 16];
#pragma unroll
            for (int e = 0; e < 8; ++e) op[e] = packbf(o[2 * e], o[2 * e + 1]);
        }
        __syncthreads();

        {   // out proj + residual
            bf16x8 a0 = *(const bf16x8*)&XN[fr][fk * 8];
            bf16x8 a1 = *(const bf16x8*)&XN[fr][fk * 8 + 32];
#pragma unroll
            for (int nf = 0; nf < 4; ++nf) {
                const short* bp = lo + (nf * 16 + fr) * 64 + fk * 8;
                bf16x8 bv0 = *(const bf16x8*)bp;
                bf16x8 bv1 = *(const bf16x8*)(bp + 32);
                f32x4 acc = {};
                acc = __builtin_amdgcn_mfma_f32_16x16x32_bf16(a0, bv0, acc, 0, 0, 0);
                acc = __builtin_amdgcn_mfma_f32_16x16x32_bf16(a1, bv1, acc, 0, 0, 0);
                int cc = nf * 16 + fr;
#pragma unroll
                for (int rr = 0; rr < 4; ++rr) Xr[rb + rr][cc] += acc[rr];
            }
        }
        __syncthreads();

        {   // LN2 -> XN
            float wv = l2w[lane], bv = l2b[lane];
#pragma unroll
            for (int i = 0; i < 16; ++i) {
                float v = Xr[i][lane];
                float m = wsum(v) * (1.f / 64.f);
                float d = v - m;
                float var = wsum(d * d) * (1.f / 64.f);
                XN[i][lane] = f2bf_s(d * rsqrtf(var + EPSV) * wv + bv);
            }
        }
        __syncthreads();

        {   // FFN: ff1 halves -> KVb (K/V dead), ff2 acc in regs
            bf16x8 a0 = *(const bf16x8*)&XN[fr][fk * 8];
            bf16x8 a1 = *(const bf16x8*)&XN[fr][fk * 8 + 32];
            f32x4 facc[4] = {};
#pragma unroll
            for (int half = 0; half < 2; ++half) {
#pragma unroll
                for (int nf = 0; nf < 8; ++nf) {
                    int ng = half * 128 + nf * 16;
                    const short* bp = lf1 + (ng + fr) * 64 + fk * 8;
                    bf16x8 bv0 = *(const bf16x8*)bp;
                    bf16x8 bv1 = *(const bf16x8*)(bp + 32);
                    f32x4 acc = {};
                    acc = __builtin_amdgcn_mfma_f32_16x16x32_bf16(a0, bv0, acc, 0, 0, 0);
                    acc = __builtin_amdgcn_mfma_f32_16x16x32_bf16(a1, bv1, acc, 0, 0, 0);
                    int cc = nf * 16 + fr;
                    float bias1 = fb1[ng + fr];
#pragma unroll
                    for (int rr = 0; rr < 4; ++rr)
                        KVb[rb + rr][cc] = f2bf_s(gelu_f(acc[rr] + bias1));
                }
                __syncthreads();
                bf16x8 fa[4];
#pragma unroll
                for (int kf = 0; kf < 4; ++kf)
                    fa[kf] = *(const bf16x8*)&KVb[fr][kf * 32 + fk * 8];
#pragma unroll
                for (int nf = 0; nf < 4; ++nf) {
                    const short* bp = lf2 + (nf * 16 + fr) * 256 + half * 128 + fk * 8;
#pragma unroll
                    for (int kf = 0; kf < 4; ++kf)
                        facc[nf] = __builtin_amdgcn_mfma_f32_16x16x32_bf16(
                            fa[kf], *(const bf16x8*)(bp + kf * 32), facc[nf], 0, 0, 0);
                }
                __syncthreads();
            }
#pragma unroll
            for (int nf = 0; nf < 4; ++nf) {
                int cc = nf * 16 + fr;
                float bias2 = fb2[cc];
#pragma unroll
                for (int rr = 0; rr < 4; ++rr) Xr[rb + rr][cc] += facc[nf][rr] + bias2;
            }
        }
        __syncthreads();
    }

    // store residual (fp32) + bf16 token part of Abf
    {
        int r = lane >> 2, c0 = (lane & 3) * 16;
        float* gx = xflat + (size_t)b * FLATN + r * 64 + c0;
#pragma unroll
        for (int u = 0; u < 4; ++u) *(float4*)(gx + u * 4) = *(const float4*)&Xr[r][c0 + u * 4];
        unsigned int pk[8];
#pragma unroll
        for (int e = 0; e < 8; ++e) pk[e] = packbf(Xr[r][c0 + 2 * e], Xr[r][c0 + 2 * e + 1]);
        unsigned int* ga = (unsigned int*)(Abf + (size_t)b * KP1 + r * 64 + c0);
#pragma unroll
        for (int e = 0; e < 8; ++e) ga[e] = pk[e];
    }
    // cont + zero-pad cols (1024..1087) of Abf
    {
        float v = (lane < CONTN) ? xflat[(size_t)b * FLATN + 1024 + lane] : 0.f;
        Abf[(size_t)b * KP1 + 1024 + lane] = __float2bfloat16(v);
    }
}

// ---------------- transpose + convert: W[K][N] fp32 -> Wt[Np][Kp] bf16 (zero-padded) ----
__global__ __launch_bounds__(256) void transpose_conv(
    const float* __restrict__ src, __hip_bfloat16* __restrict__ dst,
    int K, int N, int Kp, int Np)
{
    __shared__ float T[32][33];
    int k0 = blockIdx.y * 32, n0 = blockIdx.x * 32;
    int tn = threadIdx.x & 31, tk = threadIdx.x >> 5;
#pragma unroll
    for (int r = 0; r < 4; ++r) {
        int k = k0 + tk + r * 8, n = n0 + tn;
        T[tk + r * 8][tn] = (k < K && n < N) ? src[(size_t)k * N + n] : 0.f;
    }
    __syncthreads();
#pragma unroll
    for (int r = 0; r < 4; ++r) {
        int n = n0 + tk + r * 8, k = k0 + tn;
        dst[(size_t)n * Kp + k] = __float2bfloat16(T[tn][tk + r * 8]);
    }
}

// ---------------- bf16 MFMA GEMM: 128x128x64, dbuf prefetch + T2 swizzle ----------------
// A: [M][Kp] bf16; Bt: [Np][Kp] bf16 (= W^T).
// T2 (rule #21): linear LDS dest (gload_lds) + pre-swizzled GLOBAL k-slot
// (lane&7)^(lane>>3) + same XOR on the fragment-read slot -> 2-way banks (free).
// T3-min: stage next tile BEFORE compute, one __syncthreads per K-step.
// MODE 1: C[M][Np] bf16 gelu, coalesced via slot-swizzled LDS restage.
// MODE 2: partials[row][bx] = sum_cols gelu(.)*w3[col] (fused final dot).
template <int MODE>
__global__ __launch_bounds__(256) void gemm_mfma(
    const __hip_bfloat16* __restrict__ A, const __hip_bfloat16* __restrict__ Bt,
    const float* __restrict__ bias, int bias_n,
    __hip_bfloat16* __restrict__ Cbf, const float* __restrict__ w3,
    float* __restrict__ partials, int Np, int Kp)
{
    __shared__ __align__(16) short LDSbuf[32768];   // 64KB: buf{0,1} x (A 8192 | B 8192 shorts)

    int tid = threadIdx.x;
    int lane = tid & 63, wave = tid >> 6;

    // bijective XCD swizzle (m204)
    int nbx = gridDim.x;
    int nwg = nbx * gridDim.y;
    int wgid = blockIdx.y * nbx + blockIdx.x;
    int q = nwg >> 3, r = nwg & 7;
    int xcd = wgid & 7, loc = wgid >> 3;
    int sw = (xcd < r ? xcd * (q + 1) : r * (q + 1) + (xcd - r) * q) + loc;
    int bm = (sw / nbx) * 128, bx = sw % nbx, bn = bx * 128;

    // staging addresses: lane l -> row (l>>3), k-slot (l&7)^(l>>3)  [T2 pre-swizzle]
    int lrow8 = lane >> 3;
    int lk8sw = ((lane & 7) ^ lrow8) * 8;
    const __hip_bfloat16* Ag = A  + (size_t)(bm + wave * 32 + lrow8) * Kp + lk8sw;
    const __hip_bfloat16* Bg = Bt + (size_t)(bn + wave * 32 + lrow8) * Kp + lk8sw;

    int wm = (wave >> 1) * 64, wn = (wave & 1) * 64;
    int lrow = lane & 15, lk = lane >> 4;
    int key = lane & 7;                     // = (row&7) for this lane's fragment rows

    f32x4 acc[4][4] = {};
    int nt = Kp >> 6;

    // prologue: stage tile 0 into buf 0
    {
        short* Al = LDSbuf + wave * 32 * 64;
        short* Bl = Al + 8192;
#pragma unroll
        for (int it = 0; it < 4; ++it) {
            gload16(Ag + (size_t)(it * 8) * Kp, Al + it * 8 * 64);
            gload16(Bg + (size_t)(it * 8) * Kp, Bl + it * 8 * 64);
        }
    }
    __syncthreads();

    for (int t = 0; t < nt; ++t) {
        int cur = (t & 1) << 14;            // *16384 shorts
        if (t + 1 < nt) {
            int k0 = (t + 1) << 6;
            short* Al = LDSbuf + (((t + 1) & 1) << 14) + wave * 32 * 64;
            short* Bl = Al + 8192;
#pragma unroll
            for (int it = 0; it < 4; ++it) {
                gload16(Ag + (size_t)(it * 8) * Kp + k0, Al + it * 8 * 64);
                gload16(Bg + (size_t)(it * 8) * Kp + k0, Bl + it * 8 * 64);
            }
        }
        const short* Ab = LDSbuf + cur;
        const short* Bb = Ab + 8192;
#pragma unroll
        for (int ks = 0; ks < 2; ++ks) {
            int so = ((ks * 4 + lk) ^ key) * 8;     // swizzled slot offset (shorts)
            bf16x8 af[4], bf[4];
#pragma unroll
            for (int i = 0; i < 4; ++i) af[i] = *(const bf16x8*)(Ab + (wm + i * 16 + lrow) * 64 + so);
#pragma unroll
            for (int j = 0; j < 4; ++j) bf[j] = *(const bf16x8*)(Bb + (wn + j * 16 + lrow) * 64 + so);
#pragma unroll
            for (int i = 0; i < 4; ++i)
#pragma unroll
                for (int j = 0; j < 4; ++j)
                    acc[i][j] = __builtin_amdgcn_mfma_f32_16x16x32_bf16(af[i], bf[j], acc[i][j], 0, 0, 0);
        }
        __syncthreads();   // drains prefetch (issued before compute -> latency hidden)
    }

    if (MODE == 1) {
        // slot-swizzled LDS restage -> full-line coalesced bf16 stores
        short* Cs = LDSbuf;                 // [128][128] shorts, slot = 8 shorts
#pragma unroll
        for (int j = 0; j < 4; ++j) {
            int cl = wn + j * 16 + lrow;
            float bv = (bn + cl < bias_n) ? bias[bn + cl] : 0.f;
#pragma unroll
            for (int i = 0; i < 4; ++i) {
#pragma unroll
                for (int rr = 0; rr < 4; ++rr) {
                    int rl = wm + i * 16 + 4 * lk + rr;
                    int pos = ((((cl >> 3) ^ (rl & 7)) << 3) | (cl & 7));
                    Cs[rl * 128 + pos] = f2bf_s(gelu_f(acc[i][j][rr] + bv));
                }
            }
        }
        __syncthreads();
        int rloc = tid >> 1, half = tid & 1;
        int4* dst = (int4*)(Cbf + (size_t)(bm + rloc) * Np + bn + half * 64);
#pragma unroll
        for (int u = 0; u < 8; ++u) {
            int slot = half * 8 + (u ^ (rloc & 7));
            dst[u] = *(const int4*)&Cs[rloc * 128 + slot * 8];
        }
    } else {
        // fused w3 reduction
        float rs[16];
#pragma unroll
        for (int t = 0; t < 16; ++t) rs[t] = 0.f;
#pragma unroll
        for (int j = 0; j < 4; ++j) {
            int gcol = bn + wn + j * 16 + lrow;
            float bv  = (gcol < bias_n) ? bias[gcol] : 0.f;
            float w3v = (gcol < H2N) ? w3[gcol] : 0.f;
#pragma unroll
            for (int i = 0; i < 4; ++i)
#pragma unroll
                for (int rr = 0; rr < 4; ++rr)
                    rs[i * 4 + rr] += gelu_f(acc[i][j][rr] + bv) * w3v;
        }
#pragma unroll
        for (int o = 1; o < 16; o <<= 1)
#pragma unroll
            for (int t = 0; t < 16; ++t) rs[t] += __shfl_xor(rs[t], o, 64);
        float* pr = (float*)LDSbuf;         // [128][2]
        if (lrow == 0) {
#pragma unroll
            for (int i = 0; i < 4; ++i)
#pragma unroll
                for (int rr = 0; rr < 4; ++rr)
                    pr[(wm + i * 16 + 4 * lk + rr) * 2 + (wave & 1)] = rs[i * 4 + rr];
        }
        __syncthreads();
        if (tid < 128)
            partials[(size_t)(bm + tid) * nbx + bx] = pr[tid * 2] + pr[tid * 2 + 1];
    }
}

// ---------------- logits = b3 + sum over N-tiles of partials ----------------
__global__ __launch_bounds__(256) void reduce_partials(
    const float* __restrict__ partials, const float* __restrict__ b3,
    float* __restrict__ out, int n, int nbx)
{
    int b = blockIdx.x * 256 + threadIdx.x;
    if (b >= n) return;
    float s = b3[0];
    for (int x = 0; x < nbx; ++x) s += partials[(size_t)b * nbx + x];
    out[b] = s;
}

extern "C" void kernel_launch(void* const* d_in, const int* in_sizes, int n_in,
                              void* d_out, int out_size, void* d_ws, size_t ws_size,
                              hipStream_t stream)
{
    const int*   x_cat      = (const int*)  d_in[0];
    const float* x_cont     = (const float*)d_in[1];
    const float* shared_emb = (const float*)d_in[2];
    const float* emb        = (const float*)d_in[3];
    const float* mi_qkv  = (const float*)d_in[4];
    const float* mi_out  = (const float*)d_in[5];
    const float* mi_ln1w = (const float*)d_in[6];
    const float* mi_ln1b = (const float*)d_in[7];
    const float* mi_ln2w = (const float*)d_in[8];
    const float* mi_ln2b = (const float*)d_in[9];
    const float* mi_w1   = (const float*)d_in[10];
    const float* mi_b1   = (const float*)d_in[11];
    const float* mi_w2   = (const float*)d_in[12];
    const float* mi_b2   = (const float*)d_in[13];
    const float* ma_qkv  = (const float*)d_in[14];
    const float* ma_out  = (const float*)d_in[15];
    const float* ma_ln1w = (const float*)d_in[16];
    const float* ma_ln1b = (const float*)d_in[17];
    const float* ma_ln2w = (const float*)d_in[18];
    const float* ma_ln2b = (const float*)d_in[19];
    const float* ma_w1   = (const float*)d_in[20];
    const float* ma_b1   = (const float*)d_in[21];
    const float* ma_w2   = (const float*)d_in[22];
    const float* ma_b2   = (const float*)d_in[23];
    const float* cont_w  = (const float*)d_in[24];
    const float* cont_b  = (const float*)d_in[25];
    const float* w1      = (const float*)d_in[26];
    const float* b1      = (const float*)d_in[27];
    const float* w2      = (const float*)d_in[28];
    const float* b2      = (const float*)d_in[29];
    const float* w3      = (const float*)d_in[30];
    const float* b3      = (const float*)d_in[31];
    float* out = (float*)d_out;

    const int NBX2 = NP2 / 128;          // 17 N-tiles in GEMM2
    const size_t ENC_SH = 2 * 49152;
    const size_t FIXED = ((size_t)NP1 * KP1 + (size_t)NP2 * KP2 + ENC_SH) * 2;
    const size_t PER_ROW = (size_t)NP1 * 2 + (size_t)FLATN * 4 + (size_t)KP1 * 2 + (size_t)NBX2 * 4;
    size_t avail = (ws_size > FIXED) ? ws_size - FIXED : 0;
    long long chl = (long long)(avail / PER_ROW);
    int CH = (int)((chl / 128) * 128);
    if (CH > BATCH) CH = BATCH;
    if (CH < 128) CH = 128;

    char* p = (char*)d_ws;
    __hip_bfloat16* w1T = (__hip_bfloat16*)p; p += (size_t)NP1 * KP1 * 2;
    __hip_bfloat16* w2T = (__hip_bfloat16*)p; p += (size_t)NP2 * KP2 * 2;
    __hip_bfloat16* encT = (__hip_bfloat16*)p; p += ENC_SH * 2;
    __hip_bfloat16* h1  = (__hip_bfloat16*)p; p += (size_t)CH * NP1 * 2;
    float* xflat = (float*)p;                 p += (size_t)CH * FLATN * 4;
    __hip_bfloat16* Abf = (__hip_bfloat16*)p; p += (size_t)CH * KP1 * 2;
    float* partials = (float*)p;

    transpose_conv<<<dim3(NP1 / 32, KP1 / 32), 256, 0, stream>>>(w1, w1T, FLATN, H1N, KP1, NP1);
    transpose_conv<<<dim3(NP2 / 32, KP2 / 32), 256, 0, stream>>>(w2, w2T, H1N, H2N, KP2, NP2);

    for (int pl = 0; pl < 2; ++pl) {
        __hip_bfloat16* base = encT + (size_t)pl * 49152;
        transpose_conv<<<dim3(192 / 32, 64 / 32), 256, 0, stream>>>(
            ma_qkv + pl * 64 * 192, base, 64, 192, 64, 192);
        transpose_conv<<<dim3(64 / 32, 64 / 32), 256, 0, stream>>>(
            ma_out + pl * 64 * 64, base + 12288, 64, 64, 64, 64);
        transpose_conv<<<dim3(256 / 32, 64 / 32), 256, 0, stream>>>(
            ma_w1 + pl * 64 * 256, base + 16384, 64, 256, 64, 256);
        transpose_conv<<<dim3(64 / 32, 256 / 32), 256, 0, stream>>>(
            ma_w2 + pl * 256 * 64, base + 32768, 256, 64, 256, 64);
    }

    for (int m0 = 0; m0 < BATCH; m0 += CH) {
        int mc = BATCH - m0 < CH ? BATCH - m0 : CH;   // multiple of 128

        build_tokens<<<(mc * 1024) / 256, 256, 0, stream>>>(
            x_cat + (size_t)m0 * NCATS, shared_emb, emb, xflat);
        cont_proj<<<(mc * 16) / 256, 256, 0, stream>>>(
            x_cont + (size_t)m0 * CONTN, cont_w, cont_b, xflat);
        micro_enc<<<mc, 64, 0, stream>>>(xflat, mi_qkv, mi_out, mi_ln1w, mi_ln1b,
                                         mi_ln2w, mi_ln2b, mi_w1, mi_b1, mi_w2, mi_b2);
        macro_enc_mfma<<<mc, 64, 0, stream>>>(
            xflat, Abf, (const short*)encT, ma_ln1w, ma_ln1b, ma_ln2w, ma_ln2b, ma_b1, ma_b2);

        gemm_mfma<1><<<dim3(NP1 / 128, mc / 128), 256, 0, stream>>>(
            Abf, w1T, b1, H1N, h1, nullptr, nullptr, NP1, KP1);
        gemm_mfma<2><<<dim3(NBX2, mc / 128), 256, 0, stream>>>(
            h1, w2T, b2, H2N, nullptr, w3, partials, NP2, KP2);

        reduce_partials<<<(mc + 255) / 256, 256, 0, stream>>>(partials, b3, out + m0, mc, NBX2);
    }
}

// Round 9
// 1580.435 us; speedup vs baseline: 5.9268x; 1.4578x over previous
//
#include <hip/hip_runtime.h>
#include <hip/hip_bf16.h>
#include <math.h>

#define BATCH  16384
#define NCATS  16
#define VOCABN 1000
#define DIMD   64
#define SHARED_E 10
#define INDIVE 54
#define CONTN  16
#define FLATN  1040   // NCATS*DIMD + CONTN
#define H1N    4160
#define H2N    2080
#define KP1    1088   // FLATN padded to mult of 64
#define NP1    4224   // H1N padded to mult of 128
#define KP2    4224   // = NP1 (GEMM2 K)
#define NP2    2176   // H2N padded to mult of 128
#define EPSV   1e-5f

typedef __attribute__((ext_vector_type(8))) short bf16x8;
typedef __attribute__((ext_vector_type(4))) float f32x4;

__device__ __forceinline__ float gelu_f(float x) {
    return 0.5f * x * (1.0f + erff(x * 0.70710678118654752440f));
}
__device__ __forceinline__ float wsum(float v) {
#pragma unroll
    for (int o = 32; o > 0; o >>= 1) v += __shfl_xor(v, o, 64);
    return v;
}
__device__ __forceinline__ short f2bf_s(float a) {
    __hip_bfloat16 x = __float2bfloat16(a);
    return *reinterpret_cast<short*>(&x);
}
__device__ __forceinline__ unsigned int packbf(float a, float b) {
    __hip_bfloat16 x = __float2bfloat16(a), y = __float2bfloat16(b);
    unsigned short ux = *reinterpret_cast<unsigned short*>(&x);
    unsigned short uy = *reinterpret_cast<unsigned short*>(&y);
    return (unsigned)ux | ((unsigned)uy << 16);
}
__device__ __forceinline__ float bf_lo(unsigned int u) { return __uint_as_float(u << 16); }
__device__ __forceinline__ float bf_hi(unsigned int u) { return __uint_as_float(u & 0xffff0000u); }
// async global->LDS, 16B per lane; LDS dest is wave-uniform base + lane*16 (m97)
__device__ __forceinline__ void gload16(const void* g, void* l) {
    __builtin_amdgcn_global_load_lds(
        (const __attribute__((address_space(1))) void*)g,
        (__attribute__((address_space(3))) void*)l, 16, 0, 0);
}

// ---------------- token build: xflat[:, 0:1024] (chunk-local rows) ----------------
__global__ __launch_bounds__(256) void build_tokens(
    const int* __restrict__ x_cat, const float* __restrict__ shared_emb,
    const float* __restrict__ emb, float* __restrict__ xflat)
{
    int idx = blockIdx.x * 256 + threadIdx.x;      // mc*1024 total
    int b = idx >> 10, r = idx & 1023;
    int c = r >> 6, d = r & 63;
    float v;
    if (d < SHARED_E) v = shared_emb[d];
    else              v = emb[((size_t)c * VOCABN + x_cat[b * NCATS + c]) * INDIVE + (d - SHARED_E)];
    xflat[(size_t)b * FLATN + r] = v;
}

// ---------------- cont projection: xflat[:, 1024:1040] ----------------
__global__ __launch_bounds__(256) void cont_proj(
    const float* __restrict__ x_cont, const float* __restrict__ cw,
    const float* __restrict__ cb, float* __restrict__ xflat)
{
    int idx = blockIdx.x * 256 + threadIdx.x;      // mc*16 total
    int b = idx >> 4, j = idx & 15;
    float acc = cb[j];
#pragma unroll
    for (int k = 0; k < 16; ++k) acc += x_cont[b * 16 + k] * cw[k * 16 + j];
    xflat[(size_t)b * FLATN + 1024 + j] = acc;
}

// ---------------- micro encoder (MFMA): 8 samples/block (16 rows), 1 wave ----------------
// row r = sample(r>>1)*2 + token(r&1); weights layout same as macro (wT block).
__global__ __launch_bounds__(64) void micro_enc_mfma(
    float* __restrict__ xflat, const short* __restrict__ wT,
    const float* __restrict__ ln1w, const float* __restrict__ ln1b,
    const float* __restrict__ ln2w, const float* __restrict__ ln2b,
    const float* __restrict__ b1, const float* __restrict__ b2)
{
    __shared__ __align__(16) float Xr[16][68];
    __shared__ __align__(16) short XN[16][72];
    __shared__ __align__(16) short KVb[16][136];  // K cols 0-63, V 64-127; later ff1
    __shared__ __align__(16) short Qb[16][72];

    int lane = threadIdx.x;
    int b0 = blockIdx.x * 8;

    {   // load: row r = s*2+t  <-  xflat[(b0+s)][t*64 + c]
        int r = lane >> 2, c0 = (lane & 3) * 16;
        const float* gx = xflat + (size_t)(b0 + (r >> 1)) * FLATN + (r & 1) * 64 + c0;
#pragma unroll
        for (int u = 0; u < 4; ++u) *(float4*)&Xr[r][c0 + u * 4] = *(const float4*)(gx + u * 4);
    }
    __syncthreads();

    int fr = lane & 15, fk = lane >> 4;
    int rb = 4 * fk;
    float prevM[2] = {0.f, 0.f};

    for (int p = 0; p < 2; ++p) {
        const short* lq  = wT + p * 49152;
        const short* lo  = lq + 12288;
        const short* lf1 = lo + 4096;
        const short* lf2 = lf1 + 16384;
        const float* l1w = ln1w + p * 64; const float* l1b = ln1b + p * 64;
        const float* l2w = ln2w + p * 64; const float* l2b = ln2b + p * 64;
        const float* fb1 = b1 + p * 256;  const float* fb2 = b2 + p * 64;

        {   // LN1 -> XN
            float wv = l1w[lane], bv = l1b[lane];
#pragma unroll
            for (int i = 0; i < 16; ++i) {
                float v = Xr[i][lane];
                float m = wsum(v) * (1.f / 64.f);
                float d = v - m;
                float var = wsum(d * d) * (1.f / 64.f);
                XN[i][lane] = f2bf_s(d * rsqrtf(var + EPSV) * wv + bv);
            }
        }
        __syncthreads();

        {   // qkv MFMA: nf 0-3 -> Qb, nf 4-11 -> KVb
            bf16x8 a0 = *(const bf16x8*)&XN[fr][fk * 8];
            bf16x8 a1 = *(const bf16x8*)&XN[fr][fk * 8 + 32];
#pragma unroll
            for (int nf = 0; nf < 12; ++nf) {
                const short* bp = lq + (nf * 16 + fr) * 64 + fk * 8;
                bf16x8 bv0 = *(const bf16x8*)bp;
                bf16x8 bv1 = *(const bf16x8*)(bp + 32);
                f32x4 acc = {};
                acc = __builtin_amdgcn_mfma_f32_16x16x32_bf16(a0, bv0, acc, 0, 0, 0);
                acc = __builtin_amdgcn_mfma_f32_16x16x32_bf16(a1, bv1, acc, 0, 0, 0);
                int cc = nf * 16 + fr;
#pragma unroll
                for (int rr = 0; rr < 4; ++rr) {
                    if (nf < 4) Qb[rb + rr][cc] = f2bf_s(acc[rr]);
                    else        KVb[rb + rr][cc - 64] = f2bf_s(acc[rr]);
                }
            }
        }
        __syncthreads();

        {   // attention: lane = (s=lane>>3, h=(lane>>1)&3, qi=lane&1); 2 keys, registers
            int s_ = lane >> 3, h = (lane >> 1) & 3, qi = lane & 1;
            int qrow = s_ * 2 + qi;
            float q[16];
            {
                const unsigned* qp = (const unsigned*)&Qb[qrow][h * 16];
#pragma unroll
                for (int e = 0; e < 8; ++e) { q[2 * e] = bf_lo(qp[e]); q[2 * e + 1] = bf_hi(qp[e]); }
            }
            float sc[2];
#pragma unroll
            for (int j = 0; j < 2; ++j) {
                const unsigned* kp = (const unsigned*)&KVb[s_ * 2 + j][h * 16];
                float a = 0.f;
#pragma unroll
                for (int e = 0; e < 8; ++e)
                    a += q[2 * e] * bf_lo(kp[e]) + q[2 * e + 1] * bf_hi(kp[e]);
                a = a * 0.25f + prevM[j];
                prevM[j] = a;
                sc[j] = a;
            }
            float mx = fmaxf(sc[0], sc[1]);
            float e0 = expf(sc[0] - mx), e1 = expf(sc[1] - mx);
            float inv = 1.f / (e0 + e1);
            float p0 = e0 * inv, p1 = e1 * inv;
            const unsigned* v0 = (const unsigned*)&KVb[s_ * 2 + 0][64 + h * 16];
            const unsigned* v1 = (const unsigned*)&KVb[s_ * 2 + 1][64 + h * 16];
            unsigned* op = (unsigned*)&XN[qrow][h * 16];
#pragma unroll
            for (int e = 0; e < 8; ++e) {
                unsigned ua = v0[e], ub = v1[e];
                float olo = p0 * bf_lo(ua) + p1 * bf_lo(ub);
                float ohi = p0 * bf_hi(ua) + p1 * bf_hi(ub);
                op[e] = packbf(olo, ohi);
            }
        }
        __syncthreads();

        {   // out proj + residual
            bf16x8 a0 = *(const bf16x8*)&XN[fr][fk * 8];
            bf16x8 a1 = *(const bf16x8*)&XN[fr][fk * 8 + 32];
#pragma unroll
            for (int nf = 0; nf < 4; ++nf) {
                const short* bp = lo + (nf * 16 + fr) * 64 + fk * 8;
                bf16x8 bv0 = *(const bf16x8*)bp;
                bf16x8 bv1 = *(const bf16x8*)(bp + 32);
                f32x4 acc = {};
                acc = __builtin_amdgcn_mfma_f32_16x16x32_bf16(a0, bv0, acc, 0, 0, 0);
                acc = __builtin_amdgcn_mfma_f32_16x16x32_bf16(a1, bv1, acc, 0, 0, 0);
                int cc = nf * 16 + fr;
#pragma unroll
                for (int rr = 0; rr < 4; ++rr) Xr[rb + rr][cc] += acc[rr];
            }
        }
        __syncthreads();

        {   // LN2 -> XN
            float wv = l2w[lane], bv = l2b[lane];
#pragma unroll
            for (int i = 0; i < 16; ++i) {
                float v = Xr[i][lane];
                float m = wsum(v) * (1.f / 64.f);
                float d = v - m;
                float var = wsum(d * d) * (1.f / 64.f);
                XN[i][lane] = f2bf_s(d * rsqrtf(var + EPSV) * wv + bv);
            }
        }
        __syncthreads();

        {   // FFN: ff1 halves -> KVb, ff2 acc in regs
            bf16x8 a0 = *(const bf16x8*)&XN[fr][fk * 8];
            bf16x8 a1 = *(const bf16x8*)&XN[fr][fk * 8 + 32];
            f32x4 facc[4] = {};
#pragma unroll
            for (int half = 0; half < 2; ++half) {
#pragma unroll
                for (int nf = 0; nf < 8; ++nf) {
                    int ng = half * 128 + nf * 16;
                    const short* bp = lf1 + (ng + fr) * 64 + fk * 8;
                    bf16x8 bv0 = *(const bf16x8*)bp;
                    bf16x8 bv1 = *(const bf16x8*)(bp + 32);
                    f32x4 acc = {};
                    acc = __builtin_amdgcn_mfma_f32_16x16x32_bf16(a0, bv0, acc, 0, 0, 0);
                    acc = __builtin_amdgcn_mfma_f32_16x16x32_bf16(a1, bv1, acc, 0, 0, 0);
                    int cc = nf * 16 + fr;
                    float bias1 = fb1[ng + fr];
#pragma unroll
                    for (int rr = 0; rr < 4; ++rr)
                        KVb[rb + rr][cc] = f2bf_s(gelu_f(acc[rr] + bias1));
                }
                __syncthreads();
                bf16x8 fa[4];
#pragma unroll
                for (int kf = 0; kf < 4; ++kf)
                    fa[kf] = *(const bf16x8*)&KVb[fr][kf * 32 + fk * 8];
#pragma unroll
                for (int nf = 0; nf < 4; ++nf) {
                    const short* bp = lf2 + (nf * 16 + fr) * 256 + half * 128 + fk * 8;
#pragma unroll
                    for (int kf = 0; kf < 4; ++kf)
                        facc[nf] = __builtin_amdgcn_mfma_f32_16x16x32_bf16(
                            fa[kf], *(const bf16x8*)(bp + kf * 32), facc[nf], 0, 0, 0);
                }
                __syncthreads();
            }
#pragma unroll
            for (int nf = 0; nf < 4; ++nf) {
                int cc = nf * 16 + fr;
                float bias2 = fb2[cc];
#pragma unroll
                for (int rr = 0; rr < 4; ++rr) Xr[rb + rr][cc] += facc[nf][rr] + bias2;
            }
        }
        __syncthreads();
    }

    {   // store back
        int r = lane >> 2, c0 = (lane & 3) * 16;
        float* gx = xflat + (size_t)(b0 + (r >> 1)) * FLATN + (r & 1) * 64 + c0;
#pragma unroll
        for (int u = 0; u < 4; ++u) *(float4*)(gx + u * 4) = *(const float4*)&Xr[r][c0 + u * 4];
    }
}

// ---------------- macro encoder (MFMA attn): 1 sample / block, single wave ----------------
// Attention on matrix cores: S^T = K@Q^T (one 16x16x32 MFMA/head, d zero-padded via
// predication), softmax in 4 regs + 2 shfl, P->PV A-frag via 4 dword shuffles,
// V stored transposed (VT[d][h*16+j]) straight from the qkv MFMA epilogue.
__global__ __launch_bounds__(64) void macro_enc_mfma(
    float* __restrict__ xflat, __hip_bfloat16* __restrict__ Abf,
    const short* __restrict__ wT,
    const float* __restrict__ ln1w, const float* __restrict__ ln1b,
    const float* __restrict__ ln2w, const float* __restrict__ ln2b,
    const float* __restrict__ b1, const float* __restrict__ b2)
{
    __shared__ __align__(16) float Xr[16][68];
    __shared__ __align__(16) short XN[16][72];
    __shared__ __align__(16) short Qb[16][72];
    __shared__ __align__(16) short Kb[16][72];
    __shared__ __align__(16) short VT[16][72];   // VT[d][h*16 + token]

    int lane = threadIdx.x;
    int b = blockIdx.x;

    {   // load residual
        int r = lane >> 2, c0 = (lane & 3) * 16;
        const float* gx = xflat + (size_t)b * FLATN + r * 64 + c0;
#pragma unroll
        for (int u = 0; u < 4; ++u) *(float4*)&Xr[r][c0 + u * 4] = *(const float4*)(gx + u * 4);
    }
    __syncthreads();

    int fr = lane & 15, fk = lane >> 4;
    int rb = 4 * fk;
    f32x4 prevA[4] = {};

    for (int p = 0; p < 2; ++p) {
        const short* lq  = wT + p * 49152;
        const short* lo  = lq + 12288;
        const short* lf1 = lo + 4096;
        const short* lf2 = lf1 + 16384;
        const float* l1w = ln1w + p * 64; const float* l1b = ln1b + p * 64;
        const float* l2w = ln2w + p * 64; const float* l2b = ln2b + p * 64;
        const float* fb1 = b1 + p * 256;  const float* fb2 = b2 + p * 64;

        {   // LN1 -> XN
            float wv = l1w[lane], bv = l1b[lane];
#pragma unroll
            for (int i = 0; i < 16; ++i) {
                float v = Xr[i][lane];
                float m = wsum(v) * (1.f / 64.f);
                float d = v - m;
                float var = wsum(d * d) * (1.f / 64.f);
                XN[i][lane] = f2bf_s(d * rsqrtf(var + EPSV) * wv + bv);
            }
        }
        __syncthreads();

        {   // qkv MFMA: nf 0-3 -> Qb, 4-7 -> Kb, 8-11 -> VT (transposed write)
            bf16x8 a0 = *(const bf16x8*)&XN[fr][fk * 8];
            bf16x8 a1 = *(const bf16x8*)&XN[fr][fk * 8 + 32];
#pragma unroll
            for (int nf = 0; nf < 12; ++nf) {
                const short* bp = lq + (nf * 16 + fr) * 64 + fk * 8;
                bf16x8 bv0 = *(const bf16x8*)bp;
                bf16x8 bv1 = *(const bf16x8*)(bp + 32);
                f32x4 acc = {};
                acc = __builtin_amdgcn_mfma_f32_16x16x32_bf16(a0, bv0, acc, 0, 0, 0);
                acc = __builtin_amdgcn_mfma_f32_16x16x32_bf16(a1, bv1, acc, 0, 0, 0);
#pragma unroll
                for (int rr = 0; rr < 4; ++rr) {
                    short sv = f2bf_s(acc[rr]);
                    if (nf < 4)       Qb[rb + rr][nf * 16 + fr] = sv;
                    else if (nf < 8)  Kb[rb + rr][(nf - 4) * 16 + fr] = sv;
                    else              VT[fr][(nf - 8) * 16 + rb + rr] = sv;   // V[t][h16+d] -> VT[d][h16+t]
                }
            }
        }
        __syncthreads();

        {   // MFMA attention, per head
            bf16x8 zero8 = {};
#pragma unroll
            for (int h = 0; h < 4; ++h) {
                bf16x8 ka = zero8, qa = zero8, va = zero8;
                if (fk < 2) {
                    ka = *(const bf16x8*)&Kb[fr][h * 16 + fk * 8];
                    qa = *(const bf16x8*)&Qb[fr][h * 16 + fk * 8];
                    va = *(const bf16x8*)&VT[fr][h * 16 + fk * 8];
                }
                f32x4 s = {};
                s = __builtin_amdgcn_mfma_f32_16x16x32_bf16(ka, qa, s, 0, 0, 0);
                // s[rr] = S[i=fr][j=4*fk+rr]; carry prev
#pragma unroll
                for (int rr = 0; rr < 4; ++rr) {
                    s[rr] = s[rr] * 0.25f + prevA[h][rr];
                    prevA[h][rr] = s[rr];
                }
                // softmax over j (rr in-lane, fk across lanes 16/32)
                float m = fmaxf(fmaxf(s[0], s[1]), fmaxf(s[2], s[3]));
                m = fmaxf(m, __shfl_xor(m, 16, 64));
                m = fmaxf(m, __shfl_xor(m, 32, 64));
                float e0 = expf(s[0] - m), e1 = expf(s[1] - m);
                float e2 = expf(s[2] - m), e3 = expf(s[3] - m);
                float sum = e0 + e1 + e2 + e3;
                sum += __shfl_xor(sum, 16, 64);
                sum += __shfl_xor(sum, 32, 64);
                float inv = 1.f / sum;
                int pk0 = (int)packbf(e0 * inv, e1 * inv);   // j = 4fk+0,1
                int pk1 = (int)packbf(e2 * inv, e3 * inv);   // j = 4fk+2,3
                // PV A-frag: lane fk needs P[fr][fk*8 .. fk*8+7] <- src lanes (fr, 2fk),(fr, 2fk+1)
                int s1 = fr + (((2 * fk) & 3) << 4);
                int s2 = fr + (((2 * fk + 1) & 3) << 4);
                int d0 = __shfl(pk0, s1, 64), d1 = __shfl(pk1, s1, 64);
                int d2 = __shfl(pk0, s2, 64), d3 = __shfl(pk1, s2, 64);
                bf16x8 pa = zero8;
                if (fk < 2) {
                    union { int i[4]; bf16x8 v; } u;
                    u.i[0] = d0; u.i[1] = d1; u.i[2] = d2; u.i[3] = d3;
                    pa = u.v;
                }
                f32x4 o = {};
                o = __builtin_amdgcn_mfma_f32_16x16x32_bf16(pa, va, o, 0, 0, 0);
                // o[rr] = O[i=4fk+rr][d=fr]
#pragma unroll
                for (int rr = 0; rr < 4; ++rr)
                    XN[4 * fk + rr][h * 16 + fr] = f2bf_s(o[rr]);
            }
        }
        __syncthreads();

        {   // out proj + residual
            bf16x8 a0 = *(const bf16x8*)&XN[fr][fk * 8];
            bf16x8 a1 = *(const bf16x8*)&XN[fr][fk * 8 + 32];
#pragma unroll
            for (int nf = 0; nf < 4; ++nf) {
                const short* bp = lo + (nf * 16 + fr) * 64 + fk * 8;
                bf16x8 bv0 = *(const bf16x8*)bp;
                bf16x8 bv1 = *(const bf16x8*)(bp + 32);
                f32x4 acc = {};
                acc = __builtin_amdgcn_mfma_f32_16x16x32_bf16(a0, bv0, acc, 0, 0, 0);
                acc = __builtin_amdgcn_mfma_f32_16x16x32_bf16(a1, bv1, acc, 0, 0, 0);
                int cc = nf * 16 + fr;
#pragma unroll
                for (int rr = 0; rr < 4; ++rr) Xr[rb + rr][cc] += acc[rr];
            }
        }
        __syncthreads();

        {   // LN2 -> XN
            float wv = l2w[lane], bv = l2b[lane];
#pragma unroll
            for (int i = 0; i < 16; ++i) {
                float v = Xr[i][lane];
                float m = wsum(v) * (1.f / 64.f);
                float d = v - m;
                float var = wsum(d * d) * (1.f / 64.f);
                XN[i][lane] = f2bf_s(d * rsqrtf(var + EPSV) * wv + bv);
            }
        }
        __syncthreads();

        {   // FFN: ff1 halves -> Qb(cols 0-63)+Kb(cols 64-127), ff2 acc in regs
            bf16x8 a0 = *(const bf16x8*)&XN[fr][fk * 8];
            bf16x8 a1 = *(const bf16x8*)&XN[fr][fk * 8 + 32];
            f32x4 facc[4] = {};
#pragma unroll
            for (int half = 0; half < 2; ++half) {
#pragma unroll
                for (int nf = 0; nf < 8; ++nf) {
                    int ng = half * 128 + nf * 16;
                    const short* bp = lf1 + (ng + fr) * 64 + fk * 8;
                    bf16x8 bv0 = *(const bf16x8*)bp;
                    bf16x8 bv1 = *(const bf16x8*)(bp + 32);
                    f32x4 acc = {};
                    acc = __builtin_amdgcn_mfma_f32_16x16x32_bf16(a0, bv0, acc, 0, 0, 0);
                    acc = __builtin_amdgcn_mfma_f32_16x16x32_bf16(a1, bv1, acc, 0, 0, 0);
                    int cc = nf * 16 + fr;
                    float bias1 = fb1[ng + fr];
#pragma unroll
                    for (int rr = 0; rr < 4; ++rr) {
                        short sv = f2bf_s(gelu_f(acc[rr] + bias1));
                        if (cc < 64) Qb[rb + rr][cc] = sv;
                        else         Kb[rb + rr][cc - 64] = sv;
                    }
                }
                __syncthreads();
                bf16x8 fa[4];
                fa[0] = *(const bf16x8*)&Qb[fr][fk * 8];
                fa[1] = *(const bf16x8*)&Qb[fr][32 + fk * 8];
                fa[2] = *(const bf16x8*)&Kb[fr][fk * 8];
                fa[3] = *(const bf16x8*)&Kb[fr][32 + fk * 8];
#pragma unroll
                for (int nf = 0; nf < 4; ++nf) {
                    const short* bp = lf2 + (nf * 16 + fr) * 256 + half * 128 + fk * 8;
#pragma unroll
                    for (int kf = 0; kf < 4; ++kf)
                        facc[nf] = __builtin_amdgcn_mfma_f32_16x16x32_bf16(
                            fa[kf], *(const bf16x8*)(bp + kf * 32), facc[nf], 0, 0, 0);
                }
                __syncthreads();
            }
#pragma unroll
            for (int nf = 0; nf < 4; ++nf) {
                int cc = nf * 16 + fr;
                float bias2 = fb2[cc];
#pragma unroll
                for (int rr = 0; rr < 4; ++rr) Xr[rb + rr][cc] += facc[nf][rr] + bias2;
            }
        }
        __syncthreads();
    }

    // store residual (fp32) + bf16 token part of Abf
    {
        int r = lane >> 2, c0 = (lane & 3) * 16;
        float* gx = xflat + (size_t)b * FLATN + r * 64 + c0;
#pragma unroll
        for (int u = 0; u < 4; ++u) *(float4*)(gx + u * 4) = *(const float4*)&Xr[r][c0 + u * 4];
        unsigned int pk[8];
#pragma unroll
        for (int e = 0; e < 8; ++e) pk[e] = packbf(Xr[r][c0 + 2 * e], Xr[r][c0 + 2 * e + 1]);
        unsigned int* ga = (unsigned int*)(Abf + (size_t)b * KP1 + r * 64 + c0);
#pragma unroll
        for (int e = 0; e < 8; ++e) ga[e] = pk[e];
    }
    {
        float v = (lane < CONTN) ? xflat[(size_t)b * FLATN + 1024 + lane] : 0.f;
        Abf[(size_t)b * KP1 + 1024 + lane] = __float2bfloat16(v);
    }
}

// ---------------- transpose + convert: W[K][N] fp32 -> Wt[Np][Kp] bf16 (zero-padded) ----
__global__ __launch_bounds__(256) void transpose_conv(
    const float* __restrict__ src, __hip_bfloat16* __restrict__ dst,
    int K, int N, int Kp, int Np)
{
    __shared__ float T[32][33];
    int k0 = blockIdx.y * 32, n0 = blockIdx.x * 32;
    int tn = threadIdx.x & 31, tk = threadIdx.x >> 5;
#pragma unroll
    for (int r = 0; r < 4; ++r) {
        int k = k0 + tk + r * 8, n = n0 + tn;
        T[tk + r * 8][tn] = (k < K && n < N) ? src[(size_t)k * N + n] : 0.f;
    }
    __syncthreads();
#pragma unroll
    for (int r = 0; r < 4; ++r) {
        int n = n0 + tk + r * 8, k = k0 + tn;
        dst[(size_t)n * Kp + k] = __float2bfloat16(T[tn][tk + r * 8]);
    }
}

// ---------------- bf16 MFMA GEMM: 128x128x64, dbuf prefetch + T2 swizzle ----------------
template <int MODE>
__global__ __launch_bounds__(256) void gemm_mfma(
    const __hip_bfloat16* __restrict__ A, const __hip_bfloat16* __restrict__ Bt,
    const float* __restrict__ bias, int bias_n,
    __hip_bfloat16* __restrict__ Cbf, const float* __restrict__ w3,
    float* __restrict__ partials, int Np, int Kp)
{
    __shared__ __align__(16) short LDSbuf[32768];   // 64KB

    int tid = threadIdx.x;
    int lane = tid & 63, wave = tid >> 6;

    int nbx = gridDim.x;
    int nwg = nbx * gridDim.y;
    int wgid = blockIdx.y * nbx + blockIdx.x;
    int q = nwg >> 3, r = nwg & 7;
    int xcd = wgid & 7, loc = wgid >> 3;
    int sw = (xcd < r ? xcd * (q + 1) : r * (q + 1) + (xcd - r) * q) + loc;
    int bm = (sw / nbx) * 128, bx = sw % nbx, bn = bx * 128;

    int lrow8 = lane >> 3;
    int lk8sw = ((lane & 7) ^ lrow8) * 8;
    const __hip_bfloat16* Ag = A  + (size_t)(bm + wave * 32 + lrow8) * Kp + lk8sw;
    const __hip_bfloat16* Bg = Bt + (size_t)(bn + wave * 32 + lrow8) * Kp + lk8sw;

    int wm = (wave >> 1) * 64, wn = (wave & 1) * 64;
    int lrow = lane & 15, lk = lane >> 4;
    int key = lane & 7;

    f32x4 acc[4][4] = {};
    int nt = Kp >> 6;

    {
        short* Al = LDSbuf + wave * 32 * 64;
        short* Bl = Al + 8192;
#pragma unroll
        for (int it = 0; it < 4; ++it) {
            gload16(Ag + (size_t)(it * 8) * Kp, Al + it * 8 * 64);
            gload16(Bg + (size_t)(it * 8) * Kp, Bl + it * 8 * 64);
        }
    }
    __syncthreads();

    for (int t = 0; t < nt; ++t) {
        int cur = (t & 1) << 14;
        if (t + 1 < nt) {
            int k0 = (t + 1) << 6;
            short* Al = LDSbuf + (((t + 1) & 1) << 14) + wave * 32 * 64;
            short* Bl = Al + 8192;
#pragma unroll
            for (int it = 0; it < 4; ++it) {
                gload16(Ag + (size_t)(it * 8) * Kp + k0, Al + it * 8 * 64);
                gload16(Bg + (size_t)(it * 8) * Kp + k0, Bl + it * 8 * 64);
            }
        }
        const short* Ab = LDSbuf + cur;
        const short* Bb = Ab + 8192;
#pragma unroll
        for (int ks = 0; ks < 2; ++ks) {
            int so = ((ks * 4 + lk) ^ key) * 8;
            bf16x8 af[4], bf[4];
#pragma unroll
            for (int i = 0; i < 4; ++i) af[i] = *(const bf16x8*)(Ab + (wm + i * 16 + lrow) * 64 + so);
#pragma unroll
            for (int j = 0; j < 4; ++j) bf[j] = *(const bf16x8*)(Bb + (wn + j * 16 + lrow) * 64 + so);
#pragma unroll
            for (int i = 0; i < 4; ++i)
#pragma unroll
                for (int j = 0; j < 4; ++j)
                    acc[i][j] = __builtin_amdgcn_mfma_f32_16x16x32_bf16(af[i], bf[j], acc[i][j], 0, 0, 0);
        }
        __syncthreads();
    }

    if (MODE == 1) {
        short* Cs = LDSbuf;
#pragma unroll
        for (int j = 0; j < 4; ++j) {
            int cl = wn + j * 16 + lrow;
            float bv = (bn + cl < bias_n) ? bias[bn + cl] : 0.f;
#pragma unroll
            for (int i = 0; i < 4; ++i) {
#pragma unroll
                for (int rr = 0; rr < 4; ++rr) {
                    int rl = wm + i * 16 + 4 * lk + rr;
                    int pos = ((((cl >> 3) ^ (rl & 7)) << 3) | (cl & 7));
                    Cs[rl * 128 + pos] = f2bf_s(gelu_f(acc[i][j][rr] + bv));
                }
            }
        }
        __syncthreads();
        int rloc = tid >> 1, half = tid & 1;
        int4* dst = (int4*)(Cbf + (size_t)(bm + rloc) * Np + bn + half * 64);
#pragma unroll
        for (int u = 0; u < 8; ++u) {
            int slot = half * 8 + (u ^ (rloc & 7));
            dst[u] = *(const int4*)&Cs[rloc * 128 + slot * 8];
        }
    } else {
        float rs[16];
#pragma unroll
        for (int t = 0; t < 16; ++t) rs[t] = 0.f;
#pragma unroll
        for (int j = 0; j < 4; ++j) {
            int gcol = bn + wn + j * 16 + lrow;
            float bv  = (gcol < bias_n) ? bias[gcol] : 0.f;
            float w3v = (gcol < H2N) ? w3[gcol] : 0.f;
#pragma unroll
            for (int i = 0; i < 4; ++i)
#pragma unroll
                for (int rr = 0; rr < 4; ++rr)
                    rs[i * 4 + rr] += gelu_f(acc[i][j][rr] + bv) * w3v;
        }
#pragma unroll
        for (int o = 1; o < 16; o <<= 1)
#pragma unroll
            for (int t = 0; t < 16; ++t) rs[t] += __shfl_xor(rs[t], o, 64);
        float* pr = (float*)LDSbuf;
        if (lrow == 0) {
#pragma unroll
            for (int i = 0; i < 4; ++i)
#pragma unroll
                for (int rr = 0; rr < 4; ++rr)
                    pr[(wm + i * 16 + 4 * lk + rr) * 2 + (wave & 1)] = rs[i * 4 + rr];
        }
        __syncthreads();
        if (tid < 128)
            partials[(size_t)(bm + tid) * nbx + bx] = pr[tid * 2] + pr[tid * 2 + 1];
    }
}

// ---------------- logits = b3 + sum over N-tiles of partials ----------------
__global__ __launch_bounds__(256) void reduce_partials(
    const float* __restrict__ partials, const float* __restrict__ b3,
    float* __restrict__ out, int n, int nbx)
{
    int b = blockIdx.x * 256 + threadIdx.x;
    if (b >= n) return;
    float s = b3[0];
    for (int x = 0; x < nbx; ++x) s += partials[(size_t)b * nbx + x];
    out[b] = s;
}

extern "C" void kernel_launch(void* const* d_in, const int* in_sizes, int n_in,
                              void* d_out, int out_size, void* d_ws, size_t ws_size,
                              hipStream_t stream)
{
    const int*   x_cat      = (const int*)  d_in[0];
    const float* x_cont     = (const float*)d_in[1];
    const float* shared_emb = (const float*)d_in[2];
    const float* emb        = (const float*)d_in[3];
    const float* mi_qkv  = (const float*)d_in[4];
    const float* mi_out  = (const float*)d_in[5];
    const float* mi_ln1w = (const float*)d_in[6];
    const float* mi_ln1b = (const float*)d_in[7];
    const float* mi_ln2w = (const float*)d_in[8];
    const float* mi_ln2b = (const float*)d_in[9];
    const float* mi_w1   = (const float*)d_in[10];
    const float* mi_b1   = (const float*)d_in[11];
    const float* mi_w2   = (const float*)d_in[12];
    const float* mi_b2   = (const float*)d_in[13];
    const float* ma_qkv  = (const float*)d_in[14];
    const float* ma_out  = (const float*)d_in[15];
    const float* ma_ln1w = (const float*)d_in[16];
    const float* ma_ln1b = (const float*)d_in[17];
    const float* ma_ln2w = (const float*)d_in[18];
    const float* ma_ln2b = (const float*)d_in[19];
    const float* ma_w1   = (const float*)d_in[20];
    const float* ma_b1   = (const float*)d_in[21];
    const float* ma_w2   = (const float*)d_in[22];
    const float* ma_b2   = (const float*)d_in[23];
    const float* cont_w  = (const float*)d_in[24];
    const float* cont_b  = (const float*)d_in[25];
    const float* w1      = (const float*)d_in[26];
    const float* b1      = (const float*)d_in[27];
    const float* w2      = (const float*)d_in[28];
    const float* b2      = (const float*)d_in[29];
    const float* w3      = (const float*)d_in[30];
    const float* b3      = (const float*)d_in[31];
    float* out = (float*)d_out;

    const int NBX2 = NP2 / 128;          // 17 N-tiles in GEMM2
    const size_t ENC_SH = 4 * 49152;     // ma L0, ma L1, mi L0, mi L1
    const size_t FIXED = ((size_t)NP1 * KP1 + (size_t)NP2 * KP2 + ENC_SH) * 2;
    const size_t PER_ROW = (size_t)NP1 * 2 + (size_t)FLATN * 4 + (size_t)KP1 * 2 + (size_t)NBX2 * 4;
    size_t avail = (ws_size > FIXED) ? ws_size - FIXED : 0;
    long long chl = (long long)(avail / PER_ROW);
    int CH = (int)((chl / 128) * 128);
    if (CH > BATCH) CH = BATCH;
    if (CH < 128) CH = 128;

    char* p = (char*)d_ws;
    __hip_bfloat16* w1T = (__hip_bfloat16*)p; p += (size_t)NP1 * KP1 * 2;
    __hip_bfloat16* w2T = (__hip_bfloat16*)p; p += (size_t)NP2 * KP2 * 2;
    __hip_bfloat16* encT = (__hip_bfloat16*)p; p += ENC_SH * 2;
    __hip_bfloat16* h1  = (__hip_bfloat16*)p; p += (size_t)CH * NP1 * 2;
    float* xflat = (float*)p;                 p += (size_t)CH * FLATN * 4;
    __hip_bfloat16* Abf = (__hip_bfloat16*)p; p += (size_t)CH * KP1 * 2;
    float* partials = (float*)p;

    transpose_conv<<<dim3(NP1 / 32, KP1 / 32), 256, 0, stream>>>(w1, w1T, FLATN, H1N, KP1, NP1);
    transpose_conv<<<dim3(NP2 / 32, KP2 / 32), 256, 0, stream>>>(w2, w2T, H1N, H2N, KP2, NP2);

    // encoder weights -> bf16 [N][K] per layer: qkvT | outT | ff1T | ff2T
    const float* enc_qkv[2] = {ma_qkv, mi_qkv};
    const float* enc_out[2] = {ma_out, mi_out};
    const float* enc_w1[2]  = {ma_w1,  mi_w1};
    const float* enc_w2[2]  = {ma_w2,  mi_w2};
    for (int grp = 0; grp < 2; ++grp) {
        for (int pl = 0; pl < 2; ++pl) {
            __hip_bfloat16* base = encT + (size_t)(grp * 2 + pl) * 49152;
            transpose_conv<<<dim3(192 / 32, 64 / 32), 256, 0, stream>>>(
                enc_qkv[grp] + pl * 64 * 192, base, 64, 192, 64, 192);
            transpose_conv<<<dim3(64 / 32, 64 / 32), 256, 0, stream>>>(
                enc_out[grp] + pl * 64 * 64, base + 12288, 64, 64, 64, 64);
            transpose_conv<<<dim3(256 / 32, 64 / 32), 256, 0, stream>>>(
                enc_w1[grp] + pl * 64 * 256, base + 16384, 64, 256, 64, 256);
            transpose_conv<<<dim3(64 / 32, 256 / 32), 256, 0, stream>>>(
                enc_w2[grp] + pl * 256 * 64, base + 32768, 256, 64, 256, 64);
        }
    }

    for (int m0 = 0; m0 < BATCH; m0 += CH) {
        int mc = BATCH - m0 < CH ? BATCH - m0 : CH;   // multiple of 128

        build_tokens<<<(mc * 1024) / 256, 256, 0, stream>>>(
            x_cat + (size_t)m0 * NCATS, shared_emb, emb, xflat);
        cont_proj<<<(mc * 16) / 256, 256, 0, stream>>>(
            x_cont + (size_t)m0 * CONTN, cont_w, cont_b, xflat);
        micro_enc_mfma<<<mc / 8, 64, 0, stream>>>(
            xflat, (const short*)encT + 2 * 49152, mi_ln1w, mi_ln1b, mi_ln2w, mi_ln2b, mi_b1, mi_b2);
        macro_enc_mfma<<<mc, 64, 0, stream>>>(
            xflat, Abf, (const short*)encT, ma_ln1w, ma_ln1b, ma_ln2w, ma_ln2b, ma_b1, ma_b2);

        gemm_mfma<1><<<dim3(NP1 / 128, mc / 128), 256, 0, stream>>>(
            Abf, w1T, b1, H1N, h1, nullptr, nullptr, NP1, KP1);
        gemm_mfma<2><<<dim3(NBX2, mc / 128), 256, 0, stream>>>(
            h1, w2T, b2, H2N, nullptr, w3, partials, NP2, KP2);

        reduce_partials<<<(mc + 255) / 256, 256, 0, stream>>>(partials, b3, out + m0, mc, NBX2);
    }
}